// Round 4
// baseline (2224.911 us; speedup 1.0000x reference)
//
#include <hip/hip_runtime.h>
#include <stddef.h>

typedef unsigned short u16;
typedef unsigned int u32;

#define DEV __device__ __forceinline__

constexpr int Bb = 64;
constexpr int Tt = 512;
constexpr int Ee = 256;     // embedding dim == 2H (layer-1 input dim)
constexpr int Hh = 128;
constexpr int Kk = 32;
constexpr int G4 = 4 * Hh;  // 512 gates
constexpr int BT = Bb * Tt; // 32768 rows

DEV u16 f2b(float f) {
  u32 u = __builtin_bit_cast(u32, f);
  u += 0x7fffu + ((u >> 16) & 1u);   // round-to-nearest-even
  return (u16)(u >> 16);
}
DEV float b2f(u16 v) { return __builtin_bit_cast(float, (u32)v << 16); }
DEV float sigmoidf_(float x) { return 1.0f / (1.0f + __expf(-x)); }
DEV float tanhf_(float x) { return 1.0f - 2.0f / (1.0f + __expf(2.0f * x)); }

// ---------------- embedding lookup + cast to bf16 (t-major rows) ----------
__global__ __launch_bounds__(256) void k_embed(const int* __restrict__ x,
                                               const float* __restrict__ emb,
                                               u16* __restrict__ out) {
  int m = blockIdx.x * 4 + (threadIdx.x >> 6);  // out row = t*64 + b
  int lane = threadIdx.x & 63;
  int b = m & 63, t = m >> 6;
  int idx = x[b * Tt + t];
  float4 v = ((const float4*)(emb + (size_t)idx * Ee))[lane];
  uint2 p;
  p.x = (u32)f2b(v.x) | ((u32)f2b(v.y) << 16);
  p.y = (u32)f2b(v.z) | ((u32)f2b(v.w) << 16);
  ((uint2*)(out + (size_t)m * Ee))[lane] = p;
}

// ---------------- generic f32 -> bf16 cast --------------------------------
__global__ void k_cast(const float* __restrict__ s, u16* __restrict__ d, int n4) {
  int i = blockIdx.x * blockDim.x + threadIdx.x;
  if (i < n4) {
    float4 v = ((const float4*)s)[i];
    uint2 p;
    p.x = (u32)f2b(v.x) | ((u32)f2b(v.y) << 16);
    p.y = (u32)f2b(v.z) | ((u32)f2b(v.w) << 16);
    ((uint2*)d)[i] = p;
  }
}

// ---------------- MFMA GEMM (NT), fwd+bwd fused, lstm-layout epilogue -----
// A: (32768,256) bf16; W0/W1: (512,256) bf16; writes xp in the "lstm layout":
// element (t, b, g, j) at flat = ((t*16 + b>>2)*128 + (j>>4)*16 + (j&15))*16
//                               + g*4 + (b&3)
// so one lstm loader thread reads its 16 values as 32 contiguous bytes.
typedef __attribute__((ext_vector_type(8))) short bfrag;
typedef __attribute__((ext_vector_type(4))) float ffrag;

__global__ __launch_bounds__(256) void k_gemm2(const u16* __restrict__ A,
                                               const u16* __restrict__ W0,
                                               const u16* __restrict__ W1,
                                               const float* __restrict__ bias0,
                                               const float* __restrict__ bias1,
                                               u16* __restrict__ out0,
                                               u16* __restrict__ out1) {
  constexpr int BM = 128, BN = 64, BK = 64, LDT = 72;
  __shared__ u16 As[BM * LDT];
  __shared__ u16 Ws[BN * LDT];
  const int tid = threadIdx.x;
  const int bm = blockIdx.x * BM;
  const int sel = blockIdx.y >> 3;
  const int bn = (blockIdx.y & 7) * BN;
  const u16* __restrict__ W = sel ? W1 : W0;
  const float* __restrict__ bias = sel ? bias1 : bias0;
  u16* __restrict__ outp = sel ? out1 : out0;
  const int w = tid >> 6;
  const int l = tid & 63;
  const int r16 = l & 15;
  const int k8 = (l >> 4) << 3;

  ffrag acc[2][4];
#pragma unroll
  for (int i = 0; i < 2; ++i)
#pragma unroll
    for (int j = 0; j < 4; ++j) acc[i][j] = (ffrag)0.0f;

  for (int kt = 0; kt < 256; kt += BK) {
#pragma unroll
    for (int c = 0; c < 4; ++c) {
      int ch = tid + 256 * c;
      int row = ch >> 3, c8 = (ch & 7) << 3;
      *(uint4*)&As[row * LDT + c8] =
          *(const uint4*)&A[(size_t)(bm + row) * 256 + kt + c8];
    }
#pragma unroll
    for (int c = 0; c < 2; ++c) {
      int ch = tid + 256 * c;
      int row = ch >> 3, c8 = (ch & 7) << 3;
      *(uint4*)&Ws[row * LDT + c8] =
          *(const uint4*)&W[(size_t)(bn + row) * 256 + kt + c8];
    }
    __syncthreads();
#pragma unroll
    for (int kk = 0; kk < 2; ++kk) {
      bfrag af[2], wf[4];
#pragma unroll
      for (int fm = 0; fm < 2; ++fm)
        af[fm] = *(const bfrag*)&As[(w * 32 + fm * 16 + r16) * LDT + kk * 32 + k8];
#pragma unroll
      for (int fn = 0; fn < 4; ++fn)
        wf[fn] = *(const bfrag*)&Ws[(fn * 16 + r16) * LDT + kk * 32 + k8];
#pragma unroll
      for (int fm = 0; fm < 2; ++fm)
#pragma unroll
        for (int fn = 0; fn < 4; ++fn)
          acc[fm][fn] = __builtin_amdgcn_mfma_f32_16x16x32_bf16(
              af[fm], wf[fn], acc[fm][fn], 0, 0, 0);
    }
    __syncthreads();
  }
  const int rbase = (l >> 4) * 4;  // C/D: col = lane&15, row = (lane>>4)*4 + reg
#pragma unroll
  for (int fm = 0; fm < 2; ++fm)
#pragma unroll
    for (int fn = 0; fn < 4; ++fn) {
      int col = bn + fn * 16 + r16;
      int g = col >> 7, jc = col & 127;
      float bv = bias[col];
      int row0 = bm + w * 32 + fm * 16 + rbase;           // rows row0..row0+3
      int t = row0 >> 6, bbv = row0 & 63;                 // b-quad fixed
      size_t flat = (((size_t)t * 16 + (bbv >> 2)) * 128 +
                     (jc >> 4) * 16 + (jc & 15)) * 16 + (size_t)g * 4;
      u32 lo = (u32)f2b(acc[fm][fn][0] + bv) | ((u32)f2b(acc[fm][fn][1] + bv) << 16);
      u32 hi = (u32)f2b(acc[fm][fn][2] + bv) | ((u32)f2b(acc[fm][fn][3] + bv) << 16);
      uint2 st; st.x = lo; st.y = hi;
      *(uint2*)&outp[flat] = st;
    }
}

// extract bf16 element K (0..7) of a uint4 holding 8 packed bf16
#define EXU(V, K) b2f((u16)((((K) & 1) ? ((&(V).x)[(K) >> 1] >> 16) \
                                        : (&(V).x)[(K) >> 1])))

// ---------------- MFMA LSTM: 4 batches/WG, 32 WGs, batch-as-M -------------
// Wave w owns j in [16w,16w+16) for all 4 gates. Whh resident in VGPRs
// (B-operand). h rows 0-3 in LDS (rows 4-15 stay zero). EW + xp loads on
// q==0 lanes only (16/wave, 4 cells each). xp read as 2 coalesced dwordx4
// per loader (lstm layout, see k_gemm2), depth-2 prefetch via unroll-by-2.
// Out stores deferred one step. One barrier per step.
__global__ __launch_bounds__(512, 1) void k_lstm4(const u16* __restrict__ xpf,
                                                  const u16* __restrict__ xpb,
                                                  const float* __restrict__ whhf,
                                                  const float* __restrict__ whhb,
                                                  u16* __restrict__ out) {
  __shared__ u16 hbuf[2 * 16 * 128];   // 8 KB: [buf][row][j ^ (row<<3)]
  const int dir = blockIdx.x >> 4;
  const int wg = blockIdx.x & 15;
  const int b0 = wg * 4;
  const u16* __restrict__ xp = dir ? xpb : xpf;
  const float* __restrict__ whh = dir ? whhb : whhf;
  const int tid = threadIdx.x;
  const int w = tid >> 6;
  const int l = tid & 63;
  const int q = l >> 4;
  const int jw = l & 15;
  const int j = 16 * w + jw;

  for (int i = tid; i < 2 * 16 * 128; i += 512) hbuf[i] = 0;

  // B-operand fragments: Whh row = g*128 + j, k-slice = ks*32 + q*8 .. +8
  bfrag wf[4][4];
#pragma unroll
  for (int g = 0; g < 4; ++g) {
    const float* rowp = whh + (size_t)(g * 128 + j) * 128;
#pragma unroll
    for (int ks = 0; ks < 4; ++ks) {
      float4 x0 = ((const float4*)(rowp + ks * 32 + q * 8))[0];
      float4 x1 = ((const float4*)(rowp + ks * 32 + q * 8))[1];
      bfrag t;
      t[0] = (short)f2b(x0.x); t[1] = (short)f2b(x0.y);
      t[2] = (short)f2b(x0.z); t[3] = (short)f2b(x0.w);
      t[4] = (short)f2b(x1.x); t[5] = (short)f2b(x1.y);
      t[6] = (short)f2b(x1.z); t[7] = (short)f2b(x1.w);
      wf[g][ks] = t;
    }
  }
  __syncthreads();

  const int dt = dir ? -1 : 1;
  int tp = dir ? (Tt - 1) : 0;
  const size_t xconst = (size_t)wg * 2048 + (size_t)(w * 16 + jw) * 16;
  float cc[4] = {0.f, 0.f, 0.f, 0.f};
  int cur = 0;
  u16 ho[4];
  size_t oprev = 0;

  uint4 xa0, xb0, xa1, xb1;   // even/odd step prefetch buffers
  if (q == 0) {
    size_t o0 = (size_t)tp * 32768 + xconst;
    xa0 = *(const uint4*)&xp[o0]; xb0 = *(const uint4*)&xp[o0 + 8];
    size_t o1 = (size_t)(tp + dt) * 32768 + xconst;
    xa1 = *(const uint4*)&xp[o1]; xb1 = *(const uint4*)&xp[o1 + 8];
  }

#define LSTM_STEP(XA, XB, FIRST)                                              \
  {                                                                           \
    if (!(FIRST) && q == 0) {                                                 \
      out[oprev] = ho[0]; out[oprev + 256] = ho[1];                           \
      out[oprev + 512] = ho[2]; out[oprev + 768] = ho[3];                     \
    }                                                                         \
    ffrag a0 = (ffrag)0.f, a1 = (ffrag)0.f, a2 = (ffrag)0.f, a3 = (ffrag)0.f; \
    const u16* hb = hbuf + cur * 2048;                                        \
    _Pragma("unroll")                                                         \
    for (int ks = 0; ks < 4; ++ks) {                                          \
      bfrag hf = *(const bfrag*)&hb[jw * 128 + ((ks * 32 + q * 8) ^ (jw << 3))]; \
      a0 = __builtin_amdgcn_mfma_f32_16x16x32_bf16(hf, wf[0][ks], a0, 0, 0, 0); \
      a1 = __builtin_amdgcn_mfma_f32_16x16x32_bf16(hf, wf[1][ks], a1, 0, 0, 0); \
      a2 = __builtin_amdgcn_mfma_f32_16x16x32_bf16(hf, wf[2][ks], a2, 0, 0, 0); \
      a3 = __builtin_amdgcn_mfma_f32_16x16x32_bf16(hf, wf[3][ks], a3, 0, 0, 0); \
    }                                                                         \
    if (q == 0) {                                                             \
      float hvf[4];                                                           \
      _Pragma("unroll")                                                       \
      for (int r = 0; r < 4; ++r) {                                           \
        float gi = a0[r] + EXU(XA, r);                                        \
        float gf = a1[r] + EXU(XA, 4 + r);                                    \
        float gg = a2[r] + EXU(XB, r);                                        \
        float go = a3[r] + EXU(XB, 4 + r);                                    \
        cc[r] = sigmoidf_(gf) * cc[r] + sigmoidf_(gi) * tanhf_(gg);           \
        hvf[r] = sigmoidf_(go) * tanhf_(cc[r]);                               \
      }                                                                       \
      u32 p01, p23;                                                           \
      asm("v_cvt_pk_bf16_f32 %0, %1, %2" : "=v"(p01) : "v"(hvf[0]), "v"(hvf[1])); \
      asm("v_cvt_pk_bf16_f32 %0, %1, %2" : "=v"(p23) : "v"(hvf[2]), "v"(hvf[3])); \
      u16* hw = hbuf + (cur ^ 1) * 2048;                                      \
      hw[0 * 128 + (j ^ 0)]  = (u16)p01;                                      \
      hw[1 * 128 + (j ^ 8)]  = (u16)(p01 >> 16);                              \
      hw[2 * 128 + (j ^ 16)] = (u16)p23;                                      \
      hw[3 * 128 + (j ^ 24)] = (u16)(p23 >> 16);                              \
      ho[0] = (u16)p01; ho[1] = (u16)(p01 >> 16);                             \
      ho[2] = (u16)p23; ho[3] = (u16)(p23 >> 16);                             \
    }                                                                         \
    oprev = ((size_t)tp * 64 + b0) * 256 + (size_t)dir * 128 + j;             \
    int tpre = tp + 2 * dt;                                                   \
    if (tpre < 0 || tpre > Tt - 1) tpre = tp;                                 \
    if (q == 0) {                                                             \
      size_t op = (size_t)tpre * 32768 + xconst;                              \
      XA = *(const uint4*)&xp[op]; XB = *(const uint4*)&xp[op + 8];           \
    }                                                                         \
    __syncthreads();                                                          \
    cur ^= 1; tp += dt;                                                       \
  }

  for (int s2 = 0; s2 < Tt; s2 += 2) {
    LSTM_STEP(xa0, xb0, (s2 == 0));
    LSTM_STEP(xa1, xb1, false);
  }
#undef LSTM_STEP
  if (q == 0) {
    out[oprev] = ho[0]; out[oprev + 256] = ho[1];
    out[oprev + 512] = ho[2]; out[oprev + 768] = ho[3];
  }
}

// ---------------- FC: emissions = out1 @ fcW^T + fcb (fp32 out) -----------
__global__ __launch_bounds__(256) void k_fc(const u16* __restrict__ Aa,
                                            const u16* __restrict__ Wc,
                                            const float* __restrict__ bias,
                                            float* __restrict__ emis) {
  constexpr int LDW = 260;
  __shared__ u16 As[8 * 256];
  __shared__ u16 Ws[32 * LDW];
  int tid = threadIdx.x;
  int row0 = blockIdx.x * 8;
  *(uint4*)&As[tid * 8] = *(const uint4*)&Aa[(size_t)row0 * 256 + tid * 8];
#pragma unroll
  for (int cfc = 0; cfc < 8; ++cfc) {
    int ch = tid + 256 * cfc;
    int row = ch >> 6, c4 = (ch & 63) << 2;
    *(uint2*)&Ws[row * LDW + c4] = *(const uint2*)&Wc[row * 256 + c4];
  }
  __syncthreads();
  int r = tid >> 5, cj = tid & 31;
  const u16* ap = &As[r * 256];
  const u16* wp = &Ws[cj * LDW];
  float s0 = 0.f, s1 = 0.f;
#pragma unroll
  for (int k2 = 0; k2 < 128; ++k2) {
    u32 av = *(const u32*)&ap[k2 * 2];
    u32 wv = *(const u32*)&wp[k2 * 2];
    s0 += b2f((u16)av) * b2f((u16)wv);
    s1 += b2f((u16)(av >> 16)) * b2f((u16)(wv >> 16));
  }
  emis[(size_t)(row0 + r) * Kk + cj] = s0 + s1 + bias[cj];
}

// ---------------- CRF (emissions t-major: row = t*64 + b) -----------------
__global__ __launch_bounds__(64) void k_crf(const float* __restrict__ emis,
                                            const int* __restrict__ tags,
                                            const float* __restrict__ trans,
                                            const float* __restrict__ startv,
                                            const float* __restrict__ endv,
                                            float* __restrict__ nll) {
  __shared__ float alpha[Kk];
  __shared__ float tr[Kk * Kk];
  const int b = blockIdx.x;
  const int l = threadIdx.x;
  const int j = l & 31;
  const int half = l >> 5;
  for (int i = l; i < Kk * Kk; i += 64) tr[i] = trans[i];
  const float* eb = emis + (size_t)b * Kk;   // stride per t = 64*Kk
  if (l < Kk) alpha[l] = startv[l] + eb[l];
  __syncthreads();
  for (int t = 1; t < Tt; ++t) {
    float v[16];
    float m = -1e30f;
#pragma unroll
    for (int i = 0; i < 16; ++i) {
      int ii = half * 16 + i;
      v[i] = alpha[ii] + tr[ii * Kk + j];
      m = fmaxf(m, v[i]);
    }
    float s = 0.f;
#pragma unroll
    for (int i = 0; i < 16; ++i) s += __expf(v[i] - m);
    float m2 = __shfl_xor(m, 32);
    float s2 = __shfl_xor(s, 32);
    float M = fmaxf(m, m2);
    s = s * __expf(m - M) + s2 * __expf(m2 - M);
    float na = eb[(size_t)t * (64 * Kk) + j] + M + __logf(s);
    __syncthreads();
    if (l < Kk) alpha[l] = na;
    __syncthreads();
  }
  float val = (l < Kk) ? alpha[l] + endv[l] : -1e30f;
  float M = val;
#pragma unroll
  for (int off = 32; off > 0; off >>= 1) M = fmaxf(M, __shfl_xor(M, off));
  float sz = (l < Kk) ? __expf(val - M) : 0.f;
#pragma unroll
  for (int off = 32; off > 0; off >>= 1) sz += __shfl_xor(sz, off);
  float logZ = M + __logf(sz);

  const int* tg = tags + (size_t)b * Tt;
  float g = 0.f;
  for (int t = l; t < Tt; t += 64) {
    int cur = tg[t];
    g += eb[(size_t)t * (64 * Kk) + cur];
    if (t >= 1) g += tr[cur * Kk + tg[t - 1]];
  }
#pragma unroll
  for (int off = 32; off > 0; off >>= 1) g += __shfl_xor(g, off);
  if (l == 0) {
    g += startv[tg[0]] + endv[tg[Tt - 1]];
    nll[b] = logZ - g;
  }
}

__global__ void k_reduce(const float* __restrict__ nll, float* __restrict__ out) {
  float v = nll[threadIdx.x];
#pragma unroll
  for (int off = 32; off > 0; off >>= 1) v += __shfl_xor(v, off);
  if (threadIdx.x == 0) out[0] = v * (1.0f / 64.0f);
}

// --------------------------------------------------------------------------
extern "C" void kernel_launch(void* const* d_in, const int* in_sizes, int n_in,
                              void* d_out, int out_size, void* d_ws, size_t ws_size,
                              hipStream_t stream) {
  (void)in_sizes; (void)n_in; (void)out_size; (void)ws_size;
  const int*   x      = (const int*)d_in[0];
  const int*   tags   = (const int*)d_in[2];
  const float* emb    = (const float*)d_in[4];
  const float* Wih0f  = (const float*)d_in[5];
  const float* Whh0f  = (const float*)d_in[6];
  const float* b0f    = (const float*)d_in[7];
  const float* Wih0b  = (const float*)d_in[8];
  const float* Whh0b  = (const float*)d_in[9];
  const float* b0b    = (const float*)d_in[10];
  const float* Wih1f  = (const float*)d_in[11];
  const float* Whh1f  = (const float*)d_in[12];
  const float* b1f    = (const float*)d_in[13];
  const float* Wih1b  = (const float*)d_in[14];
  const float* Whh1b  = (const float*)d_in[15];
  const float* b1b    = (const float*)d_in[16];
  const float* fcW    = (const float*)d_in[17];
  const float* fcb    = (const float*)d_in[18];
  const float* trans  = (const float*)d_in[19];
  const float* startv = (const float*)d_in[20];
  const float* endv   = (const float*)d_in[21];

  char* p = (char*)d_ws;
  u16* buf0 = (u16*)p; p += (size_t)BT * Ee * 2;   // embeddings / layer-1 out
  u16* buf1 = (u16*)p; p += (size_t)BT * 256 * 2;  // layer-0 out
  u16* xpf  = (u16*)p; p += (size_t)BT * G4 * 2;   // fwd proj (lstm layout)
  u16* xpb  = (u16*)p; p += (size_t)BT * G4 * 2;   // bwd proj (lstm layout)
  u16* wb[4];
  for (int i = 0; i < 4; ++i) { wb[i] = (u16*)p; p += (size_t)512 * 256 * 2; }
  u16* fcwb = (u16*)p; p += (size_t)32 * 256 * 2;
  float* emis = (float*)p; p += (size_t)BT * Kk * 4;
  float* nll  = (float*)p; p += 256;

  k_embed<<<dim3(BT / 4), dim3(256), 0, stream>>>(x, emb, buf0);

  const float* wsrc[5] = {Wih0f, Wih0b, Wih1f, Wih1b, fcW};
  u16* wdst[5] = {wb[0], wb[1], wb[2], wb[3], fcwb};
  int wn[5] = {512 * 256, 512 * 256, 512 * 256, 512 * 256, 32 * 256};
  for (int i = 0; i < 5; ++i) {
    int n4 = wn[i] / 4;
    k_cast<<<dim3((n4 + 255) / 256), dim3(256), 0, stream>>>(wsrc[i], wdst[i], n4);
  }

  dim3 ggrid(BT / 128, 16);
  // layer 0
  k_gemm2<<<ggrid, dim3(256), 0, stream>>>(buf0, wb[0], wb[1], b0f, b0b, xpf, xpb);
  k_lstm4<<<dim3(32), dim3(512), 0, stream>>>(xpf, xpb, Whh0f, Whh0b, buf1);
  // layer 1
  k_gemm2<<<ggrid, dim3(256), 0, stream>>>(buf1, wb[2], wb[3], b1f, b1b, xpf, xpb);
  k_lstm4<<<dim3(32), dim3(512), 0, stream>>>(xpf, xpb, Whh1f, Whh1b, buf0);
  // emissions + CRF
  k_fc<<<dim3(BT / 8), dim3(256), 0, stream>>>(buf0, fcwb, fcb, emis);
  k_crf<<<dim3(Bb), dim3(64), 0, stream>>>(emis, tags, trans, startv, endv, nll);
  k_reduce<<<dim3(1), dim3(64), 0, stream>>>(nll, (float*)d_out);
}

// Round 5
// 1089.167 us; speedup vs baseline: 2.0428x; 2.0428x over previous
//
#include <hip/hip_runtime.h>
#include <stddef.h>

typedef unsigned short u16;
typedef unsigned int u32;

#define DEV __device__ __forceinline__

constexpr int Bb = 64;
constexpr int Tt = 512;
constexpr int Ee = 256;     // embedding dim == 2H (layer-1 input dim)
constexpr int Hh = 128;
constexpr int Kk = 32;
constexpr int G4 = 4 * Hh;  // 512 gates
constexpr int BT = Bb * Tt; // 32768 rows

DEV u16 f2b(float f) {
  u32 u = __builtin_bit_cast(u32, f);
  u += 0x7fffu + ((u >> 16) & 1u);   // round-to-nearest-even
  return (u16)(u >> 16);
}
DEV float b2f(u16 v) { return __builtin_bit_cast(float, (u32)v << 16); }
DEV float sigmoidf_(float x) { return 1.0f / (1.0f + __expf(-x)); }
DEV float tanhf_(float x) { return 1.0f - 2.0f / (1.0f + __expf(2.0f * x)); }

// LDS-only barrier: does NOT drain vmcnt, so global prefetch loads and
// h-stores stay in flight across steps (T4: never vmcnt(0) in the loop).
DEV void lds_barrier() {
  asm volatile("s_waitcnt lgkmcnt(0)" ::: "memory");
  __builtin_amdgcn_sched_barrier(0);
  __builtin_amdgcn_s_barrier();
  __builtin_amdgcn_sched_barrier(0);
}

// ---------------- embedding lookup + cast to bf16 (t-major rows) ----------
__global__ __launch_bounds__(256) void k_embed(const int* __restrict__ x,
                                               const float* __restrict__ emb,
                                               u16* __restrict__ out) {
  int m = blockIdx.x * 4 + (threadIdx.x >> 6);  // out row = t*64 + b
  int lane = threadIdx.x & 63;
  int b = m & 63, t = m >> 6;
  int idx = x[b * Tt + t];
  float4 v = ((const float4*)(emb + (size_t)idx * Ee))[lane];
  uint2 p;
  p.x = (u32)f2b(v.x) | ((u32)f2b(v.y) << 16);
  p.y = (u32)f2b(v.z) | ((u32)f2b(v.w) << 16);
  ((uint2*)(out + (size_t)m * Ee))[lane] = p;
}

// ---------------- generic f32 -> bf16 cast --------------------------------
__global__ void k_cast(const float* __restrict__ s, u16* __restrict__ d, int n4) {
  int i = blockIdx.x * blockDim.x + threadIdx.x;
  if (i < n4) {
    float4 v = ((const float4*)s)[i];
    uint2 p;
    p.x = (u32)f2b(v.x) | ((u32)f2b(v.y) << 16);
    p.y = (u32)f2b(v.z) | ((u32)f2b(v.w) << 16);
    ((uint2*)d)[i] = p;
  }
}

// ---------------- Wih cast with row permutation n' = j*4 + g --------------
// wb'[n'][k] = Wih[(n'&3)*128 + (n'>>2)][k]; 512x256, one uint2 per thread
__global__ __launch_bounds__(256) void k_castW(const float* __restrict__ s,
                                               u16* __restrict__ d) {
  int i = blockIdx.x * 256 + threadIdx.x;  // 32768 = 512 rows x 64 float4
  int np = i >> 6, k4 = i & 63;
  int src = (np & 3) * 128 + (np >> 2);
  float4 v = ((const float4*)(s + (size_t)src * 256))[k4];
  uint2 p;
  p.x = (u32)f2b(v.x) | ((u32)f2b(v.y) << 16);
  p.y = (u32)f2b(v.z) | ((u32)f2b(v.w) << 16);
  ((uint2*)(d + (size_t)np * 256))[k4] = p;
}

// ---------------- MFMA GEMM (NT), fwd+bwd fused, lstm-layout epilogue -----
// A: (32768,256) bf16; W: permuted rows (n' = j*4+g). Output element
// (t,b,g,j) at flat = (t*16 + b/4)*2048 + j*16 + (b&3)*4 + g, so one lstm
// lane (batch b, j) reads its 4 gates as one uint2.
typedef __attribute__((ext_vector_type(8))) short bfrag;
typedef __attribute__((ext_vector_type(4))) float ffrag;

__global__ __launch_bounds__(256) void k_gemm2(const u16* __restrict__ A,
                                               const u16* __restrict__ W0,
                                               const u16* __restrict__ W1,
                                               const float* __restrict__ bias0,
                                               const float* __restrict__ bias1,
                                               u16* __restrict__ out0,
                                               u16* __restrict__ out1) {
  constexpr int BM = 128, BN = 64, BK = 64, LDT = 72;
  __shared__ u16 As[BM * LDT];
  __shared__ u16 Ws[BN * LDT];
  const int tid = threadIdx.x;
  const int bm = blockIdx.x * BM;
  const int sel = blockIdx.y >> 3;
  const int bn = (blockIdx.y & 7) * BN;
  const u16* __restrict__ W = sel ? W1 : W0;
  const float* __restrict__ bias = sel ? bias1 : bias0;
  u16* __restrict__ outp = sel ? out1 : out0;
  const int w = tid >> 6;
  const int l = tid & 63;
  const int r16 = l & 15;
  const int k8 = (l >> 4) << 3;

  ffrag acc[2][4];
#pragma unroll
  for (int i = 0; i < 2; ++i)
#pragma unroll
    for (int j = 0; j < 4; ++j) acc[i][j] = (ffrag)0.0f;

  for (int kt = 0; kt < 256; kt += BK) {
#pragma unroll
    for (int c = 0; c < 4; ++c) {
      int ch = tid + 256 * c;
      int row = ch >> 3, c8 = (ch & 7) << 3;
      *(uint4*)&As[row * LDT + c8] =
          *(const uint4*)&A[(size_t)(bm + row) * 256 + kt + c8];
    }
#pragma unroll
    for (int c = 0; c < 2; ++c) {
      int ch = tid + 256 * c;
      int row = ch >> 3, c8 = (ch & 7) << 3;
      *(uint4*)&Ws[row * LDT + c8] =
          *(const uint4*)&W[(size_t)(bn + row) * 256 + kt + c8];
    }
    __syncthreads();
#pragma unroll
    for (int kk = 0; kk < 2; ++kk) {
      bfrag af[2], wf[4];
#pragma unroll
      for (int fm = 0; fm < 2; ++fm)
        af[fm] = *(const bfrag*)&As[(w * 32 + fm * 16 + r16) * LDT + kk * 32 + k8];
#pragma unroll
      for (int fn = 0; fn < 4; ++fn)
        wf[fn] = *(const bfrag*)&Ws[(fn * 16 + r16) * LDT + kk * 32 + k8];
#pragma unroll
      for (int fm = 0; fm < 2; ++fm)
#pragma unroll
        for (int fn = 0; fn < 4; ++fn)
          acc[fm][fn] = __builtin_amdgcn_mfma_f32_16x16x32_bf16(
              af[fm], wf[fn], acc[fm][fn], 0, 0, 0);
    }
    __syncthreads();
  }
  const int rbase = (l >> 4) * 4;  // C/D: col = lane&15, row = (lane>>4)*4 + reg
#pragma unroll
  for (int fm = 0; fm < 2; ++fm)
#pragma unroll
    for (int fn = 0; fn < 4; ++fn) {
      int np = bn + fn * 16 + r16;          // permuted col index n' = j*4 + g
      int g = np & 3, jc = np >> 2;
      float bv = bias[g * 128 + jc];
      int row0 = bm + w * 32 + fm * 16 + rbase;   // 4 consecutive b, same t
      int t = row0 >> 6, bq = (row0 & 63) >> 2;
      size_t base = ((size_t)t * 16 + bq) * 2048 + (size_t)jc * 16 + g;
#pragma unroll
      for (int r = 0; r < 4; ++r)
        outp[base + 4 * r] = f2b(acc[fm][fn][r] + bv);
    }
}

// ---------------- MFMA LSTM v5: 4 batches/WG, 32 WGs, batch-as-M ----------
// Batch q lives at A/D row 4q (rows != 0 mod 4 are zero), so after MFMA
// every lane (q,jw) holds batch q's 4 gate values for j=16w+jw in acc[g][0]:
// EW is 1 cell/lane across all 64 lanes, no redistribution. Whh resident in
// VGPRs (B-operand). h double-buffered in LDS with (row<<3) XOR swizzle.
// xp loads: one uint2/lane/step, prefetch distance 4; out-stores deferred
// one step; lds_barrier never drains vmcnt -> loads/stores span steps.
__global__ __launch_bounds__(512, 1) void k_lstm5(const u16* __restrict__ xpf,
                                                  const u16* __restrict__ xpb,
                                                  const float* __restrict__ whhf,
                                                  const float* __restrict__ whhb,
                                                  u16* __restrict__ out) {
  __shared__ u16 hbuf[2 * 16 * 128];   // 8 KB: [buf][row][col ^ (row<<3)]
  const int dir = blockIdx.x >> 4;
  const int wg = blockIdx.x & 15;      // batch quad: b = 4*wg + q
  const u16* __restrict__ xp = dir ? xpb : xpf;
  const float* __restrict__ whh = dir ? whhb : whhf;
  const int tid = threadIdx.x;
  const int w = tid >> 6;
  const int l = tid & 63;
  const int q = l >> 4;
  const int jw = l & 15;
  const int j = 16 * w + jw;

  for (int i = tid; i < 2 * 16 * 128; i += 512) hbuf[i] = 0;

  // B-operand fragments: Whh row = g*128 + j, k-slice = ks*32 + q*8 .. +8
  bfrag wf[4][4];
#pragma unroll
  for (int g = 0; g < 4; ++g) {
    const float* rowp = whh + (size_t)(g * 128 + j) * 128;
#pragma unroll
    for (int ks = 0; ks < 4; ++ks) {
      float4 x0 = ((const float4*)(rowp + ks * 32 + q * 8))[0];
      float4 x1 = ((const float4*)(rowp + ks * 32 + q * 8))[1];
      bfrag t;
      t[0] = (short)f2b(x0.x); t[1] = (short)f2b(x0.y);
      t[2] = (short)f2b(x0.z); t[3] = (short)f2b(x0.w);
      t[4] = (short)f2b(x1.x); t[5] = (short)f2b(x1.y);
      t[6] = (short)f2b(x1.z); t[7] = (short)f2b(x1.w);
      wf[g][ks] = t;
    }
  }
  __syncthreads();

  const int dt = dir ? -1 : 1;
  int tp = dir ? (Tt - 1) : 0;
  // xp flat: (t*16 + wg)*2048 + j*16 + q*4 (+g)
  const size_t xoff = (size_t)wg * 2048 + (size_t)j * 16 + (size_t)q * 4;
  float cc = 0.f;
  int cur = 0;
  u16 hprev = 0;
  size_t oprev = 0;

  uint2 xv[4];
#pragma unroll
  for (int d = 0; d < 4; ++d)
    xv[d] = *(const uint2*)&xp[(size_t)(tp + d * dt) * 32768 + xoff];

  for (int it = 0; it < Tt / 4; ++it) {
#pragma unroll
    for (int d = 0; d < 4; ++d) {
      // deferred out-store of previous step's h (private; crosses barriers)
      if (it > 0 || d > 0) out[oprev] = hprev;

      // MFMA: A = h (batch q at row 4q), B = Whh rows
      ffrag a0 = (ffrag)0.f, a1 = (ffrag)0.f, a2 = (ffrag)0.f, a3 = (ffrag)0.f;
      const u16* hb = hbuf + cur * 2048;
#pragma unroll
      for (int ks = 0; ks < 4; ++ks) {
        bfrag hf = *(const bfrag*)&hb[jw * 128 + ((ks * 32 + q * 8) ^ (jw << 3))];
        a0 = __builtin_amdgcn_mfma_f32_16x16x32_bf16(hf, wf[0][ks], a0, 0, 0, 0);
        a1 = __builtin_amdgcn_mfma_f32_16x16x32_bf16(hf, wf[1][ks], a1, 0, 0, 0);
        a2 = __builtin_amdgcn_mfma_f32_16x16x32_bf16(hf, wf[2][ks], a2, 0, 0, 0);
        a3 = __builtin_amdgcn_mfma_f32_16x16x32_bf16(hf, wf[3][ks], a3, 0, 0, 0);
      }

      // EW: one cell per lane (batch 4wg+q, unit j)
      float gi = a0[0] + b2f((u16)xv[d].x);
      float gf = a1[0] + b2f((u16)(xv[d].x >> 16));
      float gg = a2[0] + b2f((u16)xv[d].y);
      float go = a3[0] + b2f((u16)(xv[d].y >> 16));
      cc = sigmoidf_(gf) * cc + sigmoidf_(gi) * tanhf_(gg);
      float h = sigmoidf_(go) * tanhf_(cc);
      u16 hv = f2b(h);

      // publish h(next): row 4q, col j, swizzle col ^ (row<<3)
      hbuf[(cur ^ 1) * 2048 + (4 * q) * 128 + (j ^ (q << 5))] = hv;
      hprev = hv;
      oprev = ((size_t)tp * 64 + 4 * wg + q) * 256 + (size_t)dir * 128 + j;

      // prefetch xp for t+4 (clamped; tail loads unused)
      int tpre = tp + 4 * dt;
      if (tpre < 0 || tpre > Tt - 1) tpre = tp;
      xv[d] = *(const uint2*)&xp[(size_t)tpre * 32768 + xoff];

      lds_barrier();
      cur ^= 1;
      tp += dt;
    }
  }
  out[oprev] = hprev;
}

// ---------------- FC: emissions = out1 @ fcW^T + fcb (fp32 out) -----------
__global__ __launch_bounds__(256) void k_fc(const u16* __restrict__ Aa,
                                            const u16* __restrict__ Wc,
                                            const float* __restrict__ bias,
                                            float* __restrict__ emis) {
  constexpr int LDW = 260;
  __shared__ u16 As[8 * 256];
  __shared__ u16 Ws[32 * LDW];
  int tid = threadIdx.x;
  int row0 = blockIdx.x * 8;
  *(uint4*)&As[tid * 8] = *(const uint4*)&Aa[(size_t)row0 * 256 + tid * 8];
#pragma unroll
  for (int cfc = 0; cfc < 8; ++cfc) {
    int ch = tid + 256 * cfc;
    int row = ch >> 6, c4 = (ch & 63) << 2;
    *(uint2*)&Ws[row * LDW + c4] = *(const uint2*)&Wc[row * 256 + c4];
  }
  __syncthreads();
  int r = tid >> 5, cj = tid & 31;
  const u16* ap = &As[r * 256];
  const u16* wp = &Ws[cj * LDW];
  float s0 = 0.f, s1 = 0.f;
#pragma unroll
  for (int k2 = 0; k2 < 128; ++k2) {
    u32 av = *(const u32*)&ap[k2 * 2];
    u32 wv = *(const u32*)&wp[k2 * 2];
    s0 += b2f((u16)av) * b2f((u16)wv);
    s1 += b2f((u16)(av >> 16)) * b2f((u16)(wv >> 16));
  }
  emis[(size_t)(row0 + r) * Kk + cj] = s0 + s1 + bias[cj];
}

// ---------------- CRF (emissions t-major: row = t*64 + b) -----------------
__global__ __launch_bounds__(64) void k_crf(const float* __restrict__ emis,
                                            const int* __restrict__ tags,
                                            const float* __restrict__ trans,
                                            const float* __restrict__ startv,
                                            const float* __restrict__ endv,
                                            float* __restrict__ nll) {
  __shared__ float alpha[Kk];
  __shared__ float tr[Kk * Kk];
  const int b = blockIdx.x;
  const int l = threadIdx.x;
  const int j = l & 31;
  const int half = l >> 5;
  for (int i = l; i < Kk * Kk; i += 64) tr[i] = trans[i];
  const float* eb = emis + (size_t)b * Kk;   // stride per t = 64*Kk
  if (l < Kk) alpha[l] = startv[l] + eb[l];
  __syncthreads();
  for (int t = 1; t < Tt; ++t) {
    float v[16];
    float m = -1e30f;
#pragma unroll
    for (int i = 0; i < 16; ++i) {
      int ii = half * 16 + i;
      v[i] = alpha[ii] + tr[ii * Kk + j];
      m = fmaxf(m, v[i]);
    }
    float s = 0.f;
#pragma unroll
    for (int i = 0; i < 16; ++i) s += __expf(v[i] - m);
    float m2 = __shfl_xor(m, 32);
    float s2 = __shfl_xor(s, 32);
    float M = fmaxf(m, m2);
    s = s * __expf(m - M) + s2 * __expf(m2 - M);
    float na = eb[(size_t)t * (64 * Kk) + j] + M + __logf(s);
    __syncthreads();
    if (l < Kk) alpha[l] = na;
    __syncthreads();
  }
  float val = (l < Kk) ? alpha[l] + endv[l] : -1e30f;
  float M = val;
#pragma unroll
  for (int off = 32; off > 0; off >>= 1) M = fmaxf(M, __shfl_xor(M, off));
  float sz = (l < Kk) ? __expf(val - M) : 0.f;
#pragma unroll
  for (int off = 32; off > 0; off >>= 1) sz += __shfl_xor(sz, off);
  float logZ = M + __logf(sz);

  const int* tg = tags + (size_t)b * Tt;
  float g = 0.f;
  for (int t = l; t < Tt; t += 64) {
    int cur = tg[t];
    g += eb[(size_t)t * (64 * Kk) + cur];
    if (t >= 1) g += tr[cur * Kk + tg[t - 1]];
  }
#pragma unroll
  for (int off = 32; off > 0; off >>= 1) g += __shfl_xor(g, off);
  if (l == 0) {
    g += startv[tg[0]] + endv[tg[Tt - 1]];
    nll[b] = logZ - g;
  }
}

__global__ void k_reduce(const float* __restrict__ nll, float* __restrict__ out) {
  float v = nll[threadIdx.x];
#pragma unroll
  for (int off = 32; off > 0; off >>= 1) v += __shfl_xor(v, off);
  if (threadIdx.x == 0) out[0] = v * (1.0f / 64.0f);
}

// --------------------------------------------------------------------------
extern "C" void kernel_launch(void* const* d_in, const int* in_sizes, int n_in,
                              void* d_out, int out_size, void* d_ws, size_t ws_size,
                              hipStream_t stream) {
  (void)in_sizes; (void)n_in; (void)out_size; (void)ws_size;
  const int*   x      = (const int*)d_in[0];
  const int*   tags   = (const int*)d_in[2];
  const float* emb    = (const float*)d_in[4];
  const float* Wih0f  = (const float*)d_in[5];
  const float* Whh0f  = (const float*)d_in[6];
  const float* b0f    = (const float*)d_in[7];
  const float* Wih0b  = (const float*)d_in[8];
  const float* Whh0b  = (const float*)d_in[9];
  const float* b0b    = (const float*)d_in[10];
  const float* Wih1f  = (const float*)d_in[11];
  const float* Whh1f  = (const float*)d_in[12];
  const float* b1f    = (const float*)d_in[13];
  const float* Wih1b  = (const float*)d_in[14];
  const float* Whh1b  = (const float*)d_in[15];
  const float* b1b    = (const float*)d_in[16];
  const float* fcW    = (const float*)d_in[17];
  const float* fcb    = (const float*)d_in[18];
  const float* trans  = (const float*)d_in[19];
  const float* startv = (const float*)d_in[20];
  const float* endv   = (const float*)d_in[21];

  char* p = (char*)d_ws;
  u16* buf0 = (u16*)p; p += (size_t)BT * Ee * 2;   // embeddings / layer-1 out
  u16* buf1 = (u16*)p; p += (size_t)BT * 256 * 2;  // layer-0 out
  u16* xpf  = (u16*)p; p += (size_t)BT * G4 * 2;   // fwd proj (lstm layout)
  u16* xpb  = (u16*)p; p += (size_t)BT * G4 * 2;   // bwd proj (lstm layout)
  u16* wb[4];
  for (int i = 0; i < 4; ++i) { wb[i] = (u16*)p; p += (size_t)512 * 256 * 2; }
  u16* fcwb = (u16*)p; p += (size_t)32 * 256 * 2;
  float* emis = (float*)p; p += (size_t)BT * Kk * 4;
  float* nll  = (float*)p; p += 256;

  k_embed<<<dim3(BT / 4), dim3(256), 0, stream>>>(x, emb, buf0);

  const float* wsrc[4] = {Wih0f, Wih0b, Wih1f, Wih1b};
  for (int i = 0; i < 4; ++i)
    k_castW<<<dim3(128), dim3(256), 0, stream>>>(wsrc[i], wb[i]);
  k_cast<<<dim3(8), dim3(256), 0, stream>>>(fcW, fcwb, 32 * 256 / 4);

  dim3 ggrid(BT / 128, 16);
  // layer 0
  k_gemm2<<<ggrid, dim3(256), 0, stream>>>(buf0, wb[0], wb[1], b0f, b0b, xpf, xpb);
  k_lstm5<<<dim3(32), dim3(512), 0, stream>>>(xpf, xpb, Whh0f, Whh0b, buf1);
  // layer 1
  k_gemm2<<<ggrid, dim3(256), 0, stream>>>(buf1, wb[2], wb[3], b1f, b1b, xpf, xpb);
  k_lstm5<<<dim3(32), dim3(512), 0, stream>>>(xpf, xpb, Whh1f, Whh1b, buf0);
  // emissions + CRF
  k_fc<<<dim3(BT / 8), dim3(256), 0, stream>>>(buf0, fcwb, fcb, emis);
  k_crf<<<dim3(Bb), dim3(64), 0, stream>>>(emis, tags, trans, startv, endv, nll);
  k_reduce<<<dim3(1), dim3(64), 0, stream>>>(nll, (float*)d_out);
}

// Round 6
// 1067.228 us; speedup vs baseline: 2.0848x; 1.0206x over previous
//
#include <hip/hip_runtime.h>
#include <stddef.h>

typedef unsigned short u16;
typedef unsigned int u32;

#define DEV __device__ __forceinline__

constexpr int Bb = 64;
constexpr int Tt = 512;
constexpr int Ee = 256;     // embedding dim == 2H (layer-1 input dim)
constexpr int Hh = 128;
constexpr int Kk = 32;
constexpr int G4 = 4 * Hh;  // 512 gates
constexpr int BT = Bb * Tt; // 32768 rows

DEV u16 f2b(float f) {
  u32 u = __builtin_bit_cast(u32, f);
  u += 0x7fffu + ((u >> 16) & 1u);   // round-to-nearest-even
  return (u16)(u >> 16);
}
DEV float b2f(u16 v) { return __builtin_bit_cast(float, (u32)v << 16); }
DEV float sigmoidf_(float x) { return 1.0f / (1.0f + __expf(-x)); }
DEV float tanhf_(float x) { return 1.0f - 2.0f / (1.0f + __expf(2.0f * x)); }

// LDS-only barrier: does NOT drain vmcnt, so global prefetch loads and
// h-stores stay in flight across steps (T4: never vmcnt(0) in the loop).
DEV void lds_barrier() {
  asm volatile("s_waitcnt lgkmcnt(0)" ::: "memory");
  __builtin_amdgcn_sched_barrier(0);
  __builtin_amdgcn_s_barrier();
  __builtin_amdgcn_sched_barrier(0);
}

// ---------------- embedding lookup + cast to bf16 (t-major rows) ----------
__global__ __launch_bounds__(256) void k_embed(const int* __restrict__ x,
                                               const float* __restrict__ emb,
                                               u16* __restrict__ out) {
  int m = blockIdx.x * 4 + (threadIdx.x >> 6);  // out row = t*64 + b
  int lane = threadIdx.x & 63;
  int b = m & 63, t = m >> 6;
  int idx = x[b * Tt + t];
  float4 v = ((const float4*)(emb + (size_t)idx * Ee))[lane];
  uint2 p;
  p.x = (u32)f2b(v.x) | ((u32)f2b(v.y) << 16);
  p.y = (u32)f2b(v.z) | ((u32)f2b(v.w) << 16);
  ((uint2*)(out + (size_t)m * Ee))[lane] = p;
}

// ---------------- generic f32 -> bf16 cast --------------------------------
__global__ void k_cast(const float* __restrict__ s, u16* __restrict__ d, int n4) {
  int i = blockIdx.x * blockDim.x + threadIdx.x;
  if (i < n4) {
    float4 v = ((const float4*)s)[i];
    uint2 p;
    p.x = (u32)f2b(v.x) | ((u32)f2b(v.y) << 16);
    p.y = (u32)f2b(v.z) | ((u32)f2b(v.w) << 16);
    ((uint2*)d)[i] = p;
  }
}

// ---------------- Wih cast with row permutation n' = j*4 + g --------------
__global__ __launch_bounds__(256) void k_castW(const float* __restrict__ s,
                                               u16* __restrict__ d) {
  int i = blockIdx.x * 256 + threadIdx.x;  // 32768 = 512 rows x 64 float4
  int np = i >> 6, k4 = i & 63;
  int src = (np & 3) * 128 + (np >> 2);
  float4 v = ((const float4*)(s + (size_t)src * 256))[k4];
  uint2 p;
  p.x = (u32)f2b(v.x) | ((u32)f2b(v.y) << 16);
  p.y = (u32)f2b(v.z) | ((u32)f2b(v.w) << 16);
  ((uint2*)(d + (size_t)np * 256))[k4] = p;
}

// ---------------- MFMA GEMM (NT), fwd+bwd fused, lstm-layout epilogue -----
// Output element (t,b,g,j) at flat = (t*16 + b/4)*2048 + j*16 + (b&3)*4 + g
typedef __attribute__((ext_vector_type(8))) short bfrag;
typedef __attribute__((ext_vector_type(4))) float ffrag;

__global__ __launch_bounds__(256) void k_gemm2(const u16* __restrict__ A,
                                               const u16* __restrict__ W0,
                                               const u16* __restrict__ W1,
                                               const float* __restrict__ bias0,
                                               const float* __restrict__ bias1,
                                               u16* __restrict__ out0,
                                               u16* __restrict__ out1) {
  constexpr int BM = 128, BN = 64, BK = 64, LDT = 72;
  __shared__ u16 As[BM * LDT];
  __shared__ u16 Ws[BN * LDT];
  const int tid = threadIdx.x;
  const int bm = blockIdx.x * BM;
  const int sel = blockIdx.y >> 3;
  const int bn = (blockIdx.y & 7) * BN;
  const u16* __restrict__ W = sel ? W1 : W0;
  const float* __restrict__ bias = sel ? bias1 : bias0;
  u16* __restrict__ outp = sel ? out1 : out0;
  const int w = tid >> 6;
  const int l = tid & 63;
  const int r16 = l & 15;
  const int k8 = (l >> 4) << 3;

  ffrag acc[2][4];
#pragma unroll
  for (int i = 0; i < 2; ++i)
#pragma unroll
    for (int j = 0; j < 4; ++j) acc[i][j] = (ffrag)0.0f;

  for (int kt = 0; kt < 256; kt += BK) {
#pragma unroll
    for (int c = 0; c < 4; ++c) {
      int ch = tid + 256 * c;
      int row = ch >> 3, c8 = (ch & 7) << 3;
      *(uint4*)&As[row * LDT + c8] =
          *(const uint4*)&A[(size_t)(bm + row) * 256 + kt + c8];
    }
#pragma unroll
    for (int c = 0; c < 2; ++c) {
      int ch = tid + 256 * c;
      int row = ch >> 3, c8 = (ch & 7) << 3;
      *(uint4*)&Ws[row * LDT + c8] =
          *(const uint4*)&W[(size_t)(bn + row) * 256 + kt + c8];
    }
    __syncthreads();
#pragma unroll
    for (int kk = 0; kk < 2; ++kk) {
      bfrag af[2], wf[4];
#pragma unroll
      for (int fm = 0; fm < 2; ++fm)
        af[fm] = *(const bfrag*)&As[(w * 32 + fm * 16 + r16) * LDT + kk * 32 + k8];
#pragma unroll
      for (int fn = 0; fn < 4; ++fn)
        wf[fn] = *(const bfrag*)&Ws[(fn * 16 + r16) * LDT + kk * 32 + k8];
#pragma unroll
      for (int fm = 0; fm < 2; ++fm)
#pragma unroll
        for (int fn = 0; fn < 4; ++fn)
          acc[fm][fn] = __builtin_amdgcn_mfma_f32_16x16x32_bf16(
              af[fm], wf[fn], acc[fm][fn], 0, 0, 0);
    }
    __syncthreads();
  }
  const int rbase = (l >> 4) * 4;  // C/D: col = lane&15, row = (lane>>4)*4 + reg
#pragma unroll
  for (int fm = 0; fm < 2; ++fm)
#pragma unroll
    for (int fn = 0; fn < 4; ++fn) {
      int np = bn + fn * 16 + r16;          // permuted col index n' = j*4 + g
      int g = np & 3, jc = np >> 2;
      float bv = bias[g * 128 + jc];
      int row0 = bm + w * 32 + fm * 16 + rbase;   // 4 consecutive b, same t
      int t = row0 >> 6, bq = (row0 & 63) >> 2;
      size_t base = ((size_t)t * 16 + bq) * 2048 + (size_t)jc * 16 + g;
#pragma unroll
      for (int r = 0; r < 4; ++r)
        outp[base + 4 * r] = f2b(acc[fm][fn][r] + bv);
    }
}

// ---------------- MFMA LSTM v6: 4 waves, 4 batches/WG, 32 WGs -------------
// Wave w covers gate-cols j in [32w, 32w+32) (8 tiles = 4 gates x 2 j-sub).
// Halves the duplicated per-wave h-read vs 8 waves (16 KB/step LDS total).
// Batch q at A/D row 4q; lane (q,jw) gets cells (q, j0=32w+jw), (q, j0+16)
// in acc[*][0] -> EW in-register, 2 cells/lane, all lanes active.
// Whh resident in VGPRs; h double-buffered in LDS (col ^ (row<<3) swizzle).
// xp: 2 uint2/lane/step, prefetch distance 4 across non-draining barriers.
__global__ __launch_bounds__(256, 1) void k_lstm6(const u16* __restrict__ xpf,
                                                  const u16* __restrict__ xpb,
                                                  const float* __restrict__ whhf,
                                                  const float* __restrict__ whhb,
                                                  u16* __restrict__ out) {
  __shared__ u16 hbuf[2 * 16 * 128];   // 8 KB
  const int dir = blockIdx.x >> 4;
  const int wg = blockIdx.x & 15;      // batch quad: b = 4*wg + q
  const u16* __restrict__ xp = dir ? xpb : xpf;
  const float* __restrict__ whh = dir ? whhb : whhf;
  const int tid = threadIdx.x;
  const int w = tid >> 6;
  const int l = tid & 63;
  const int q = l >> 4;
  const int jw = l & 15;
  const int j0 = 32 * w + jw;
  const int j1 = j0 + 16;

  for (int i = tid; i < 2 * 16 * 128; i += 256) hbuf[i] = 0;

  // B-operand: wf[t8][ks], t8 = g*2+sj, row = g*128 + 32w + sj*16 + jw
  bfrag wf[8][4];
#pragma unroll
  for (int g = 0; g < 4; ++g)
#pragma unroll
    for (int sj = 0; sj < 2; ++sj) {
      const float* rowp = whh + (size_t)(g * 128 + 32 * w + sj * 16 + jw) * 128;
#pragma unroll
      for (int ks = 0; ks < 4; ++ks) {
        float4 x0 = ((const float4*)(rowp + ks * 32 + q * 8))[0];
        float4 x1 = ((const float4*)(rowp + ks * 32 + q * 8))[1];
        bfrag t;
        t[0] = (short)f2b(x0.x); t[1] = (short)f2b(x0.y);
        t[2] = (short)f2b(x0.z); t[3] = (short)f2b(x0.w);
        t[4] = (short)f2b(x1.x); t[5] = (short)f2b(x1.y);
        t[6] = (short)f2b(x1.z); t[7] = (short)f2b(x1.w);
        wf[g * 2 + sj][ks] = t;
      }
    }
  __syncthreads();

  const int dt = dir ? -1 : 1;
  int tp = dir ? (Tt - 1) : 0;
  // xp flat: (t*16 + wg)*2048 + j*16 + q*4 (+g)
  const size_t xoff = (size_t)wg * 2048 + (size_t)j0 * 16 + (size_t)q * 4;
  float cc0 = 0.f, cc1 = 0.f;
  int cur = 0;
  u16 hp0 = 0, hp1 = 0;
  size_t oprev = 0;

  uint2 xv0[4], xv1[4];
#pragma unroll
  for (int d = 0; d < 4; ++d) {
    size_t o = (size_t)(tp + d * dt) * 32768 + xoff;
    xv0[d] = *(const uint2*)&xp[o];
    xv1[d] = *(const uint2*)&xp[o + 256];
  }

  for (int it = 0; it < Tt / 4; ++it) {
#pragma unroll
    for (int d = 0; d < 4; ++d) {
      // deferred out-store of previous step's h (private; crosses barriers)
      if (it > 0 || d > 0) { out[oprev] = hp0; out[oprev + 16] = hp1; }

      // MFMA: A = h (batch q at row 4q), B = Whh rows
      ffrag acc[8];
#pragma unroll
      for (int t8 = 0; t8 < 8; ++t8) acc[t8] = (ffrag)0.f;
      const u16* hb = hbuf + cur * 2048;
#pragma unroll
      for (int ks = 0; ks < 4; ++ks) {
        bfrag hf = *(const bfrag*)&hb[jw * 128 + ((ks * 32 + q * 8) ^ (jw << 3))];
#pragma unroll
        for (int t8 = 0; t8 < 8; ++t8)
          acc[t8] = __builtin_amdgcn_mfma_f32_16x16x32_bf16(hf, wf[t8][ks], acc[t8], 0, 0, 0);
      }

      // EW: 2 cells/lane (batch 4wg+q; j0 and j1)
      float gi0 = acc[0][0] + b2f((u16)xv0[d].x);
      float gf0 = acc[2][0] + b2f((u16)(xv0[d].x >> 16));
      float gg0 = acc[4][0] + b2f((u16)xv0[d].y);
      float go0 = acc[6][0] + b2f((u16)(xv0[d].y >> 16));
      cc0 = sigmoidf_(gf0) * cc0 + sigmoidf_(gi0) * tanhf_(gg0);
      float h0 = sigmoidf_(go0) * tanhf_(cc0);
      float gi1 = acc[1][0] + b2f((u16)xv1[d].x);
      float gf1 = acc[3][0] + b2f((u16)(xv1[d].x >> 16));
      float gg1 = acc[5][0] + b2f((u16)xv1[d].y);
      float go1 = acc[7][0] + b2f((u16)(xv1[d].y >> 16));
      cc1 = sigmoidf_(gf1) * cc1 + sigmoidf_(gi1) * tanhf_(cc1 * 0.f + gg1);
      float h1 = sigmoidf_(go1) * tanhf_(cc1);
      u32 p01;
      asm("v_cvt_pk_bf16_f32 %0, %1, %2" : "=v"(p01) : "v"(h0), "v"(h1));
      u16 hv0 = (u16)p01, hv1 = (u16)(p01 >> 16);

      // publish h(next): row 4q, col j, swizzle col ^ (row<<3) = col ^ (q<<5)
      u16* hw = hbuf + (cur ^ 1) * 2048 + (4 * q) * 128;
      hw[j0 ^ (q << 5)] = hv0;
      hw[j1 ^ (q << 5)] = hv1;
      hp0 = hv0; hp1 = hv1;
      oprev = ((size_t)tp * 64 + 4 * wg + q) * 256 + (size_t)dir * 128 + j0;

      // prefetch xp for t+4 (clamped; tail loads unused)
      int tpre = tp + 4 * dt;
      if (tpre < 0 || tpre > Tt - 1) tpre = tp;
      size_t op = (size_t)tpre * 32768 + xoff;
      xv0[d] = *(const uint2*)&xp[op];
      xv1[d] = *(const uint2*)&xp[op + 256];

      lds_barrier();
      cur ^= 1;
      tp += dt;
    }
  }
  out[oprev] = hp0; out[oprev + 16] = hp1;
}

// ---------------- FC: emissions = out1 @ fcW^T + fcb (fp32 out) -----------
__global__ __launch_bounds__(256) void k_fc(const u16* __restrict__ Aa,
                                            const u16* __restrict__ Wc,
                                            const float* __restrict__ bias,
                                            float* __restrict__ emis) {
  constexpr int LDW = 260;
  __shared__ u16 As[8 * 256];
  __shared__ u16 Ws[32 * LDW];
  int tid = threadIdx.x;
  int row0 = blockIdx.x * 8;
  *(uint4*)&As[tid * 8] = *(const uint4*)&Aa[(size_t)row0 * 256 + tid * 8];
#pragma unroll
  for (int cfc = 0; cfc < 8; ++cfc) {
    int ch = tid + 256 * cfc;
    int row = ch >> 6, c4 = (ch & 63) << 2;
    *(uint2*)&Ws[row * LDW + c4] = *(const uint2*)&Wc[row * 256 + c4];
  }
  __syncthreads();
  int r = tid >> 5, cj = tid & 31;
  const u16* ap = &As[r * 256];
  const u16* wp = &Ws[cj * LDW];
  float s0 = 0.f, s1 = 0.f;
#pragma unroll
  for (int k2 = 0; k2 < 128; ++k2) {
    u32 av = *(const u32*)&ap[k2 * 2];
    u32 wv = *(const u32*)&wp[k2 * 2];
    s0 += b2f((u16)av) * b2f((u16)wv);
    s1 += b2f((u16)(av >> 16)) * b2f((u16)(wv >> 16));
  }
  emis[(size_t)(row0 + r) * Kk + cj] = s0 + s1 + bias[cj];
}

// ---------------- CRF v2: alpha + trans-slice in registers ----------------
// Lane (half, j): tr_r[i] = trans[(half*16+i)*32 + j]; alpha replicated via
// 16 shfl broadcasts per step (no LDS round-trip, no barriers in the loop).
// Emissions prefetched depth-1 (emis buffer has one padded extra row).
__global__ __launch_bounds__(64) void k_crf(const float* __restrict__ emis,
                                            const int* __restrict__ tags,
                                            const float* __restrict__ trans,
                                            const float* __restrict__ startv,
                                            const float* __restrict__ endv,
                                            float* __restrict__ nll) {
  __shared__ float tr[Kk * Kk];
  const int b = blockIdx.x;
  const int l = threadIdx.x;
  const int j = l & 31;
  const int half = l >> 5;
  for (int i = l; i < Kk * Kk; i += 64) tr[i] = trans[i];
  float tr_r[16];
#pragma unroll
  for (int i = 0; i < 16; ++i) tr_r[i] = trans[(half * 16 + i) * Kk + j];
  const float* eb = emis + (size_t)b * Kk;   // stride per t = 64*Kk = 2048
  float aj = startv[j] + eb[j];
  float alpha_r[16];
#pragma unroll
  for (int i = 0; i < 16; ++i) alpha_r[i] = __shfl(aj, half * 16 + i);
  float ebc = eb[2048 + j];
  __syncthreads();

  for (int t = 1; t < Tt; ++t) {
    float ebn = eb[(size_t)(t + 1) * 2048 + j];  // t+1==512 hits pad row
    float v[16];
#pragma unroll
    for (int i = 0; i < 16; ++i) v[i] = alpha_r[i] + tr_r[i];
    float m = v[0];
#pragma unroll
    for (int i = 1; i < 16; ++i) m = fmaxf(m, v[i]);
    float s = 0.f;
#pragma unroll
    for (int i = 0; i < 16; ++i) s += __expf(v[i] - m);
    float m2 = __shfl_xor(m, 32);
    float s2 = __shfl_xor(s, 32);
    float M = fmaxf(m, m2);
    s = s * __expf(m - M) + s2 * __expf(m2 - M);
    aj = ebc + M + __logf(s);
#pragma unroll
    for (int i = 0; i < 16; ++i) alpha_r[i] = __shfl(aj, half * 16 + i);
    ebc = ebn;
  }

  float val = aj + endv[j];           // both halves hold identical val(j)
  float M = val;
#pragma unroll
  for (int off = 16; off > 0; off >>= 1) M = fmaxf(M, __shfl_xor(M, off));
  float sz = __expf(val - M);
#pragma unroll
  for (int off = 16; off > 0; off >>= 1) sz += __shfl_xor(sz, off);
  float logZ = M + __logf(sz);        // valid within each 32-lane group

  const int* tg = tags + (size_t)b * Tt;
  float g = 0.f;
  for (int t = l; t < Tt; t += 64) {
    int cur = tg[t];
    g += eb[(size_t)t * 2048 + cur];
    if (t >= 1) g += tr[cur * Kk + tg[t - 1]];
  }
#pragma unroll
  for (int off = 32; off > 0; off >>= 1) g += __shfl_xor(g, off);
  if (l == 0) {
    g += startv[tg[0]] + endv[tg[Tt - 1]];
    nll[b] = logZ - g;
  }
}

__global__ void k_reduce(const float* __restrict__ nll, float* __restrict__ out) {
  float v = nll[threadIdx.x];
#pragma unroll
  for (int off = 32; off > 0; off >>= 1) v += __shfl_xor(v, off);
  if (threadIdx.x == 0) out[0] = v * (1.0f / 64.0f);
}

// --------------------------------------------------------------------------
extern "C" void kernel_launch(void* const* d_in, const int* in_sizes, int n_in,
                              void* d_out, int out_size, void* d_ws, size_t ws_size,
                              hipStream_t stream) {
  (void)in_sizes; (void)n_in; (void)out_size; (void)ws_size;
  const int*   x      = (const int*)d_in[0];
  const int*   tags   = (const int*)d_in[2];
  const float* emb    = (const float*)d_in[4];
  const float* Wih0f  = (const float*)d_in[5];
  const float* Whh0f  = (const float*)d_in[6];
  const float* b0f    = (const float*)d_in[7];
  const float* Wih0b  = (const float*)d_in[8];
  const float* Whh0b  = (const float*)d_in[9];
  const float* b0b    = (const float*)d_in[10];
  const float* Wih1f  = (const float*)d_in[11];
  const float* Whh1f  = (const float*)d_in[12];
  const float* b1f    = (const float*)d_in[13];
  const float* Wih1b  = (const float*)d_in[14];
  const float* Whh1b  = (const float*)d_in[15];
  const float* b1b    = (const float*)d_in[16];
  const float* fcW    = (const float*)d_in[17];
  const float* fcb    = (const float*)d_in[18];
  const float* trans  = (const float*)d_in[19];
  const float* startv = (const float*)d_in[20];
  const float* endv   = (const float*)d_in[21];

  char* p = (char*)d_ws;
  u16* buf0 = (u16*)p; p += (size_t)BT * Ee * 2;   // embeddings / layer-1 out
  u16* buf1 = (u16*)p; p += (size_t)BT * 256 * 2;  // layer-0 out
  u16* xpf  = (u16*)p; p += (size_t)BT * G4 * 2;   // fwd proj (lstm layout)
  u16* xpb  = (u16*)p; p += (size_t)BT * G4 * 2;   // bwd proj (lstm layout)
  u16* wb[4];
  for (int i = 0; i < 4; ++i) { wb[i] = (u16*)p; p += (size_t)512 * 256 * 2; }
  u16* fcwb = (u16*)p; p += (size_t)32 * 256 * 2;
  float* emis = (float*)p; p += ((size_t)BT * Kk + 64 * Kk) * 4;  // +1 pad row
  float* nll  = (float*)p; p += 256;

  k_embed<<<dim3(BT / 4), dim3(256), 0, stream>>>(x, emb, buf0);

  const float* wsrc[4] = {Wih0f, Wih0b, Wih1f, Wih1b};
  for (int i = 0; i < 4; ++i)
    k_castW<<<dim3(128), dim3(256), 0, stream>>>(wsrc[i], wb[i]);
  k_cast<<<dim3(8), dim3(256), 0, stream>>>(fcW, fcwb, 32 * 256 / 4);

  dim3 ggrid(BT / 128, 16);
  // layer 0
  k_gemm2<<<ggrid, dim3(256), 0, stream>>>(buf0, wb[0], wb[1], b0f, b0b, xpf, xpb);
  k_lstm6<<<dim3(32), dim3(256), 0, stream>>>(xpf, xpb, Whh0f, Whh0b, buf1);
  // layer 1
  k_gemm2<<<ggrid, dim3(256), 0, stream>>>(buf1, wb[2], wb[3], b1f, b1b, xpf, xpb);
  k_lstm6<<<dim3(32), dim3(256), 0, stream>>>(xpf, xpb, Whh1f, Whh1b, buf0);
  // emissions + CRF
  k_fc<<<dim3(BT / 8), dim3(256), 0, stream>>>(buf0, fcwb, fcb, emis);
  k_crf<<<dim3(Bb), dim3(64), 0, stream>>>(emis, tags, trans, startv, endv, nll);
  k_reduce<<<dim3(1), dim3(64), 0, stream>>>(nll, (float*)d_out);
}

// Round 7
// 1021.045 us; speedup vs baseline: 2.1791x; 1.0452x over previous
//
#include <hip/hip_runtime.h>
#include <stddef.h>

typedef unsigned short u16;
typedef unsigned int u32;

#define DEV __device__ __forceinline__

constexpr int Bb = 64;
constexpr int Tt = 512;
constexpr int Ee = 256;     // embedding dim == 2H (layer-1 input dim)
constexpr int Hh = 128;
constexpr int Kk = 32;
constexpr int G4 = 4 * Hh;  // 512 gates
constexpr int BT = Bb * Tt; // 32768 rows

DEV u16 f2b(float f) {
  u32 u = __builtin_bit_cast(u32, f);
  u += 0x7fffu + ((u >> 16) & 1u);   // round-to-nearest-even
  return (u16)(u >> 16);
}
DEV float b2f(u16 v) { return __builtin_bit_cast(float, (u32)v << 16); }
DEV float sigmoidf_(float x) { return 1.0f / (1.0f + __expf(-x)); }
DEV float tanhf_(float x) { return 1.0f - 2.0f / (1.0f + __expf(2.0f * x)); }

// LDS-only barrier: does NOT drain vmcnt, so global prefetch loads and
// h-stores stay in flight across steps (T4: never vmcnt(0) in the loop).
DEV void lds_barrier() {
  asm volatile("s_waitcnt lgkmcnt(0)" ::: "memory");
  __builtin_amdgcn_sched_barrier(0);
  __builtin_amdgcn_s_barrier();
  __builtin_amdgcn_sched_barrier(0);
}

// ---------------- embedding lookup + cast to bf16 (t-major rows) ----------
__global__ __launch_bounds__(256) void k_embed(const int* __restrict__ x,
                                               const float* __restrict__ emb,
                                               u16* __restrict__ out) {
  int m = blockIdx.x * 4 + (threadIdx.x >> 6);  // out row = t*64 + b
  int lane = threadIdx.x & 63;
  int b = m & 63, t = m >> 6;
  int idx = x[b * Tt + t];
  float4 v = ((const float4*)(emb + (size_t)idx * Ee))[lane];
  uint2 p;
  p.x = (u32)f2b(v.x) | ((u32)f2b(v.y) << 16);
  p.y = (u32)f2b(v.z) | ((u32)f2b(v.w) << 16);
  ((uint2*)(out + (size_t)m * Ee))[lane] = p;
}

// ---------------- generic f32 -> bf16 cast --------------------------------
__global__ void k_cast(const float* __restrict__ s, u16* __restrict__ d, int n4) {
  int i = blockIdx.x * blockDim.x + threadIdx.x;
  if (i < n4) {
    float4 v = ((const float4*)s)[i];
    uint2 p;
    p.x = (u32)f2b(v.x) | ((u32)f2b(v.y) << 16);
    p.y = (u32)f2b(v.z) | ((u32)f2b(v.w) << 16);
    ((uint2*)d)[i] = p;
  }
}

// ---------------- Wih cast with row permutation n' = j*4 + g --------------
__global__ __launch_bounds__(256) void k_castW(const float* __restrict__ s,
                                               u16* __restrict__ d) {
  int i = blockIdx.x * 256 + threadIdx.x;  // 32768 = 512 rows x 64 float4
  int np = i >> 6, k4 = i & 63;
  int src = (np & 3) * 128 + (np >> 2);
  float4 v = ((const float4*)(s + (size_t)src * 256))[k4];
  uint2 p;
  p.x = (u32)f2b(v.x) | ((u32)f2b(v.y) << 16);
  p.y = (u32)f2b(v.z) | ((u32)f2b(v.w) << 16);
  ((uint2*)(d + (size_t)np * 256))[k4] = p;
}

// ---------------- MFMA GEMM (NT), fwd+bwd fused, lstm-layout epilogue -----
// Output element (t,b,g,j) at flat = (t*16 + b/4)*2048 + j*16 + (b&3)*4 + g
typedef __attribute__((ext_vector_type(8))) short bfrag;
typedef __attribute__((ext_vector_type(4))) float ffrag;

__global__ __launch_bounds__(256) void k_gemm2(const u16* __restrict__ A,
                                               const u16* __restrict__ W0,
                                               const u16* __restrict__ W1,
                                               const float* __restrict__ bias0,
                                               const float* __restrict__ bias1,
                                               u16* __restrict__ out0,
                                               u16* __restrict__ out1) {
  constexpr int BM = 128, BN = 64, BK = 64, LDT = 72;
  __shared__ u16 As[BM * LDT];
  __shared__ u16 Ws[BN * LDT];
  const int tid = threadIdx.x;
  const int bm = blockIdx.x * BM;
  const int sel = blockIdx.y >> 3;
  const int bn = (blockIdx.y & 7) * BN;
  const u16* __restrict__ W = sel ? W1 : W0;
  const float* __restrict__ bias = sel ? bias1 : bias0;
  u16* __restrict__ outp = sel ? out1 : out0;
  const int w = tid >> 6;
  const int l = tid & 63;
  const int r16 = l & 15;
  const int k8 = (l >> 4) << 3;

  ffrag acc[2][4];
#pragma unroll
  for (int i = 0; i < 2; ++i)
#pragma unroll
    for (int j = 0; j < 4; ++j) acc[i][j] = (ffrag)0.0f;

  for (int kt = 0; kt < 256; kt += BK) {
#pragma unroll
    for (int c = 0; c < 4; ++c) {
      int ch = tid + 256 * c;
      int row = ch >> 3, c8 = (ch & 7) << 3;
      *(uint4*)&As[row * LDT + c8] =
          *(const uint4*)&A[(size_t)(bm + row) * 256 + kt + c8];
    }
#pragma unroll
    for (int c = 0; c < 2; ++c) {
      int ch = tid + 256 * c;
      int row = ch >> 3, c8 = (ch & 7) << 3;
      *(uint4*)&Ws[row * LDT + c8] =
          *(const uint4*)&W[(size_t)(bn + row) * 256 + kt + c8];
    }
    __syncthreads();
#pragma unroll
    for (int kk = 0; kk < 2; ++kk) {
      bfrag af[2], wf[4];
#pragma unroll
      for (int fm = 0; fm < 2; ++fm)
        af[fm] = *(const bfrag*)&As[(w * 32 + fm * 16 + r16) * LDT + kk * 32 + k8];
#pragma unroll
      for (int fn = 0; fn < 4; ++fn)
        wf[fn] = *(const bfrag*)&Ws[(fn * 16 + r16) * LDT + kk * 32 + k8];
#pragma unroll
      for (int fm = 0; fm < 2; ++fm)
#pragma unroll
        for (int fn = 0; fn < 4; ++fn)
          acc[fm][fn] = __builtin_amdgcn_mfma_f32_16x16x32_bf16(
              af[fm], wf[fn], acc[fm][fn], 0, 0, 0);
    }
    __syncthreads();
  }
  const int rbase = (l >> 4) * 4;  // C/D: col = lane&15, row = (lane>>4)*4 + reg
#pragma unroll
  for (int fm = 0; fm < 2; ++fm)
#pragma unroll
    for (int fn = 0; fn < 4; ++fn) {
      int np = bn + fn * 16 + r16;          // permuted col index n' = j*4 + g
      int g = np & 3, jc = np >> 2;
      float bv = bias[g * 128 + jc];
      int row0 = bm + w * 32 + fm * 16 + rbase;   // 4 consecutive b, same t
      int t = row0 >> 6, bq = (row0 & 63) >> 2;
      size_t base = ((size_t)t * 16 + bq) * 2048 + (size_t)jc * 16 + g;
#pragma unroll
      for (int r = 0; r < 4; ++r)
        outp[base + 4 * r] = f2b(acc[fm][fn][r] + bv);
    }
}

// ---------------- MFMA LSTM v7: 8 waves, 4 batches/WG, 32 WGs -------------
// Dense h in LDS: 4 rows x 128 bf16 (0.5 KB/buf). A-rows are batch-indexed
// (batch q at MFMA row 4q); D-row m depends only on A-row m, so lanes with
// jw&3 != 0 supply garbage A-rows that are never read -> only 16/64 lanes
// perform ds_reads (4x less LDS traffic). 16 independent zero-C MFMAs per
// wave (no acc dep chain); gate value = sum of 4 [0]-elements.
__global__ __launch_bounds__(512, 1) void k_lstm7(const u16* __restrict__ xpf,
                                                  const u16* __restrict__ xpb,
                                                  const float* __restrict__ whhf,
                                                  const float* __restrict__ whhb,
                                                  u16* __restrict__ out) {
  __shared__ u16 hbuf[2][4][128];     // dense; byte ^= (row&1)<<6 swizzle
  const int dir = blockIdx.x >> 4;
  const int wg = blockIdx.x & 15;     // batch quad: b = 4*wg + q
  const u16* __restrict__ xp = dir ? xpb : xpf;
  const float* __restrict__ whh = dir ? whhb : whhf;
  const int tid = threadIdx.x;
  const int w = tid >> 6;
  const int l = tid & 63;
  const int q = l >> 4;
  const int jw = l & 15;
  const int j = 16 * w + jw;

  for (int i = tid; i < 2 * 4 * 128; i += 512) (&hbuf[0][0][0])[i] = 0;

  // B-operand fragments: Whh row = g*128 + j, k-slice = ks*32 + q*8 .. +8
  bfrag wf[4][4];
#pragma unroll
  for (int g = 0; g < 4; ++g) {
    const float* rowp = whh + (size_t)(g * 128 + j) * 128;
#pragma unroll
    for (int ks = 0; ks < 4; ++ks) {
      float4 x0 = ((const float4*)(rowp + ks * 32 + q * 8))[0];
      float4 x1 = ((const float4*)(rowp + ks * 32 + q * 8))[1];
      bfrag t;
      t[0] = (short)f2b(x0.x); t[1] = (short)f2b(x0.y);
      t[2] = (short)f2b(x0.z); t[3] = (short)f2b(x0.w);
      t[4] = (short)f2b(x1.x); t[5] = (short)f2b(x1.y);
      t[6] = (short)f2b(x1.z); t[7] = (short)f2b(x1.w);
      wf[g][ks] = t;
    }
  }
  __syncthreads();

  const int dt = dir ? -1 : 1;
  int tp = dir ? (Tt - 1) : 0;
  // xp flat: (t*16 + wg)*2048 + j*16 + q*4 (+g)
  const size_t xoff = (size_t)wg * 2048 + (size_t)j * 16 + (size_t)q * 4;
  float cc = 0.f;
  int cur = 0;
  u16 hprev = 0;
  size_t oprev = 0;

  // A-frag loader lanes: jw&3==0, dense row d = jw>>2 (= the batch whose
  // h-row this lane supplies). Others keep stale regs (harmless rows).
  const int ld_act = ((jw & 3) == 0);
  const int drow = jw >> 2;
  const int rsw = (drow & 1) << 5;          // u16-index XOR (64B)
  bfrag hf0 = (bfrag)(short)0, hf1 = (bfrag)(short)0;
  bfrag hf2 = (bfrag)(short)0, hf3 = (bfrag)(short)0;
  const int wsw = (q & 1) << 5;             // write-side swizzle

  uint2 xv[4];
#pragma unroll
  for (int d = 0; d < 4; ++d)
    xv[d] = *(const uint2*)&xp[(size_t)(tp + d * dt) * 32768 + xoff];

  for (int it = 0; it < Tt / 4; ++it) {
#pragma unroll
    for (int d = 0; d < 4; ++d) {
      // deferred out-store of previous step's h (private; crosses barriers)
      if (it > 0 || d > 0) out[oprev] = hprev;

      // masked dense A-frag read (16 lanes active)
      if (ld_act) {
        const u16* hb = &hbuf[cur][drow][0];
        hf0 = *(const bfrag*)&hb[(0 * 32 + q * 8) ^ rsw];
        hf1 = *(const bfrag*)&hb[(1 * 32 + q * 8) ^ rsw];
        hf2 = *(const bfrag*)&hb[(2 * 32 + q * 8) ^ rsw];
        hf3 = *(const bfrag*)&hb[(3 * 32 + q * 8) ^ rsw];
      }

      // 16 independent zero-C MFMAs; gate = sum of element [0] over ks
      ffrag a00 = __builtin_amdgcn_mfma_f32_16x16x32_bf16(hf0, wf[0][0], (ffrag)0.f, 0, 0, 0);
      ffrag a01 = __builtin_amdgcn_mfma_f32_16x16x32_bf16(hf1, wf[0][1], (ffrag)0.f, 0, 0, 0);
      ffrag a02 = __builtin_amdgcn_mfma_f32_16x16x32_bf16(hf2, wf[0][2], (ffrag)0.f, 0, 0, 0);
      ffrag a03 = __builtin_amdgcn_mfma_f32_16x16x32_bf16(hf3, wf[0][3], (ffrag)0.f, 0, 0, 0);
      ffrag a10 = __builtin_amdgcn_mfma_f32_16x16x32_bf16(hf0, wf[1][0], (ffrag)0.f, 0, 0, 0);
      ffrag a11 = __builtin_amdgcn_mfma_f32_16x16x32_bf16(hf1, wf[1][1], (ffrag)0.f, 0, 0, 0);
      ffrag a12 = __builtin_amdgcn_mfma_f32_16x16x32_bf16(hf2, wf[1][2], (ffrag)0.f, 0, 0, 0);
      ffrag a13 = __builtin_amdgcn_mfma_f32_16x16x32_bf16(hf3, wf[1][3], (ffrag)0.f, 0, 0, 0);
      ffrag a20 = __builtin_amdgcn_mfma_f32_16x16x32_bf16(hf0, wf[2][0], (ffrag)0.f, 0, 0, 0);
      ffrag a21 = __builtin_amdgcn_mfma_f32_16x16x32_bf16(hf1, wf[2][1], (ffrag)0.f, 0, 0, 0);
      ffrag a22 = __builtin_amdgcn_mfma_f32_16x16x32_bf16(hf2, wf[2][2], (ffrag)0.f, 0, 0, 0);
      ffrag a23 = __builtin_amdgcn_mfma_f32_16x16x32_bf16(hf3, wf[2][3], (ffrag)0.f, 0, 0, 0);
      ffrag a30 = __builtin_amdgcn_mfma_f32_16x16x32_bf16(hf0, wf[3][0], (ffrag)0.f, 0, 0, 0);
      ffrag a31 = __builtin_amdgcn_mfma_f32_16x16x32_bf16(hf1, wf[3][1], (ffrag)0.f, 0, 0, 0);
      ffrag a32 = __builtin_amdgcn_mfma_f32_16x16x32_bf16(hf2, wf[3][2], (ffrag)0.f, 0, 0, 0);
      ffrag a33 = __builtin_amdgcn_mfma_f32_16x16x32_bf16(hf3, wf[3][3], (ffrag)0.f, 0, 0, 0);

      float gi = (a00[0] + a01[0]) + (a02[0] + a03[0]) + b2f((u16)xv[d].x);
      float gf = (a10[0] + a11[0]) + (a12[0] + a13[0]) + b2f((u16)(xv[d].x >> 16));
      float gg = (a20[0] + a21[0]) + (a22[0] + a23[0]) + b2f((u16)xv[d].y);
      float go = (a30[0] + a31[0]) + (a32[0] + a33[0]) + b2f((u16)(xv[d].y >> 16));
      cc = sigmoidf_(gf) * cc + sigmoidf_(gi) * tanhf_(gg);
      float h = sigmoidf_(go) * tanhf_(cc);
      u16 hv = f2b(h);

      // publish h(next): dense row q, col j ^ ((q&1)<<5)
      hbuf[cur ^ 1][q][j ^ wsw] = hv;
      hprev = hv;
      oprev = ((size_t)tp * 64 + 4 * wg + q) * 256 + (size_t)dir * 128 + j;

      // prefetch xp for t+4 (clamped; tail loads unused)
      int tpre = tp + 4 * dt;
      if (tpre < 0 || tpre > Tt - 1) tpre = tp;
      xv[d] = *(const uint2*)&xp[(size_t)tpre * 32768 + xoff];

      lds_barrier();
      cur ^= 1;
      tp += dt;
    }
  }
  out[oprev] = hprev;
}

// ---------------- FC: emissions = out1 @ fcW^T + fcb (fp32 out) -----------
__global__ __launch_bounds__(256) void k_fc(const u16* __restrict__ Aa,
                                            const u16* __restrict__ Wc,
                                            const float* __restrict__ bias,
                                            float* __restrict__ emis) {
  constexpr int LDW = 260;
  __shared__ u16 As[8 * 256];
  __shared__ u16 Ws[32 * LDW];
  int tid = threadIdx.x;
  int row0 = blockIdx.x * 8;
  *(uint4*)&As[tid * 8] = *(const uint4*)&Aa[(size_t)row0 * 256 + tid * 8];
#pragma unroll
  for (int cfc = 0; cfc < 8; ++cfc) {
    int ch = tid + 256 * cfc;
    int row = ch >> 6, c4 = (ch & 63) << 2;
    *(uint2*)&Ws[row * LDW + c4] = *(const uint2*)&Wc[row * 256 + c4];
  }
  __syncthreads();
  int r = tid >> 5, cj = tid & 31;
  const u16* ap = &As[r * 256];
  const u16* wp = &Ws[cj * LDW];
  float s0 = 0.f, s1 = 0.f;
#pragma unroll
  for (int k2 = 0; k2 < 128; ++k2) {
    u32 av = *(const u32*)&ap[k2 * 2];
    u32 wv = *(const u32*)&wp[k2 * 2];
    s0 += b2f((u16)av) * b2f((u16)wv);
    s1 += b2f((u16)(av >> 16)) * b2f((u16)(wv >> 16));
  }
  emis[(size_t)(row0 + r) * Kk + cj] = s0 + s1 + bias[cj];
}

// ---------------- CRF v3: register alpha + tree reductions ----------------
__global__ __launch_bounds__(64) void k_crf(const float* __restrict__ emis,
                                            const int* __restrict__ tags,
                                            const float* __restrict__ trans,
                                            const float* __restrict__ startv,
                                            const float* __restrict__ endv,
                                            float* __restrict__ nll) {
  __shared__ float tr[Kk * Kk];
  const int b = blockIdx.x;
  const int l = threadIdx.x;
  const int j = l & 31;
  const int half = l >> 5;
  for (int i = l; i < Kk * Kk; i += 64) tr[i] = trans[i];
  float tr_r[16];
#pragma unroll
  for (int i = 0; i < 16; ++i) tr_r[i] = trans[(half * 16 + i) * Kk + j];
  const float* eb = emis + (size_t)b * Kk;   // stride per t = 64*Kk = 2048
  float aj = startv[j] + eb[j];
  float alpha_r[16];
#pragma unroll
  for (int i = 0; i < 16; ++i) alpha_r[i] = __shfl(aj, half * 16 + i);
  float ebc = eb[2048 + j];
  __syncthreads();

  for (int t = 1; t < Tt; ++t) {
    float ebn = eb[(size_t)(t + 1) * 2048 + j];  // t+1==512 hits pad row
    float v[16];
#pragma unroll
    for (int i = 0; i < 16; ++i) v[i] = alpha_r[i] + tr_r[i];
    // tree max (depth 4)
    float m8[8], m4[4], m2[2], m;
#pragma unroll
    for (int i = 0; i < 8; ++i) m8[i] = fmaxf(v[i], v[i + 8]);
#pragma unroll
    for (int i = 0; i < 4; ++i) m4[i] = fmaxf(m8[i], m8[i + 4]);
    m2[0] = fmaxf(m4[0], m4[2]); m2[1] = fmaxf(m4[1], m4[3]);
    m = fmaxf(m2[0], m2[1]);
    float e[16];
#pragma unroll
    for (int i = 0; i < 16; ++i) e[i] = __expf(v[i] - m);
    // tree sum (depth 4)
    float s8[8], s4[4], s;
#pragma unroll
    for (int i = 0; i < 8; ++i) s8[i] = e[i] + e[i + 8];
#pragma unroll
    for (int i = 0; i < 4; ++i) s4[i] = s8[i] + s8[i + 4];
    s = (s4[0] + s4[1]) + (s4[2] + s4[3]);
    float m2x = __shfl_xor(m, 32);
    float s2x = __shfl_xor(s, 32);
    float M = fmaxf(m, m2x);
    s = s * __expf(m - M) + s2x * __expf(m2x - M);
    aj = ebc + M + __logf(s);
#pragma unroll
    for (int i = 0; i < 16; ++i) alpha_r[i] = __shfl(aj, half * 16 + i);
    ebc = ebn;
  }

  float val = aj + endv[j];           // both halves hold identical val(j)
  float M = val;
#pragma unroll
  for (int off = 16; off > 0; off >>= 1) M = fmaxf(M, __shfl_xor(M, off));
  float sz = __expf(val - M);
#pragma unroll
  for (int off = 16; off > 0; off >>= 1) sz += __shfl_xor(sz, off);
  float logZ = M + __logf(sz);        // valid within each 32-lane group

  const int* tg = tags + (size_t)b * Tt;
  float g = 0.f;
  for (int t = l; t < Tt; t += 64) {
    int cur = tg[t];
    g += eb[(size_t)t * 2048 + cur];
    if (t >= 1) g += tr[cur * Kk + tg[t - 1]];
  }
#pragma unroll
  for (int off = 32; off > 0; off >>= 1) g += __shfl_xor(g, off);
  if (l == 0) {
    g += startv[tg[0]] + endv[tg[Tt - 1]];
    nll[b] = logZ - g;
  }
}

__global__ void k_reduce(const float* __restrict__ nll, float* __restrict__ out) {
  float v = nll[threadIdx.x];
#pragma unroll
  for (int off = 32; off > 0; off >>= 1) v += __shfl_xor(v, off);
  if (threadIdx.x == 0) out[0] = v * (1.0f / 64.0f);
}

// --------------------------------------------------------------------------
extern "C" void kernel_launch(void* const* d_in, const int* in_sizes, int n_in,
                              void* d_out, int out_size, void* d_ws, size_t ws_size,
                              hipStream_t stream) {
  (void)in_sizes; (void)n_in; (void)out_size; (void)ws_size;
  const int*   x      = (const int*)d_in[0];
  const int*   tags   = (const int*)d_in[2];
  const float* emb    = (const float*)d_in[4];
  const float* Wih0f  = (const float*)d_in[5];
  const float* Whh0f  = (const float*)d_in[6];
  const float* b0f    = (const float*)d_in[7];
  const float* Wih0b  = (const float*)d_in[8];
  const float* Whh0b  = (const float*)d_in[9];
  const float* b0b    = (const float*)d_in[10];
  const float* Wih1f  = (const float*)d_in[11];
  const float* Whh1f  = (const float*)d_in[12];
  const float* b1f    = (const float*)d_in[13];
  const float* Wih1b  = (const float*)d_in[14];
  const float* Whh1b  = (const float*)d_in[15];
  const float* b1b    = (const float*)d_in[16];
  const float* fcW    = (const float*)d_in[17];
  const float* fcb    = (const float*)d_in[18];
  const float* trans  = (const float*)d_in[19];
  const float* startv = (const float*)d_in[20];
  const float* endv   = (const float*)d_in[21];

  char* p = (char*)d_ws;
  u16* buf0 = (u16*)p; p += (size_t)BT * Ee * 2;   // embeddings / layer-1 out
  u16* buf1 = (u16*)p; p += (size_t)BT * 256 * 2;  // layer-0 out
  u16* xpf  = (u16*)p; p += (size_t)BT * G4 * 2;   // fwd proj (lstm layout)
  u16* xpb  = (u16*)p; p += (size_t)BT * G4 * 2;   // bwd proj (lstm layout)
  u16* wb[4];
  for (int i = 0; i < 4; ++i) { wb[i] = (u16*)p; p += (size_t)512 * 256 * 2; }
  u16* fcwb = (u16*)p; p += (size_t)32 * 256 * 2;
  float* emis = (float*)p; p += ((size_t)BT * Kk + 64 * Kk) * 4;  // +1 pad row
  float* nll  = (float*)p; p += 256;

  k_embed<<<dim3(BT / 4), dim3(256), 0, stream>>>(x, emb, buf0);

  const float* wsrc[4] = {Wih0f, Wih0b, Wih1f, Wih1b};
  for (int i = 0; i < 4; ++i)
    k_castW<<<dim3(128), dim3(256), 0, stream>>>(wsrc[i], wb[i]);
  k_cast<<<dim3(8), dim3(256), 0, stream>>>(fcW, fcwb, 32 * 256 / 4);

  dim3 ggrid(BT / 128, 16);
  // layer 0
  k_gemm2<<<ggrid, dim3(256), 0, stream>>>(buf0, wb[0], wb[1], b0f, b0b, xpf, xpb);
  k_lstm7<<<dim3(32), dim3(512), 0, stream>>>(xpf, xpb, Whh0f, Whh0b, buf1);
  // layer 1
  k_gemm2<<<ggrid, dim3(256), 0, stream>>>(buf1, wb[2], wb[3], b1f, b1b, xpf, xpb);
  k_lstm7<<<dim3(32), dim3(512), 0, stream>>>(xpf, xpb, Whh1f, Whh1b, buf0);
  // emissions + CRF
  k_fc<<<dim3(BT / 8), dim3(256), 0, stream>>>(buf0, fcwb, fcb, emis);
  k_crf<<<dim3(Bb), dim3(64), 0, stream>>>(emis, tags, trans, startv, endv, nll);
  k_reduce<<<dim3(1), dim3(64), 0, stream>>>(nll, (float*)d_out);
}

// Round 8
// 993.736 us; speedup vs baseline: 2.2389x; 1.0275x over previous
//
#include <hip/hip_runtime.h>
#include <stddef.h>

typedef unsigned short u16;
typedef unsigned int u32;

#define DEV __device__ __forceinline__

constexpr int Bb = 64;
constexpr int Tt = 512;
constexpr int Ee = 256;     // embedding dim == 2H (layer-1 input dim)
constexpr int Hh = 128;
constexpr int Kk = 32;
constexpr int G4 = 4 * Hh;  // 512 gates
constexpr int BT = Bb * Tt; // 32768 rows

DEV u16 f2b(float f) {
  u32 u = __builtin_bit_cast(u32, f);
  u += 0x7fffu + ((u >> 16) & 1u);   // round-to-nearest-even
  return (u16)(u >> 16);
}
DEV float b2f(u16 v) { return __builtin_bit_cast(float, (u32)v << 16); }
DEV float sigmoidf_(float x) { return 1.0f / (1.0f + __expf(-x)); }
DEV float tanhf_(float x) { return 1.0f - 2.0f / (1.0f + __expf(2.0f * x)); }

// LDS-only barrier: does NOT drain vmcnt, so global prefetch loads and
// h-stores stay in flight across steps (T4: never vmcnt(0) in the loop).
DEV void lds_barrier() {
  asm volatile("s_waitcnt lgkmcnt(0)" ::: "memory");
  __builtin_amdgcn_sched_barrier(0);
  __builtin_amdgcn_s_barrier();
  __builtin_amdgcn_sched_barrier(0);
}

// ---------------- embedding lookup + cast to bf16 (t-major rows) ----------
__global__ __launch_bounds__(256) void k_embed(const int* __restrict__ x,
                                               const float* __restrict__ emb,
                                               u16* __restrict__ out) {
  int m = blockIdx.x * 4 + (threadIdx.x >> 6);  // out row = t*64 + b
  int lane = threadIdx.x & 63;
  int b = m & 63, t = m >> 6;
  int idx = x[b * Tt + t];
  float4 v = ((const float4*)(emb + (size_t)idx * Ee))[lane];
  uint2 p;
  p.x = (u32)f2b(v.x) | ((u32)f2b(v.y) << 16);
  p.y = (u32)f2b(v.z) | ((u32)f2b(v.w) << 16);
  ((uint2*)(out + (size_t)m * Ee))[lane] = p;
}

// ---------------- generic f32 -> bf16 cast --------------------------------
__global__ void k_cast(const float* __restrict__ s, u16* __restrict__ d, int n4) {
  int i = blockIdx.x * blockDim.x + threadIdx.x;
  if (i < n4) {
    float4 v = ((const float4*)s)[i];
    uint2 p;
    p.x = (u32)f2b(v.x) | ((u32)f2b(v.y) << 16);
    p.y = (u32)f2b(v.z) | ((u32)f2b(v.w) << 16);
    ((uint2*)d)[i] = p;
  }
}

// ---------------- Wih cast with row permutation n' = j*4 + g --------------
__global__ __launch_bounds__(256) void k_castW(const float* __restrict__ s,
                                               u16* __restrict__ d) {
  int i = blockIdx.x * 256 + threadIdx.x;  // 32768 = 512 rows x 64 float4
  int np = i >> 6, k4 = i & 63;
  int src = (np & 3) * 128 + (np >> 2);
  float4 v = ((const float4*)(s + (size_t)src * 256))[k4];
  uint2 p;
  p.x = (u32)f2b(v.x) | ((u32)f2b(v.y) << 16);
  p.y = (u32)f2b(v.z) | ((u32)f2b(v.w) << 16);
  ((uint2*)(d + (size_t)np * 256))[k4] = p;
}

// ---------------- MFMA GEMM (NT), 128x128 tile, lstm-layout epilogue ------
// A: (32768,256) bf16 t-major; W: permuted rows (n' = j*4+g), 512x256.
// Output element (t,b,g,j) at flat = (t*16 + b/4)*2048 + j*16 + (b&3)*4 + g
typedef __attribute__((ext_vector_type(8))) short bfrag;
typedef __attribute__((ext_vector_type(4))) float ffrag;

__global__ __launch_bounds__(256) void k_gemm3(const u16* __restrict__ A,
                                               const u16* __restrict__ W0,
                                               const u16* __restrict__ W1,
                                               const float* __restrict__ bias0,
                                               const float* __restrict__ bias1,
                                               u16* __restrict__ out0,
                                               u16* __restrict__ out1) {
  constexpr int BM = 128, BN = 128, BK = 64, LDT = 72;
  __shared__ u16 As[BM * LDT];
  __shared__ u16 Ws[BN * LDT];
  const int tid = threadIdx.x;
  const int bm = blockIdx.x * BM;
  const int sel = blockIdx.y >> 2;
  const int bn = (blockIdx.y & 3) * BN;
  const u16* __restrict__ W = sel ? W1 : W0;
  const float* __restrict__ bias = sel ? bias1 : bias0;
  u16* __restrict__ outp = sel ? out1 : out0;
  const int w = tid >> 6;
  const int l = tid & 63;
  const int r16 = l & 15;
  const int k8 = (l >> 4) << 3;
  const int wr = (w >> 1) * 64;   // wave row quadrant
  const int wc = (w & 1) * 64;    // wave col quadrant

  ffrag acc[4][4];
#pragma unroll
  for (int i = 0; i < 4; ++i)
#pragma unroll
    for (int jn = 0; jn < 4; ++jn) acc[i][jn] = (ffrag)0.0f;

  for (int kt = 0; kt < 256; kt += BK) {
#pragma unroll
    for (int c = 0; c < 4; ++c) {   // A tile: 128x64 = 1024 16B chunks
      int ch = tid + 256 * c;
      int row = ch >> 3, c8 = (ch & 7) << 3;
      *(uint4*)&As[row * LDT + c8] =
          *(const uint4*)&A[(size_t)(bm + row) * 256 + kt + c8];
    }
#pragma unroll
    for (int c = 0; c < 4; ++c) {   // W tile: 128x64 = 1024 chunks
      int ch = tid + 256 * c;
      int row = ch >> 3, c8 = (ch & 7) << 3;
      *(uint4*)&Ws[row * LDT + c8] =
          *(const uint4*)&W[(size_t)(bn + row) * 256 + kt + c8];
    }
    __syncthreads();
#pragma unroll
    for (int kk = 0; kk < 2; ++kk) {
      bfrag af[4], wf[4];
#pragma unroll
      for (int fm = 0; fm < 4; ++fm)
        af[fm] = *(const bfrag*)&As[(wr + fm * 16 + r16) * LDT + kk * 32 + k8];
#pragma unroll
      for (int fn = 0; fn < 4; ++fn)
        wf[fn] = *(const bfrag*)&Ws[(wc + fn * 16 + r16) * LDT + kk * 32 + k8];
#pragma unroll
      for (int fm = 0; fm < 4; ++fm)
#pragma unroll
        for (int fn = 0; fn < 4; ++fn)
          acc[fm][fn] = __builtin_amdgcn_mfma_f32_16x16x32_bf16(
              af[fm], wf[fn], acc[fm][fn], 0, 0, 0);
    }
    __syncthreads();
  }
  const int rbase = (l >> 4) * 4;  // C/D: col = lane&15, row = (lane>>4)*4 + reg
#pragma unroll
  for (int fm = 0; fm < 4; ++fm)
#pragma unroll
    for (int fn = 0; fn < 4; ++fn) {
      int np = bn + wc + fn * 16 + r16;     // permuted col index n' = j*4 + g
      int g = np & 3, jc = np >> 2;
      float bv = bias[g * 128 + jc];
      int row0 = bm + wr + fm * 16 + rbase; // 4 consecutive b, same t
      int t = row0 >> 6, bq = (row0 & 63) >> 2;
      size_t base = ((size_t)t * 16 + bq) * 2048 + (size_t)jc * 16 + g;
#pragma unroll
      for (int r = 0; r < 4; ++r)
        outp[base + 4 * r] = f2b(acc[fm][fn][r] + bv);
    }
}

// ---------------- MFMA LSTM v8: 8 waves, 4 batches/WG, 32 WGs -------------
// Dense h[2][4][128] in LDS (batch q at MFMA A/D row 4q; other rows garbage,
// never consumed). 16 loader lanes (jw&3==0) do the 4 masked ds_read_b128.
// CHAINED MFMA accumulation (4 independent gate chains, no scalar adds).
// Incremental pointers; prefetch distance 4, unclamped (tail loads land in
// adjacent workspace, values unused). One non-draining barrier per step.
__global__ __launch_bounds__(512, 1) void k_lstm8(const u16* __restrict__ xpf,
                                                  const u16* __restrict__ xpb,
                                                  const float* __restrict__ whhf,
                                                  const float* __restrict__ whhb,
                                                  u16* __restrict__ out) {
  __shared__ u16 hbuf[2][4][128];     // dense; idx ^= (row&1)<<5 swizzle
  const int dir = blockIdx.x >> 4;
  const int wg = blockIdx.x & 15;     // batch quad: b = 4*wg + q
  const u16* __restrict__ xp = dir ? xpb : xpf;
  const float* __restrict__ whh = dir ? whhb : whhf;
  const int tid = threadIdx.x;
  const int w = tid >> 6;
  const int l = tid & 63;
  const int q = l >> 4;
  const int jw = l & 15;
  const int j = 16 * w + jw;

  for (int i = tid; i < 2 * 4 * 128; i += 512) (&hbuf[0][0][0])[i] = 0;

  // B-operand fragments: Whh row = g*128 + j, k-slice = ks*32 + q*8 .. +8
  bfrag wf[4][4];
#pragma unroll
  for (int g = 0; g < 4; ++g) {
    const float* rowp = whh + (size_t)(g * 128 + j) * 128;
#pragma unroll
    for (int ks = 0; ks < 4; ++ks) {
      float4 x0 = ((const float4*)(rowp + ks * 32 + q * 8))[0];
      float4 x1 = ((const float4*)(rowp + ks * 32 + q * 8))[1];
      bfrag t;
      t[0] = (short)f2b(x0.x); t[1] = (short)f2b(x0.y);
      t[2] = (short)f2b(x0.z); t[3] = (short)f2b(x0.w);
      t[4] = (short)f2b(x1.x); t[5] = (short)f2b(x1.y);
      t[6] = (short)f2b(x1.z); t[7] = (short)f2b(x1.w);
      wf[g][ks] = t;
    }
  }
  __syncthreads();

  const int dt = dir ? -1 : 1;
  const int tp0 = dir ? (Tt - 1) : 0;
  // xp flat: (t*16 + wg)*2048 + j*16 + q*4 (+g)
  const size_t xoff = (size_t)wg * 2048 + (size_t)j * 16 + (size_t)q * 4;
  float cc = 0.f;
  int cur = 0;
  u16 hprev = 0;

  // loader lanes: jw&3==0 supply dense row drow = jw>>2 (batch drow's h).
  const bool ld_act = ((jw & 3) == 0);
  const int drow = jw >> 2;
  const int rsw = (drow & 1) << 5;          // read-side 64B XOR (u16 idx)
  const int wsw = (q & 1) << 5;             // write-side swizzle
  bfrag hf0 = (bfrag)(short)0, hf1 = (bfrag)(short)0;
  bfrag hf2 = (bfrag)(short)0, hf3 = (bfrag)(short)0;

  uint2 xv[4];
#pragma unroll
  for (int d = 0; d < 4; ++d)
    xv[d] = *(const uint2*)&xp[(size_t)(tp0 + d * dt) * 32768 + xoff];

  const ptrdiff_t xstep = (ptrdiff_t)dt * 32768;
  const u16* pxq = xp + (size_t)(tp0 + 4 * dt) * 32768 + xoff;   // prefetch ptr
  u16* optr = out + ((size_t)tp0 * 64 + 4 * wg + q) * 256 + (size_t)dir * 128 + j;
  const ptrdiff_t ostep = (ptrdiff_t)dt * 16384;

  for (int it = 0; it < Tt / 4; ++it) {
#pragma unroll
    for (int d = 0; d < 4; ++d) {
      // deferred out-store of previous step's h (private; crosses barriers)
      if (it > 0 || d > 0) { *optr = hprev; optr += ostep; }

      // masked dense A-frag read (16 lanes active)
      if (ld_act) {
        const u16* hb = &hbuf[cur][drow][0];
        hf0 = *(const bfrag*)&hb[(0 * 32 + q * 8) ^ rsw];
        hf1 = *(const bfrag*)&hb[(1 * 32 + q * 8) ^ rsw];
        hf2 = *(const bfrag*)&hb[(2 * 32 + q * 8) ^ rsw];
        hf3 = *(const bfrag*)&hb[(3 * 32 + q * 8) ^ rsw];
      }

      // chained MFMA: 4 independent gate chains, 4 k-steps each
      ffrag a0 = __builtin_amdgcn_mfma_f32_16x16x32_bf16(hf0, wf[0][0], (ffrag)0.f, 0, 0, 0);
      ffrag a1 = __builtin_amdgcn_mfma_f32_16x16x32_bf16(hf0, wf[1][0], (ffrag)0.f, 0, 0, 0);
      ffrag a2 = __builtin_amdgcn_mfma_f32_16x16x32_bf16(hf0, wf[2][0], (ffrag)0.f, 0, 0, 0);
      ffrag a3 = __builtin_amdgcn_mfma_f32_16x16x32_bf16(hf0, wf[3][0], (ffrag)0.f, 0, 0, 0);
      a0 = __builtin_amdgcn_mfma_f32_16x16x32_bf16(hf1, wf[0][1], a0, 0, 0, 0);
      a1 = __builtin_amdgcn_mfma_f32_16x16x32_bf16(hf1, wf[1][1], a1, 0, 0, 0);
      a2 = __builtin_amdgcn_mfma_f32_16x16x32_bf16(hf1, wf[2][1], a2, 0, 0, 0);
      a3 = __builtin_amdgcn_mfma_f32_16x16x32_bf16(hf1, wf[3][1], a3, 0, 0, 0);
      a0 = __builtin_amdgcn_mfma_f32_16x16x32_bf16(hf2, wf[0][2], a0, 0, 0, 0);
      a1 = __builtin_amdgcn_mfma_f32_16x16x32_bf16(hf2, wf[1][2], a1, 0, 0, 0);
      a2 = __builtin_amdgcn_mfma_f32_16x16x32_bf16(hf2, wf[2][2], a2, 0, 0, 0);
      a3 = __builtin_amdgcn_mfma_f32_16x16x32_bf16(hf2, wf[3][2], a3, 0, 0, 0);
      a0 = __builtin_amdgcn_mfma_f32_16x16x32_bf16(hf3, wf[0][3], a0, 0, 0, 0);
      a1 = __builtin_amdgcn_mfma_f32_16x16x32_bf16(hf3, wf[1][3], a1, 0, 0, 0);
      a2 = __builtin_amdgcn_mfma_f32_16x16x32_bf16(hf3, wf[2][3], a2, 0, 0, 0);
      a3 = __builtin_amdgcn_mfma_f32_16x16x32_bf16(hf3, wf[3][3], a3, 0, 0, 0);

      // EW: one cell per lane (batch 4wg+q, unit j); D row 4q = reg 0
      float gi = a0[0] + b2f((u16)xv[d].x);
      float gf = a1[0] + b2f((u16)(xv[d].x >> 16));
      float gg = a2[0] + b2f((u16)xv[d].y);
      float go = a3[0] + b2f((u16)(xv[d].y >> 16));
      cc = sigmoidf_(gf) * cc + sigmoidf_(gi) * tanhf_(gg);
      float h = sigmoidf_(go) * tanhf_(cc);
      u16 hv = f2b(h);

      // publish h(next): dense row q, idx j ^ ((q&1)<<5)
      hbuf[cur ^ 1][q][j ^ wsw] = hv;
      hprev = hv;

      // prefetch xp for t+4 (unclamped; tail garbage lands in workspace)
      xv[d] = *(const uint2*)pxq;
      pxq += xstep;

      lds_barrier();
      cur ^= 1;
    }
  }
  *optr = hprev;
}

// ---------------- FC: emissions = out1 @ fcW^T + fcb (fp32 out) -----------
__global__ __launch_bounds__(256) void k_fc(const u16* __restrict__ Aa,
                                            const u16* __restrict__ Wc,
                                            const float* __restrict__ bias,
                                            float* __restrict__ emis) {
  constexpr int LDW = 260;
  __shared__ u16 As[8 * 256];
  __shared__ u16 Ws[32 * LDW];
  int tid = threadIdx.x;
  int row0 = blockIdx.x * 8;
  *(uint4*)&As[tid * 8] = *(const uint4*)&Aa[(size_t)row0 * 256 + tid * 8];
#pragma unroll
  for (int cfc = 0; cfc < 8; ++cfc) {
    int ch = tid + 256 * cfc;
    int row = ch >> 6, c4 = (ch & 63) << 2;
    *(uint2*)&Ws[row * LDW + c4] = *(const uint2*)&Wc[row * 256 + c4];
  }
  __syncthreads();
  int r = tid >> 5, cj = tid & 31;
  const u16* ap = &As[r * 256];
  const u16* wp = &Ws[cj * LDW];
  float s0 = 0.f, s1 = 0.f;
#pragma unroll
  for (int k2 = 0; k2 < 128; ++k2) {
    u32 av = *(const u32*)&ap[k2 * 2];
    u32 wv = *(const u32*)&wp[k2 * 2];
    s0 += b2f((u16)av) * b2f((u16)wv);
    s1 += b2f((u16)(av >> 16)) * b2f((u16)(wv >> 16));
  }
  emis[(size_t)(row0 + r) * Kk + cj] = s0 + s1 + bias[cj];
}

// ---------------- CRF v3: register alpha + tree reductions ----------------
__global__ __launch_bounds__(64) void k_crf(const float* __restrict__ emis,
                                            const int* __restrict__ tags,
                                            const float* __restrict__ trans,
                                            const float* __restrict__ startv,
                                            const float* __restrict__ endv,
                                            float* __restrict__ nll) {
  __shared__ float tr[Kk * Kk];
  const int b = blockIdx.x;
  const int l = threadIdx.x;
  const int j = l & 31;
  const int half = l >> 5;
  for (int i = l; i < Kk * Kk; i += 64) tr[i] = trans[i];
  float tr_r[16];
#pragma unroll
  for (int i = 0; i < 16; ++i) tr_r[i] = trans[(half * 16 + i) * Kk + j];
  const float* eb = emis + (size_t)b * Kk;   // stride per t = 64*Kk = 2048
  float aj = startv[j] + eb[j];
  float alpha_r[16];
#pragma unroll
  for (int i = 0; i < 16; ++i) alpha_r[i] = __shfl(aj, half * 16 + i);
  float ebc = eb[2048 + j];
  __syncthreads();

  for (int t = 1; t < Tt; ++t) {
    float ebn = eb[(size_t)(t + 1) * 2048 + j];  // t+1==512 hits pad row
    float v[16];
#pragma unroll
    for (int i = 0; i < 16; ++i) v[i] = alpha_r[i] + tr_r[i];
    // tree max (depth 4)
    float m8[8], m4[4], m2[2], m;
#pragma unroll
    for (int i = 0; i < 8; ++i) m8[i] = fmaxf(v[i], v[i + 8]);
#pragma unroll
    for (int i = 0; i < 4; ++i) m4[i] = fmaxf(m8[i], m8[i + 4]);
    m2[0] = fmaxf(m4[0], m4[2]); m2[1] = fmaxf(m4[1], m4[3]);
    m = fmaxf(m2[0], m2[1]);
    float e[16];
#pragma unroll
    for (int i = 0; i < 16; ++i) e[i] = __expf(v[i] - m);
    // tree sum (depth 4)
    float s8[8], s4[4], s;
#pragma unroll
    for (int i = 0; i < 8; ++i) s8[i] = e[i] + e[i + 8];
#pragma unroll
    for (int i = 0; i < 4; ++i) s4[i] = s8[i] + s8[i + 4];
    s = (s4[0] + s4[1]) + (s4[2] + s4[3]);
    float m2x = __shfl_xor(m, 32);
    float s2x = __shfl_xor(s, 32);
    float M = fmaxf(m, m2x);
    s = s * __expf(m - M) + s2x * __expf(m2x - M);
    aj = ebc + M + __logf(s);
#pragma unroll
    for (int i = 0; i < 16; ++i) alpha_r[i] = __shfl(aj, half * 16 + i);
    ebc = ebn;
  }

  float val = aj + endv[j];           // both halves hold identical val(j)
  float M = val;
#pragma unroll
  for (int off = 16; off > 0; off >>= 1) M = fmaxf(M, __shfl_xor(M, off));
  float sz = __expf(val - M);
#pragma unroll
  for (int off = 16; off > 0; off >>= 1) sz += __shfl_xor(sz, off);
  float logZ = M + __logf(sz);        // valid within each 32-lane group

  const int* tg = tags + (size_t)b * Tt;
  float g = 0.f;
  for (int t = l; t < Tt; t += 64) {
    int cur = tg[t];
    g += eb[(size_t)t * 2048 + cur];
    if (t >= 1) g += tr[cur * Kk + tg[t - 1]];
  }
#pragma unroll
  for (int off = 32; off > 0; off >>= 1) g += __shfl_xor(g, off);
  if (l == 0) {
    g += startv[tg[0]] + endv[tg[Tt - 1]];
    nll[b] = logZ - g;
  }
}

__global__ void k_reduce(const float* __restrict__ nll, float* __restrict__ out) {
  float v = nll[threadIdx.x];
#pragma unroll
  for (int off = 32; off > 0; off >>= 1) v += __shfl_xor(v, off);
  if (threadIdx.x == 0) out[0] = v * (1.0f / 64.0f);
}

// --------------------------------------------------------------------------
extern "C" void kernel_launch(void* const* d_in, const int* in_sizes, int n_in,
                              void* d_out, int out_size, void* d_ws, size_t ws_size,
                              hipStream_t stream) {
  (void)in_sizes; (void)n_in; (void)out_size; (void)ws_size;
  const int*   x      = (const int*)d_in[0];
  const int*   tags   = (const int*)d_in[2];
  const float* emb    = (const float*)d_in[4];
  const float* Wih0f  = (const float*)d_in[5];
  const float* Whh0f  = (const float*)d_in[6];
  const float* b0f    = (const float*)d_in[7];
  const float* Wih0b  = (const float*)d_in[8];
  const float* Whh0b  = (const float*)d_in[9];
  const float* b0b    = (const float*)d_in[10];
  const float* Wih1f  = (const float*)d_in[11];
  const float* Whh1f  = (const float*)d_in[12];
  const float* b1f    = (const float*)d_in[13];
  const float* Wih1b  = (const float*)d_in[14];
  const float* Whh1b  = (const float*)d_in[15];
  const float* b1b    = (const float*)d_in[16];
  const float* fcW    = (const float*)d_in[17];
  const float* fcb    = (const float*)d_in[18];
  const float* trans  = (const float*)d_in[19];
  const float* startv = (const float*)d_in[20];
  const float* endv   = (const float*)d_in[21];

  char* p = (char*)d_ws;
  u16* buf0 = (u16*)p; p += (size_t)BT * Ee * 2;   // embeddings / layer-1 out
  u16* buf1 = (u16*)p; p += (size_t)BT * 256 * 2;  // layer-0 out
  u16* xpf  = (u16*)p; p += (size_t)BT * G4 * 2;   // fwd proj (lstm layout)
  u16* xpb  = (u16*)p; p += (size_t)BT * G4 * 2;   // bwd proj (lstm layout)
  u16* wb[4];
  for (int i = 0; i < 4; ++i) { wb[i] = (u16*)p; p += (size_t)512 * 256 * 2; }
  u16* fcwb = (u16*)p; p += (size_t)32 * 256 * 2;
  float* emis = (float*)p; p += ((size_t)BT * Kk + 64 * Kk) * 4;  // +1 pad row
  float* nll  = (float*)p; p += 256;

  k_embed<<<dim3(BT / 4), dim3(256), 0, stream>>>(x, emb, buf0);

  const float* wsrc[4] = {Wih0f, Wih0b, Wih1f, Wih1b};
  for (int i = 0; i < 4; ++i)
    k_castW<<<dim3(128), dim3(256), 0, stream>>>(wsrc[i], wb[i]);
  k_cast<<<dim3(8), dim3(256), 0, stream>>>(fcW, fcwb, 32 * 256 / 4);

  dim3 ggrid(BT / 128, 8);
  // layer 0
  k_gemm3<<<ggrid, dim3(256), 0, stream>>>(buf0, wb[0], wb[1], b0f, b0b, xpf, xpb);
  k_lstm8<<<dim3(32), dim3(512), 0, stream>>>(xpf, xpb, Whh0f, Whh0b, buf1);
  // layer 1
  k_gemm3<<<ggrid, dim3(256), 0, stream>>>(buf1, wb[2], wb[3], b1f, b1b, xpf, xpb);
  k_lstm8<<<dim3(32), dim3(512), 0, stream>>>(xpf, xpb, Whh1f, Whh1b, buf0);
  // emissions + CRF
  k_fc<<<dim3(BT / 8), dim3(256), 0, stream>>>(buf0, fcwb, fcb, emis);
  k_crf<<<dim3(Bb), dim3(64), 0, stream>>>(emis, tags, trans, startv, endv, nll);
  k_reduce<<<dim3(1), dim3(64), 0, stream>>>(nll, (float*)d_out);
}

// Round 9
// 940.840 us; speedup vs baseline: 2.3648x; 1.0562x over previous
//
#include <hip/hip_runtime.h>
#include <stddef.h>

typedef unsigned short u16;
typedef unsigned int u32;

#define DEV __device__ __forceinline__

constexpr int Bb = 64;
constexpr int Tt = 512;
constexpr int Ee = 256;     // embedding dim == 2H (layer-1 input dim)
constexpr int Hh = 128;
constexpr int Kk = 32;
constexpr int G4 = 4 * Hh;  // 512 gates
constexpr int BT = Bb * Tt; // 32768 rows

DEV u16 f2b(float f) {
  u32 u = __builtin_bit_cast(u32, f);
  u += 0x7fffu + ((u >> 16) & 1u);   // round-to-nearest-even
  return (u16)(u >> 16);
}
DEV float b2f(u16 v) { return __builtin_bit_cast(float, (u32)v << 16); }
DEV float sigmoidf_(float x) { return 1.0f / (1.0f + __expf(-x)); }
DEV float tanhf_(float x) { return 1.0f - 2.0f / (1.0f + __expf(2.0f * x)); }

// LDS-only barrier: does NOT drain vmcnt, so global prefetch loads and
// h-stores stay in flight across steps (T4: never vmcnt(0) in the loop).
DEV void lds_barrier() {
  asm volatile("s_waitcnt lgkmcnt(0)" ::: "memory");
  __builtin_amdgcn_sched_barrier(0);
  __builtin_amdgcn_s_barrier();
  __builtin_amdgcn_sched_barrier(0);
}

// ---------------- embedding lookup + cast to bf16 (t-major rows) ----------
__global__ __launch_bounds__(256) void k_embed(const int* __restrict__ x,
                                               const float* __restrict__ emb,
                                               u16* __restrict__ out) {
  int m = blockIdx.x * 4 + (threadIdx.x >> 6);  // out row = t*64 + b
  int lane = threadIdx.x & 63;
  int b = m & 63, t = m >> 6;
  int idx = x[b * Tt + t];
  float4 v = ((const float4*)(emb + (size_t)idx * Ee))[lane];
  uint2 p;
  p.x = (u32)f2b(v.x) | ((u32)f2b(v.y) << 16);
  p.y = (u32)f2b(v.z) | ((u32)f2b(v.w) << 16);
  ((uint2*)(out + (size_t)m * Ee))[lane] = p;
}

// ---------------- fused prep: Wih casts (row-permuted), fcW cast, biases --
// blocks 0-511: castW array a=blk>>7 (row n' = j*4+g); 512-519: fcW cast;
// 520-527: permuted biases bias_p[a*512+np] = bias_a[(np&3)*128 + np>>2].
__global__ __launch_bounds__(256) void k_prep(
    const float* __restrict__ W0, const float* __restrict__ W1,
    const float* __restrict__ W2, const float* __restrict__ W3,
    u16* __restrict__ d0, u16* __restrict__ d1,
    u16* __restrict__ d2, u16* __restrict__ d3,
    const float* __restrict__ fcW, u16* __restrict__ fcwb,
    const float* __restrict__ bi0, const float* __restrict__ bi1,
    const float* __restrict__ bi2, const float* __restrict__ bi3,
    float* __restrict__ bias_p) {
  int blk = blockIdx.x, tid = threadIdx.x;
  if (blk < 512) {
    int a = blk >> 7;
    const float* s; u16* d;
    if (a == 0)      { s = W0; d = d0; }
    else if (a == 1) { s = W1; d = d1; }
    else if (a == 2) { s = W2; d = d2; }
    else             { s = W3; d = d3; }
    int i = (blk & 127) * 256 + tid;   // 32768 = 512 rows x 64 float4
    int np = i >> 6, k4 = i & 63;
    int src = (np & 3) * 128 + (np >> 2);
    float4 v = ((const float4*)(s + (size_t)src * 256))[k4];
    uint2 p;
    p.x = (u32)f2b(v.x) | ((u32)f2b(v.y) << 16);
    p.y = (u32)f2b(v.z) | ((u32)f2b(v.w) << 16);
    ((uint2*)(d + (size_t)np * 256))[k4] = p;
  } else if (blk < 520) {
    int i = (blk - 512) * 256 + tid;   // 2048 float4s = 32*256
    float4 v = ((const float4*)fcW)[i];
    uint2 p;
    p.x = (u32)f2b(v.x) | ((u32)f2b(v.y) << 16);
    p.y = (u32)f2b(v.z) | ((u32)f2b(v.w) << 16);
    ((uint2*)fcwb)[i] = p;
  } else {
    int i = (blk - 520) * 256 + tid;   // 2048 = 4 x 512
    int a = i >> 9, np = i & 511;
    const float* s;
    if (a == 0)      s = bi0;
    else if (a == 1) s = bi1;
    else if (a == 2) s = bi2;
    else             s = bi3;
    bias_p[i] = s[(np & 3) * 128 + (np >> 2)];
  }
}

// ---------------- MFMA GEMM v4 (swapped operands), uint2 epilogue ---------
// A-operand = Wp rows (np = j*4+g), B-operand = X rows (m = t*64+b), K=256.
// D rows = np, cols = m. Lane's 4 regs = 4 gates of one (j, m) -> one uint2
// store to lstm layout: flat = (t*16 + b/4)*2048 + j*16 + (b&3)*4 + g.
typedef __attribute__((ext_vector_type(8))) short bfrag;
typedef __attribute__((ext_vector_type(4))) float ffrag;

__global__ __launch_bounds__(256) void k_gemm4(const u16* __restrict__ X,
                                               const u16* __restrict__ Wp0,
                                               const u16* __restrict__ Wp1,
                                               const float* __restrict__ bp0,
                                               const float* __restrict__ bp1,
                                               u16* __restrict__ out0,
                                               u16* __restrict__ out1) {
  constexpr int LDT = 72;
  __shared__ u16 Xs[128 * LDT];
  __shared__ u16 Ws[128 * LDT];
  const int tid = threadIdx.x;
  const int bm = blockIdx.x * 128;            // m base
  const int sel = blockIdx.y >> 2;
  const int bnp = (blockIdx.y & 3) * 128;     // np base
  const u16* __restrict__ Wp = sel ? Wp1 : Wp0;
  const float* __restrict__ bp = sel ? bp1 : bp0;
  u16* __restrict__ outp = sel ? out1 : out0;
  const int w = tid >> 6;
  const int l = tid & 63;
  const int r16 = l & 15;
  const int k8 = (l >> 4) << 3;
  const int wrN = (w >> 1) * 64;   // np quadrant
  const int wcM = (w & 1) * 64;    // m quadrant

  ffrag acc[4][4];
#pragma unroll
  for (int i = 0; i < 4; ++i)
#pragma unroll
    for (int jn = 0; jn < 4; ++jn) acc[i][jn] = (ffrag)0.0f;

  for (int kt = 0; kt < 256; kt += 64) {
#pragma unroll
    for (int c = 0; c < 4; ++c) {   // X tile: 128x64
      int ch = tid + 256 * c;
      int row = ch >> 3, c8 = (ch & 7) << 3;
      *(uint4*)&Xs[row * LDT + c8] =
          *(const uint4*)&X[(size_t)(bm + row) * 256 + kt + c8];
    }
#pragma unroll
    for (int c = 0; c < 4; ++c) {   // Wp tile: 128x64
      int ch = tid + 256 * c;
      int row = ch >> 3, c8 = (ch & 7) << 3;
      *(uint4*)&Ws[row * LDT + c8] =
          *(const uint4*)&Wp[(size_t)(bnp + row) * 256 + kt + c8];
    }
    __syncthreads();
#pragma unroll
    for (int kk = 0; kk < 2; ++kk) {
      bfrag af[4], bf[4];
#pragma unroll
      for (int fm = 0; fm < 4; ++fm)
        af[fm] = *(const bfrag*)&Ws[(wrN + fm * 16 + r16) * LDT + kk * 32 + k8];
#pragma unroll
      for (int fn = 0; fn < 4; ++fn)
        bf[fn] = *(const bfrag*)&Xs[(wcM + fn * 16 + r16) * LDT + kk * 32 + k8];
#pragma unroll
      for (int fm = 0; fm < 4; ++fm)
#pragma unroll
        for (int fn = 0; fn < 4; ++fn)
          acc[fm][fn] = __builtin_amdgcn_mfma_f32_16x16x32_bf16(
              af[fm], bf[fn], acc[fm][fn], 0, 0, 0);
    }
    __syncthreads();
  }
  const int Q = l >> 4;
#pragma unroll
  for (int fm = 0; fm < 4; ++fm) {
    int np0 = bnp + wrN + fm * 16 + 4 * Q;   // 4-aligned; regs = gates 0..3
    int j = np0 >> 2;
    float4 bv = *(const float4*)&bp[np0];
#pragma unroll
    for (int fn = 0; fn < 4; ++fn) {
      int m = bm + wcM + fn * 16 + r16;
      int t = m >> 6, bq = (m & 63) >> 2;
      size_t flat = ((size_t)t * 16 + bq) * 2048 + (size_t)j * 16 + (m & 3) * 4;
      float v0 = acc[fm][fn][0] + bv.x, v1 = acc[fm][fn][1] + bv.y;
      float v2 = acc[fm][fn][2] + bv.z, v3 = acc[fm][fn][3] + bv.w;
      u32 lo, hi;
      asm("v_cvt_pk_bf16_f32 %0, %1, %2" : "=v"(lo) : "v"(v0), "v"(v1));
      asm("v_cvt_pk_bf16_f32 %0, %1, %2" : "=v"(hi) : "v"(v2), "v"(v3));
      uint2 st; st.x = lo; st.y = hi;
      *(uint2*)&outp[flat] = st;
    }
  }
}

// ---------------- MFMA LSTM v8 (unchanged from round 8) -------------------
__global__ __launch_bounds__(512, 1) void k_lstm8(const u16* __restrict__ xpf,
                                                  const u16* __restrict__ xpb,
                                                  const float* __restrict__ whhf,
                                                  const float* __restrict__ whhb,
                                                  u16* __restrict__ out) {
  __shared__ u16 hbuf[2][4][128];     // dense; idx ^= (row&1)<<5 swizzle
  const int dir = blockIdx.x >> 4;
  const int wg = blockIdx.x & 15;     // batch quad: b = 4*wg + q
  const u16* __restrict__ xp = dir ? xpb : xpf;
  const float* __restrict__ whh = dir ? whhb : whhf;
  const int tid = threadIdx.x;
  const int w = tid >> 6;
  const int l = tid & 63;
  const int q = l >> 4;
  const int jw = l & 15;
  const int j = 16 * w + jw;

  for (int i = tid; i < 2 * 4 * 128; i += 512) (&hbuf[0][0][0])[i] = 0;

  bfrag wf[4][4];
#pragma unroll
  for (int g = 0; g < 4; ++g) {
    const float* rowp = whh + (size_t)(g * 128 + j) * 128;
#pragma unroll
    for (int ks = 0; ks < 4; ++ks) {
      float4 x0 = ((const float4*)(rowp + ks * 32 + q * 8))[0];
      float4 x1 = ((const float4*)(rowp + ks * 32 + q * 8))[1];
      bfrag t;
      t[0] = (short)f2b(x0.x); t[1] = (short)f2b(x0.y);
      t[2] = (short)f2b(x0.z); t[3] = (short)f2b(x0.w);
      t[4] = (short)f2b(x1.x); t[5] = (short)f2b(x1.y);
      t[6] = (short)f2b(x1.z); t[7] = (short)f2b(x1.w);
      wf[g][ks] = t;
    }
  }
  __syncthreads();

  const int dt = dir ? -1 : 1;
  const int tp0 = dir ? (Tt - 1) : 0;
  const size_t xoff = (size_t)wg * 2048 + (size_t)j * 16 + (size_t)q * 4;
  float cc = 0.f;
  int cur = 0;
  u16 hprev = 0;

  const bool ld_act = ((jw & 3) == 0);
  const int drow = jw >> 2;
  const int rsw = (drow & 1) << 5;
  const int wsw = (q & 1) << 5;
  bfrag hf0 = (bfrag)(short)0, hf1 = (bfrag)(short)0;
  bfrag hf2 = (bfrag)(short)0, hf3 = (bfrag)(short)0;

  uint2 xv[4];
#pragma unroll
  for (int d = 0; d < 4; ++d)
    xv[d] = *(const uint2*)&xp[(size_t)(tp0 + d * dt) * 32768 + xoff];

  const ptrdiff_t xstep = (ptrdiff_t)dt * 32768;
  const u16* pxq = xp + (size_t)(tp0 + 4 * dt) * 32768 + xoff;
  u16* optr = out + ((size_t)tp0 * 64 + 4 * wg + q) * 256 + (size_t)dir * 128 + j;
  const ptrdiff_t ostep = (ptrdiff_t)dt * 16384;

  for (int it = 0; it < Tt / 4; ++it) {
#pragma unroll
    for (int d = 0; d < 4; ++d) {
      if (it > 0 || d > 0) { *optr = hprev; optr += ostep; }

      if (ld_act) {
        const u16* hb = &hbuf[cur][drow][0];
        hf0 = *(const bfrag*)&hb[(0 * 32 + q * 8) ^ rsw];
        hf1 = *(const bfrag*)&hb[(1 * 32 + q * 8) ^ rsw];
        hf2 = *(const bfrag*)&hb[(2 * 32 + q * 8) ^ rsw];
        hf3 = *(const bfrag*)&hb[(3 * 32 + q * 8) ^ rsw];
      }

      ffrag a0 = __builtin_amdgcn_mfma_f32_16x16x32_bf16(hf0, wf[0][0], (ffrag)0.f, 0, 0, 0);
      ffrag a1 = __builtin_amdgcn_mfma_f32_16x16x32_bf16(hf0, wf[1][0], (ffrag)0.f, 0, 0, 0);
      ffrag a2 = __builtin_amdgcn_mfma_f32_16x16x32_bf16(hf0, wf[2][0], (ffrag)0.f, 0, 0, 0);
      ffrag a3 = __builtin_amdgcn_mfma_f32_16x16x32_bf16(hf0, wf[3][0], (ffrag)0.f, 0, 0, 0);
      a0 = __builtin_amdgcn_mfma_f32_16x16x32_bf16(hf1, wf[0][1], a0, 0, 0, 0);
      a1 = __builtin_amdgcn_mfma_f32_16x16x32_bf16(hf1, wf[1][1], a1, 0, 0, 0);
      a2 = __builtin_amdgcn_mfma_f32_16x16x32_bf16(hf1, wf[2][1], a2, 0, 0, 0);
      a3 = __builtin_amdgcn_mfma_f32_16x16x32_bf16(hf1, wf[3][1], a3, 0, 0, 0);
      a0 = __builtin_amdgcn_mfma_f32_16x16x32_bf16(hf2, wf[0][2], a0, 0, 0, 0);
      a1 = __builtin_amdgcn_mfma_f32_16x16x32_bf16(hf2, wf[1][2], a1, 0, 0, 0);
      a2 = __builtin_amdgcn_mfma_f32_16x16x32_bf16(hf2, wf[2][2], a2, 0, 0, 0);
      a3 = __builtin_amdgcn_mfma_f32_16x16x32_bf16(hf2, wf[3][2], a3, 0, 0, 0);
      a0 = __builtin_amdgcn_mfma_f32_16x16x32_bf16(hf3, wf[0][3], a0, 0, 0, 0);
      a1 = __builtin_amdgcn_mfma_f32_16x16x32_bf16(hf3, wf[1][3], a1, 0, 0, 0);
      a2 = __builtin_amdgcn_mfma_f32_16x16x32_bf16(hf3, wf[2][3], a2, 0, 0, 0);
      a3 = __builtin_amdgcn_mfma_f32_16x16x32_bf16(hf3, wf[3][3], a3, 0, 0, 0);

      float gi = a0[0] + b2f((u16)xv[d].x);
      float gf = a1[0] + b2f((u16)(xv[d].x >> 16));
      float gg = a2[0] + b2f((u16)xv[d].y);
      float go = a3[0] + b2f((u16)(xv[d].y >> 16));
      cc = sigmoidf_(gf) * cc + sigmoidf_(gi) * tanhf_(gg);
      float h = sigmoidf_(go) * tanhf_(cc);
      u16 hv = f2b(h);

      hbuf[cur ^ 1][q][j ^ wsw] = hv;
      hprev = hv;

      xv[d] = *(const uint2*)pxq;
      pxq += xstep;

      lds_barrier();
      cur ^= 1;
    }
  }
  *optr = hprev;
}

// ---------------- FC v2 (MFMA): emis = X @ fcW^T + fcb (fp32 out) ---------
__global__ __launch_bounds__(256) void k_fc2(const u16* __restrict__ X,
                                             const u16* __restrict__ Wc,
                                             const float* __restrict__ bias,
                                             float* __restrict__ emis) {
  constexpr int LDT = 72;
  __shared__ u16 Xs[128 * LDT];
  __shared__ u16 Ws[32 * LDT];
  const int tid = threadIdx.x;
  const int bm = blockIdx.x * 128;
  const int w = tid >> 6;
  const int l = tid & 63;
  const int r16 = l & 15;
  const int k8 = (l >> 4) << 3;

  ffrag acc[2][2];
#pragma unroll
  for (int i = 0; i < 2; ++i)
#pragma unroll
    for (int jn = 0; jn < 2; ++jn) acc[i][jn] = (ffrag)0.0f;

  for (int kt = 0; kt < 256; kt += 64) {
#pragma unroll
    for (int c = 0; c < 4; ++c) {   // X tile: 128x64
      int ch = tid + 256 * c;
      int row = ch >> 3, c8 = (ch & 7) << 3;
      *(uint4*)&Xs[row * LDT + c8] =
          *(const uint4*)&X[(size_t)(bm + row) * 256 + kt + c8];
    }
    {                               // fcW tile: 32x64 = 256 chunks
      int row = tid >> 3, c8 = (tid & 7) << 3;
      *(uint4*)&Ws[row * LDT + c8] =
          *(const uint4*)&Wc[(size_t)row * 256 + kt + c8];
    }
    __syncthreads();
#pragma unroll
    for (int kk = 0; kk < 2; ++kk) {
      bfrag af[2], bf[2];
#pragma unroll
      for (int fm = 0; fm < 2; ++fm)
        af[fm] = *(const bfrag*)&Xs[(32 * w + fm * 16 + r16) * LDT + kk * 32 + k8];
#pragma unroll
      for (int fn = 0; fn < 2; ++fn)
        bf[fn] = *(const bfrag*)&Ws[(fn * 16 + r16) * LDT + kk * 32 + k8];
#pragma unroll
      for (int fm = 0; fm < 2; ++fm)
#pragma unroll
        for (int fn = 0; fn < 2; ++fn)
          acc[fm][fn] = __builtin_amdgcn_mfma_f32_16x16x32_bf16(
              af[fm], bf[fn], acc[fm][fn], 0, 0, 0);
    }
    __syncthreads();
  }
  const int rbase = (l >> 4) * 4;
#pragma unroll
  for (int fm = 0; fm < 2; ++fm)
#pragma unroll
    for (int fn = 0; fn < 2; ++fn) {
      int cj = fn * 16 + r16;
      float bv = bias[cj];
#pragma unroll
      for (int r = 0; r < 4; ++r) {
        int m = bm + 32 * w + fm * 16 + rbase + r;
        emis[(size_t)m * Kk + cj] = acc[fm][fn][r] + bv;
      }
    }
}

// ---------------- CRF v3: register alpha + tree reductions ----------------
__global__ __launch_bounds__(64) void k_crf(const float* __restrict__ emis,
                                            const int* __restrict__ tags,
                                            const float* __restrict__ trans,
                                            const float* __restrict__ startv,
                                            const float* __restrict__ endv,
                                            float* __restrict__ nll) {
  __shared__ float tr[Kk * Kk];
  const int b = blockIdx.x;
  const int l = threadIdx.x;
  const int j = l & 31;
  const int half = l >> 5;
  for (int i = l; i < Kk * Kk; i += 64) tr[i] = trans[i];
  float tr_r[16];
#pragma unroll
  for (int i = 0; i < 16; ++i) tr_r[i] = trans[(half * 16 + i) * Kk + j];
  const float* eb = emis + (size_t)b * Kk;   // stride per t = 64*Kk = 2048
  float aj = startv[j] + eb[j];
  float alpha_r[16];
#pragma unroll
  for (int i = 0; i < 16; ++i) alpha_r[i] = __shfl(aj, half * 16 + i);
  float ebc = eb[2048 + j];
  __syncthreads();

  for (int t = 1; t < Tt; ++t) {
    float ebn = eb[(size_t)(t + 1) * 2048 + j];  // t+1==512 hits pad row
    float v[16];
#pragma unroll
    for (int i = 0; i < 16; ++i) v[i] = alpha_r[i] + tr_r[i];
    float m8[8], m4[4], m2[2], m;
#pragma unroll
    for (int i = 0; i < 8; ++i) m8[i] = fmaxf(v[i], v[i + 8]);
#pragma unroll
    for (int i = 0; i < 4; ++i) m4[i] = fmaxf(m8[i], m8[i + 4]);
    m2[0] = fmaxf(m4[0], m4[2]); m2[1] = fmaxf(m4[1], m4[3]);
    m = fmaxf(m2[0], m2[1]);
    float e[16];
#pragma unroll
    for (int i = 0; i < 16; ++i) e[i] = __expf(v[i] - m);
    float s8[8], s4[4], s;
#pragma unroll
    for (int i = 0; i < 8; ++i) s8[i] = e[i] + e[i + 8];
#pragma unroll
    for (int i = 0; i < 4; ++i) s4[i] = s8[i] + s8[i + 4];
    s = (s4[0] + s4[1]) + (s4[2] + s4[3]);
    float m2x = __shfl_xor(m, 32);
    float s2x = __shfl_xor(s, 32);
    float M = fmaxf(m, m2x);
    s = s * __expf(m - M) + s2x * __expf(m2x - M);
    aj = ebc + M + __logf(s);
#pragma unroll
    for (int i = 0; i < 16; ++i) alpha_r[i] = __shfl(aj, half * 16 + i);
    ebc = ebn;
  }

  float val = aj + endv[j];
  float M = val;
#pragma unroll
  for (int off = 16; off > 0; off >>= 1) M = fmaxf(M, __shfl_xor(M, off));
  float sz = __expf(val - M);
#pragma unroll
  for (int off = 16; off > 0; off >>= 1) sz += __shfl_xor(sz, off);
  float logZ = M + __logf(sz);

  const int* tg = tags + (size_t)b * Tt;
  float g = 0.f;
  for (int t = l; t < Tt; t += 64) {
    int cur = tg[t];
    g += eb[(size_t)t * 2048 + cur];
    if (t >= 1) g += tr[cur * Kk + tg[t - 1]];
  }
#pragma unroll
  for (int off = 32; off > 0; off >>= 1) g += __shfl_xor(g, off);
  if (l == 0) {
    g += startv[tg[0]] + endv[tg[Tt - 1]];
    nll[b] = logZ - g;
  }
}

__global__ void k_reduce(const float* __restrict__ nll, float* __restrict__ out) {
  float v = nll[threadIdx.x];
#pragma unroll
  for (int off = 32; off > 0; off >>= 1) v += __shfl_xor(v, off);
  if (threadIdx.x == 0) out[0] = v * (1.0f / 64.0f);
}

// --------------------------------------------------------------------------
extern "C" void kernel_launch(void* const* d_in, const int* in_sizes, int n_in,
                              void* d_out, int out_size, void* d_ws, size_t ws_size,
                              hipStream_t stream) {
  (void)in_sizes; (void)n_in; (void)out_size; (void)ws_size;
  const int*   x      = (const int*)d_in[0];
  const int*   tags   = (const int*)d_in[2];
  const float* emb    = (const float*)d_in[4];
  const float* Wih0f  = (const float*)d_in[5];
  const float* Whh0f  = (const float*)d_in[6];
  const float* b0f    = (const float*)d_in[7];
  const float* Wih0b  = (const float*)d_in[8];
  const float* Whh0b  = (const float*)d_in[9];
  const float* b0b    = (const float*)d_in[10];
  const float* Wih1f  = (const float*)d_in[11];
  const float* Whh1f  = (const float*)d_in[12];
  const float* b1f    = (const float*)d_in[13];
  const float* Wih1b  = (const float*)d_in[14];
  const float* Whh1b  = (const float*)d_in[15];
  const float* b1b    = (const float*)d_in[16];
  const float* fcW    = (const float*)d_in[17];
  const float* fcb    = (const float*)d_in[18];
  const float* trans  = (const float*)d_in[19];
  const float* startv = (const float*)d_in[20];
  const float* endv   = (const float*)d_in[21];

  char* p = (char*)d_ws;
  u16* buf0 = (u16*)p; p += (size_t)BT * Ee * 2;   // embeddings / layer-1 out
  u16* buf1 = (u16*)p; p += (size_t)BT * 256 * 2;  // layer-0 out
  u16* xpf  = (u16*)p; p += (size_t)BT * G4 * 2;   // fwd proj (lstm layout)
  u16* xpb  = (u16*)p; p += (size_t)BT * G4 * 2;   // bwd proj (lstm layout)
  u16* wb[4];
  for (int i = 0; i < 4; ++i) { wb[i] = (u16*)p; p += (size_t)512 * 256 * 2; }
  u16* fcwb = (u16*)p; p += (size_t)32 * 256 * 2;
  float* bias_p = (float*)p; p += 4 * 512 * 4;     // permuted biases
  float* emis = (float*)p; p += ((size_t)BT * Kk + 64 * Kk) * 4;  // +pad row
  float* nll  = (float*)p; p += 256;

  k_embed<<<dim3(BT / 4), dim3(256), 0, stream>>>(x, emb, buf0);
  k_prep<<<dim3(528), dim3(256), 0, stream>>>(
      Wih0f, Wih0b, Wih1f, Wih1b, wb[0], wb[1], wb[2], wb[3],
      fcW, fcwb, b0f, b0b, b1f, b1b, bias_p);

  dim3 ggrid(BT / 128, 8);
  // layer 0
  k_gemm4<<<ggrid, dim3(256), 0, stream>>>(buf0, wb[0], wb[1],
                                           bias_p, bias_p + 512, xpf, xpb);
  k_lstm8<<<dim3(32), dim3(512), 0, stream>>>(xpf, xpb, Whh0f, Whh0b, buf1);
  // layer 1
  k_gemm4<<<ggrid, dim3(256), 0, stream>>>(buf1, wb[2], wb[3],
                                           bias_p + 1024, bias_p + 1536, xpf, xpb);
  k_lstm8<<<dim3(32), dim3(512), 0, stream>>>(xpf, xpb, Whh1f, Whh1b, buf0);
  // emissions + CRF
  k_fc2<<<dim3(BT / 128), dim3(256), 0, stream>>>(buf0, fcwb, fcb, emis);
  k_crf<<<dim3(Bb), dim3(64), 0, stream>>>(emis, tags, trans, startv, endv, nll);
  k_reduce<<<dim3(1), dim3(64), 0, stream>>>(nll, (float*)d_out);
}

// Round 10
// 791.858 us; speedup vs baseline: 2.8097x; 1.1881x over previous
//
#include <hip/hip_runtime.h>
#include <stddef.h>

typedef unsigned short u16;
typedef unsigned int u32;

#define DEV __device__ __forceinline__

constexpr int Bb = 64;
constexpr int Tt = 512;
constexpr int Ee = 256;     // embedding dim == 2H (layer-1 input dim)
constexpr int Hh = 128;
constexpr int Kk = 32;
constexpr int G4 = 4 * Hh;  // 512 gates
constexpr int BT = Bb * Tt; // 32768 rows

DEV u16 f2b(float f) {
  u32 u = __builtin_bit_cast(u32, f);
  u += 0x7fffu + ((u >> 16) & 1u);   // round-to-nearest-even
  return (u16)(u >> 16);
}
DEV float b2f(u16 v) { return __builtin_bit_cast(float, (u32)v << 16); }
// fast reciprocal (v_rcp_f32, ~1 ulp): avoids IEEE div sequence (9 instrs)
DEV float rcp_(float x) { float r; asm("v_rcp_f32 %0, %1" : "=v"(r) : "v"(x)); return r; }
DEV float sigmoidf_(float x) { return rcp_(1.0f + __expf(-x)); }
DEV float tanhf_(float x) { return 1.0f - 2.0f * rcp_(1.0f + __expf(2.0f * x)); }

// LDS-only barrier: does NOT drain vmcnt, so global prefetch loads and
// h-stores stay in flight across steps (T4: never vmcnt(0) in the loop).
DEV void lds_barrier() {
  asm volatile("s_waitcnt lgkmcnt(0)" ::: "memory");
  __builtin_amdgcn_sched_barrier(0);
  __builtin_amdgcn_s_barrier();
  __builtin_amdgcn_sched_barrier(0);
}

// ------- fused embed (blocks 0..8191) + weight prep (blocks 8192..8719) ---
__global__ __launch_bounds__(256) void k_embprep(
    const int* __restrict__ x, const float* __restrict__ emb,
    u16* __restrict__ eout,
    const float* __restrict__ W0, const float* __restrict__ W1,
    const float* __restrict__ W2, const float* __restrict__ W3,
    u16* __restrict__ d0, u16* __restrict__ d1,
    u16* __restrict__ d2, u16* __restrict__ d3,
    const float* __restrict__ fcW, u16* __restrict__ fcwb,
    const float* __restrict__ bi0, const float* __restrict__ bi1,
    const float* __restrict__ bi2, const float* __restrict__ bi3,
    float* __restrict__ bias_p) {
  int blk = blockIdx.x, tid = threadIdx.x;
  if (blk < 8192) {
    int m = blk * 4 + (tid >> 6);    // out row = t*64 + b
    int lane = tid & 63;
    int b = m & 63, t = m >> 6;
    int idx = x[b * Tt + t];
    float4 v = ((const float4*)(emb + (size_t)idx * Ee))[lane];
    uint2 p;
    p.x = (u32)f2b(v.x) | ((u32)f2b(v.y) << 16);
    p.y = (u32)f2b(v.z) | ((u32)f2b(v.w) << 16);
    ((uint2*)(eout + (size_t)m * Ee))[lane] = p;
    return;
  }
  blk -= 8192;
  if (blk < 512) {
    int a = blk >> 7;
    const float* s; u16* d;
    if (a == 0)      { s = W0; d = d0; }
    else if (a == 1) { s = W1; d = d1; }
    else if (a == 2) { s = W2; d = d2; }
    else             { s = W3; d = d3; }
    int i = (blk & 127) * 256 + tid;   // 32768 = 512 rows x 64 float4
    int np = i >> 6, k4 = i & 63;
    int src = (np & 3) * 128 + (np >> 2);
    float4 v = ((const float4*)(s + (size_t)src * 256))[k4];
    uint2 p;
    p.x = (u32)f2b(v.x) | ((u32)f2b(v.y) << 16);
    p.y = (u32)f2b(v.z) | ((u32)f2b(v.w) << 16);
    ((uint2*)(d + (size_t)np * 256))[k4] = p;
  } else if (blk < 520) {
    int i = (blk - 512) * 256 + tid;   // 2048 float4s = 32*256
    float4 v = ((const float4*)fcW)[i];
    uint2 p;
    p.x = (u32)f2b(v.x) | ((u32)f2b(v.y) << 16);
    p.y = (u32)f2b(v.z) | ((u32)f2b(v.w) << 16);
    ((uint2*)fcwb)[i] = p;
  } else {
    int i = (blk - 520) * 256 + tid;   // 2048 = 4 x 512
    int a = i >> 9, np = i & 511;
    const float* s;
    if (a == 0)      s = bi0;
    else if (a == 1) s = bi1;
    else if (a == 2) s = bi2;
    else             s = bi3;
    bias_p[i] = s[(np & 3) * 128 + (np >> 2)];
  }
}

// ---------------- MFMA GEMM v4 (swapped operands), uint2 epilogue ---------
// A-operand = Wp rows (np = j*4+g), B-operand = X rows (m = t*64+b), K=256.
// Lane's 4 regs = 4 gates of one (j, m) -> one uint2 store to lstm layout:
// flat = (t*16 + b/4)*2048 + j*16 + (b&3)*4 + g.
typedef __attribute__((ext_vector_type(8))) short bfrag;
typedef __attribute__((ext_vector_type(4))) float ffrag;

__global__ __launch_bounds__(256) void k_gemm4(const u16* __restrict__ X,
                                               const u16* __restrict__ Wp0,
                                               const u16* __restrict__ Wp1,
                                               const float* __restrict__ bp0,
                                               const float* __restrict__ bp1,
                                               u16* __restrict__ out0,
                                               u16* __restrict__ out1) {
  constexpr int LDT = 72;
  __shared__ u16 Xs[128 * LDT];
  __shared__ u16 Ws[128 * LDT];
  const int tid = threadIdx.x;
  const int bm = blockIdx.x * 128;            // m base
  const int sel = blockIdx.y >> 2;
  const int bnp = (blockIdx.y & 3) * 128;     // np base
  const u16* __restrict__ Wp = sel ? Wp1 : Wp0;
  const float* __restrict__ bp = sel ? bp1 : bp0;
  u16* __restrict__ outp = sel ? out1 : out0;
  const int w = tid >> 6;
  const int l = tid & 63;
  const int r16 = l & 15;
  const int k8 = (l >> 4) << 3;
  const int wrN = (w >> 1) * 64;   // np quadrant
  const int wcM = (w & 1) * 64;    // m quadrant

  ffrag acc[4][4];
#pragma unroll
  for (int i = 0; i < 4; ++i)
#pragma unroll
    for (int jn = 0; jn < 4; ++jn) acc[i][jn] = (ffrag)0.0f;

  for (int kt = 0; kt < 256; kt += 64) {
#pragma unroll
    for (int c = 0; c < 4; ++c) {   // X tile: 128x64
      int ch = tid + 256 * c;
      int row = ch >> 3, c8 = (ch & 7) << 3;
      *(uint4*)&Xs[row * LDT + c8] =
          *(const uint4*)&X[(size_t)(bm + row) * 256 + kt + c8];
    }
#pragma unroll
    for (int c = 0; c < 4; ++c) {   // Wp tile: 128x64
      int ch = tid + 256 * c;
      int row = ch >> 3, c8 = (ch & 7) << 3;
      *(uint4*)&Ws[row * LDT + c8] =
          *(const uint4*)&Wp[(size_t)(bnp + row) * 256 + kt + c8];
    }
    __syncthreads();
#pragma unroll
    for (int kk = 0; kk < 2; ++kk) {
      bfrag af[4], bf[4];
#pragma unroll
      for (int fm = 0; fm < 4; ++fm)
        af[fm] = *(const bfrag*)&Ws[(wrN + fm * 16 + r16) * LDT + kk * 32 + k8];
#pragma unroll
      for (int fn = 0; fn < 4; ++fn)
        bf[fn] = *(const bfrag*)&Xs[(wcM + fn * 16 + r16) * LDT + kk * 32 + k8];
#pragma unroll
      for (int fm = 0; fm < 4; ++fm)
#pragma unroll
        for (int fn = 0; fn < 4; ++fn)
          acc[fm][fn] = __builtin_amdgcn_mfma_f32_16x16x32_bf16(
              af[fm], bf[fn], acc[fm][fn], 0, 0, 0);
    }
    __syncthreads();
  }
  const int Q = l >> 4;
#pragma unroll
  for (int fm = 0; fm < 4; ++fm) {
    int np0 = bnp + wrN + fm * 16 + 4 * Q;   // 4-aligned; regs = gates 0..3
    int j = np0 >> 2;
    float4 bv = *(const float4*)&bp[np0];
#pragma unroll
    for (int fn = 0; fn < 4; ++fn) {
      int m = bm + wcM + fn * 16 + r16;
      int t = m >> 6, bq = (m & 63) >> 2;
      size_t flat = ((size_t)t * 16 + bq) * 2048 + (size_t)j * 16 + (m & 3) * 4;
      float v0 = acc[fm][fn][0] + bv.x, v1 = acc[fm][fn][1] + bv.y;
      float v2 = acc[fm][fn][2] + bv.z, v3 = acc[fm][fn][3] + bv.w;
      u32 lo, hi;
      asm("v_cvt_pk_bf16_f32 %0, %1, %2" : "=v"(lo) : "v"(v0), "v"(v1));
      asm("v_cvt_pk_bf16_f32 %0, %1, %2" : "=v"(hi) : "v"(v2), "v"(v3));
      uint2 st; st.x = lo; st.y = hi;
      *(uint2*)&outp[flat] = st;
    }
  }
}

// ---------------- MFMA LSTM v9: v8 structure + rcp-based activations ------
__global__ __launch_bounds__(512, 1) void k_lstm9(const u16* __restrict__ xpf,
                                                  const u16* __restrict__ xpb,
                                                  const float* __restrict__ whhf,
                                                  const float* __restrict__ whhb,
                                                  u16* __restrict__ out) {
  __shared__ u16 hbuf[2][4][128];     // dense; idx ^= (row&1)<<5 swizzle
  const int dir = blockIdx.x >> 4;
  const int wg = blockIdx.x & 15;     // batch quad: b = 4*wg + q
  const u16* __restrict__ xp = dir ? xpb : xpf;
  const float* __restrict__ whh = dir ? whhb : whhf;
  const int tid = threadIdx.x;
  const int w = tid >> 6;
  const int l = tid & 63;
  const int q = l >> 4;
  const int jw = l & 15;
  const int j = 16 * w + jw;

  for (int i = tid; i < 2 * 4 * 128; i += 512) (&hbuf[0][0][0])[i] = 0;

  bfrag wf[4][4];
#pragma unroll
  for (int g = 0; g < 4; ++g) {
    const float* rowp = whh + (size_t)(g * 128 + j) * 128;
#pragma unroll
    for (int ks = 0; ks < 4; ++ks) {
      float4 x0 = ((const float4*)(rowp + ks * 32 + q * 8))[0];
      float4 x1 = ((const float4*)(rowp + ks * 32 + q * 8))[1];
      bfrag t;
      t[0] = (short)f2b(x0.x); t[1] = (short)f2b(x0.y);
      t[2] = (short)f2b(x0.z); t[3] = (short)f2b(x0.w);
      t[4] = (short)f2b(x1.x); t[5] = (short)f2b(x1.y);
      t[6] = (short)f2b(x1.z); t[7] = (short)f2b(x1.w);
      wf[g][ks] = t;
    }
  }
  __syncthreads();

  const int dt = dir ? -1 : 1;
  const int tp0 = dir ? (Tt - 1) : 0;
  const size_t xoff = (size_t)wg * 2048 + (size_t)j * 16 + (size_t)q * 4;
  float cc = 0.f;
  int cur = 0;
  u16 hprev = 0;

  const bool ld_act = ((jw & 3) == 0);
  const int drow = jw >> 2;
  const int rsw = (drow & 1) << 5;
  const int wsw = (q & 1) << 5;
  bfrag hf0 = (bfrag)(short)0, hf1 = (bfrag)(short)0;
  bfrag hf2 = (bfrag)(short)0, hf3 = (bfrag)(short)0;

  uint2 xv[4];
#pragma unroll
  for (int d = 0; d < 4; ++d)
    xv[d] = *(const uint2*)&xp[(size_t)(tp0 + d * dt) * 32768 + xoff];

  const ptrdiff_t xstep = (ptrdiff_t)dt * 32768;
  const u16* pxq = xp + (size_t)(tp0 + 4 * dt) * 32768 + xoff;
  u16* optr = out + ((size_t)tp0 * 64 + 4 * wg + q) * 256 + (size_t)dir * 128 + j;
  const ptrdiff_t ostep = (ptrdiff_t)dt * 16384;

  for (int it = 0; it < Tt / 4; ++it) {
#pragma unroll
    for (int d = 0; d < 4; ++d) {
      if (it > 0 || d > 0) { *optr = hprev; optr += ostep; }

      if (ld_act) {
        const u16* hb = &hbuf[cur][drow][0];
        hf0 = *(const bfrag*)&hb[(0 * 32 + q * 8) ^ rsw];
        hf1 = *(const bfrag*)&hb[(1 * 32 + q * 8) ^ rsw];
        hf2 = *(const bfrag*)&hb[(2 * 32 + q * 8) ^ rsw];
        hf3 = *(const bfrag*)&hb[(3 * 32 + q * 8) ^ rsw];
      }

      ffrag a0 = __builtin_amdgcn_mfma_f32_16x16x32_bf16(hf0, wf[0][0], (ffrag)0.f, 0, 0, 0);
      ffrag a1 = __builtin_amdgcn_mfma_f32_16x16x32_bf16(hf0, wf[1][0], (ffrag)0.f, 0, 0, 0);
      ffrag a2 = __builtin_amdgcn_mfma_f32_16x16x32_bf16(hf0, wf[2][0], (ffrag)0.f, 0, 0, 0);
      ffrag a3 = __builtin_amdgcn_mfma_f32_16x16x32_bf16(hf0, wf[3][0], (ffrag)0.f, 0, 0, 0);
      a0 = __builtin_amdgcn_mfma_f32_16x16x32_bf16(hf1, wf[0][1], a0, 0, 0, 0);
      a1 = __builtin_amdgcn_mfma_f32_16x16x32_bf16(hf1, wf[1][1], a1, 0, 0, 0);
      a2 = __builtin_amdgcn_mfma_f32_16x16x32_bf16(hf1, wf[2][1], a2, 0, 0, 0);
      a3 = __builtin_amdgcn_mfma_f32_16x16x32_bf16(hf1, wf[3][1], a3, 0, 0, 0);
      a0 = __builtin_amdgcn_mfma_f32_16x16x32_bf16(hf2, wf[0][2], a0, 0, 0, 0);
      a1 = __builtin_amdgcn_mfma_f32_16x16x32_bf16(hf2, wf[1][2], a1, 0, 0, 0);
      a2 = __builtin_amdgcn_mfma_f32_16x16x32_bf16(hf2, wf[2][2], a2, 0, 0, 0);
      a3 = __builtin_amdgcn_mfma_f32_16x16x32_bf16(hf2, wf[3][2], a3, 0, 0, 0);
      a0 = __builtin_amdgcn_mfma_f32_16x16x32_bf16(hf3, wf[0][3], a0, 0, 0, 0);
      a1 = __builtin_amdgcn_mfma_f32_16x16x32_bf16(hf3, wf[1][3], a1, 0, 0, 0);
      a2 = __builtin_amdgcn_mfma_f32_16x16x32_bf16(hf3, wf[2][3], a2, 0, 0, 0);
      a3 = __builtin_amdgcn_mfma_f32_16x16x32_bf16(hf3, wf[3][3], a3, 0, 0, 0);

      float gi = a0[0] + b2f((u16)xv[d].x);
      float gf = a1[0] + b2f((u16)(xv[d].x >> 16));
      float gg = a2[0] + b2f((u16)xv[d].y);
      float go = a3[0] + b2f((u16)(xv[d].y >> 16));
      cc = sigmoidf_(gf) * cc + sigmoidf_(gi) * tanhf_(gg);
      float h = sigmoidf_(go) * tanhf_(cc);
      u16 hv = f2b(h);

      hbuf[cur ^ 1][q][j ^ wsw] = hv;
      hprev = hv;

      xv[d] = *(const uint2*)pxq;
      pxq += xstep;

      lds_barrier();
      cur ^= 1;
    }
  }
  *optr = hprev;
}

// ---------------- FC v2 (MFMA): emis = X @ fcW^T + fcb (fp32 out) ---------
__global__ __launch_bounds__(256) void k_fc2(const u16* __restrict__ X,
                                             const u16* __restrict__ Wc,
                                             const float* __restrict__ bias,
                                             float* __restrict__ emis) {
  constexpr int LDT = 72;
  __shared__ u16 Xs[128 * LDT];
  __shared__ u16 Ws[32 * LDT];
  const int tid = threadIdx.x;
  const int bm = blockIdx.x * 128;
  const int w = tid >> 6;
  const int l = tid & 63;
  const int r16 = l & 15;
  const int k8 = (l >> 4) << 3;

  ffrag acc[2][2];
#pragma unroll
  for (int i = 0; i < 2; ++i)
#pragma unroll
    for (int jn = 0; jn < 2; ++jn) acc[i][jn] = (ffrag)0.0f;

  for (int kt = 0; kt < 256; kt += 64) {
#pragma unroll
    for (int c = 0; c < 4; ++c) {   // X tile: 128x64
      int ch = tid + 256 * c;
      int row = ch >> 3, c8 = (ch & 7) << 3;
      *(uint4*)&Xs[row * LDT + c8] =
          *(const uint4*)&X[(size_t)(bm + row) * 256 + kt + c8];
    }
    {                               // fcW tile: 32x64 = 256 chunks
      int row = tid >> 3, c8 = (tid & 7) << 3;
      *(uint4*)&Ws[row * LDT + c8] =
          *(const uint4*)&Wc[(size_t)row * 256 + kt + c8];
    }
    __syncthreads();
#pragma unroll
    for (int kk = 0; kk < 2; ++kk) {
      bfrag af[2], bf[2];
#pragma unroll
      for (int fm = 0; fm < 2; ++fm)
        af[fm] = *(const bfrag*)&Xs[(32 * w + fm * 16 + r16) * LDT + kk * 32 + k8];
#pragma unroll
      for (int fn = 0; fn < 2; ++fn)
        bf[fn] = *(const bfrag*)&Ws[(fn * 16 + r16) * LDT + kk * 32 + k8];
#pragma unroll
      for (int fm = 0; fm < 2; ++fm)
#pragma unroll
        for (int fn = 0; fn < 2; ++fn)
          acc[fm][fn] = __builtin_amdgcn_mfma_f32_16x16x32_bf16(
              af[fm], bf[fn], acc[fm][fn], 0, 0, 0);
    }
    __syncthreads();
  }
  const int rbase = (l >> 4) * 4;
#pragma unroll
  for (int fm = 0; fm < 2; ++fm)
#pragma unroll
    for (int fn = 0; fn < 2; ++fn) {
      int cj = fn * 16 + r16;
      float bv = bias[cj];
#pragma unroll
      for (int r = 0; r < 4; ++r) {
        int m = bm + 32 * w + fm * 16 + rbase + r;
        emis[(size_t)m * Kk + cj] = acc[fm][fn][r] + bv;
      }
    }
}

// ---------------- CRF v4: precomputed exp(trans), single-exp step ---------
// new_j = eb + m + log(sum_i exp(alpha_i - m) * E_ij), m = max_i alpha_i.
// Lane (half, j) holds E_r[i] = exp(trans[(half*16+i)*32 + j]). Per step:
// 5-shfl global max, 1 exp, 16-shfl p broadcast, 16 FMA dot, 1 log.
__global__ __launch_bounds__(64) void k_crf(const float* __restrict__ emis,
                                            const int* __restrict__ tags,
                                            const float* __restrict__ trans,
                                            const float* __restrict__ startv,
                                            const float* __restrict__ endv,
                                            float* __restrict__ nll) {
  __shared__ float tr[Kk * Kk];
  const int b = blockIdx.x;
  const int l = threadIdx.x;
  const int j = l & 31;
  const int half = l >> 5;
  for (int i = l; i < Kk * Kk; i += 64) tr[i] = trans[i];
  float E_r[16];
#pragma unroll
  for (int i = 0; i < 16; ++i) E_r[i] = __expf(trans[(half * 16 + i) * Kk + j]);
  const float* eb = emis + (size_t)b * Kk;   // stride per t = 64*Kk = 2048
  float aj = startv[j] + eb[j];
  float ebc = eb[2048 + j];
  __syncthreads();

  for (int t = 1; t < Tt; ++t) {
    float ebn = eb[(size_t)(t + 1) * 2048 + j];  // t+1==512 hits pad row
    // global max over the 32 alphas (each 32-lane group independently)
    float m = aj;
    m = fmaxf(m, __shfl_xor(m, 16));
    m = fmaxf(m, __shfl_xor(m, 8));
    m = fmaxf(m, __shfl_xor(m, 4));
    m = fmaxf(m, __shfl_xor(m, 2));
    m = fmaxf(m, __shfl_xor(m, 1));
    float p = __expf(aj - m);          // the ONLY exp in the loop
    float c0 = 0.f, c1 = 0.f, c2 = 0.f, c3 = 0.f;
#pragma unroll
    for (int i = 0; i < 16; i += 4) {
      c0 = fmaf(__shfl(p, half * 16 + i),     E_r[i],     c0);
      c1 = fmaf(__shfl(p, half * 16 + i + 1), E_r[i + 1], c1);
      c2 = fmaf(__shfl(p, half * 16 + i + 2), E_r[i + 2], c2);
      c3 = fmaf(__shfl(p, half * 16 + i + 3), E_r[i + 3], c3);
    }
    float s = (c0 + c1) + (c2 + c3);
    s += __shfl_xor(s, 32);            // combine the two i-halves
    aj = ebc + m + __logf(s);
    ebc = ebn;
  }

  float val = aj + endv[j];           // both halves hold identical val(j)
  float M = val;
#pragma unroll
  for (int off = 16; off > 0; off >>= 1) M = fmaxf(M, __shfl_xor(M, off));
  float sz = __expf(val - M);
#pragma unroll
  for (int off = 16; off > 0; off >>= 1) sz += __shfl_xor(sz, off);
  float logZ = M + __logf(sz);

  const int* tg = tags + (size_t)b * Tt;
  float g = 0.f;
  for (int t = l; t < Tt; t += 64) {
    int cur = tg[t];
    g += eb[(size_t)t * 2048 + cur];
    if (t >= 1) g += tr[cur * Kk + tg[t - 1]];
  }
#pragma unroll
  for (int off = 32; off > 0; off >>= 1) g += __shfl_xor(g, off);
  if (l == 0) {
    g += startv[tg[0]] + endv[tg[Tt - 1]];
    nll[b] = logZ - g;
  }
}

__global__ void k_reduce(const float* __restrict__ nll, float* __restrict__ out) {
  float v = nll[threadIdx.x];
#pragma unroll
  for (int off = 32; off > 0; off >>= 1) v += __shfl_xor(v, off);
  if (threadIdx.x == 0) out[0] = v * (1.0f / 64.0f);
}

// --------------------------------------------------------------------------
extern "C" void kernel_launch(void* const* d_in, const int* in_sizes, int n_in,
                              void* d_out, int out_size, void* d_ws, size_t ws_size,
                              hipStream_t stream) {
  (void)in_sizes; (void)n_in; (void)out_size; (void)ws_size;
  const int*   x      = (const int*)d_in[0];
  const int*   tags   = (const int*)d_in[2];
  const float* emb    = (const float*)d_in[4];
  const float* Wih0f  = (const float*)d_in[5];
  const float* Whh0f  = (const float*)d_in[6];
  const float* b0f    = (const float*)d_in[7];
  const float* Wih0b  = (const float*)d_in[8];
  const float* Whh0b  = (const float*)d_in[9];
  const float* b0b    = (const float*)d_in[10];
  const float* Wih1f  = (const float*)d_in[11];
  const float* Whh1f  = (const float*)d_in[12];
  const float* b1f    = (const float*)d_in[13];
  const float* Wih1b  = (const float*)d_in[14];
  const float* Whh1b  = (const float*)d_in[15];
  const float* b1b    = (const float*)d_in[16];
  const float* fcW    = (const float*)d_in[17];
  const float* fcb    = (const float*)d_in[18];
  const float* trans  = (const float*)d_in[19];
  const float* startv = (const float*)d_in[20];
  const float* endv   = (const float*)d_in[21];

  char* p = (char*)d_ws;
  u16* buf0 = (u16*)p; p += (size_t)BT * Ee * 2;   // embeddings / layer-1 out
  u16* buf1 = (u16*)p; p += (size_t)BT * 256 * 2;  // layer-0 out
  u16* xpf  = (u16*)p; p += (size_t)BT * G4 * 2;   // fwd proj (lstm layout)
  u16* xpb  = (u16*)p; p += (size_t)BT * G4 * 2;   // bwd proj (lstm layout)
  u16* wb[4];
  for (int i = 0; i < 4; ++i) { wb[i] = (u16*)p; p += (size_t)512 * 256 * 2; }
  u16* fcwb = (u16*)p; p += (size_t)32 * 256 * 2;
  float* bias_p = (float*)p; p += 4 * 512 * 4;     // permuted biases
  float* emis = (float*)p; p += ((size_t)BT * Kk + 64 * Kk) * 4;  // +pad row
  float* nll  = (float*)p; p += 256;

  k_embprep<<<dim3(8192 + 528), dim3(256), 0, stream>>>(
      x, emb, buf0,
      Wih0f, Wih0b, Wih1f, Wih1b, wb[0], wb[1], wb[2], wb[3],
      fcW, fcwb, b0f, b0b, b1f, b1b, bias_p);

  dim3 ggrid(BT / 128, 8);
  // layer 0
  k_gemm4<<<ggrid, dim3(256), 0, stream>>>(buf0, wb[0], wb[1],
                                           bias_p, bias_p + 512, xpf, xpb);
  k_lstm9<<<dim3(32), dim3(512), 0, stream>>>(xpf, xpb, Whh0f, Whh0b, buf1);
  // layer 1
  k_gemm4<<<ggrid, dim3(256), 0, stream>>>(buf1, wb[2], wb[3],
                                           bias_p + 1024, bias_p + 1536, xpf, xpb);
  k_lstm9<<<dim3(32), dim3(512), 0, stream>>>(xpf, xpb, Whh1f, Whh1b, buf0);
  // emissions + CRF
  k_fc2<<<dim3(BT / 128), dim3(256), 0, stream>>>(buf0, fcwb, fcb, emis);
  k_crf<<<dim3(Bb), dim3(64), 0, stream>>>(emis, tags, trans, startv, endv, nll);
  k_reduce<<<dim3(1), dim3(64), 0, stream>>>(nll, (float*)d_out);
}

// Round 11
// 757.098 us; speedup vs baseline: 2.9387x; 1.0459x over previous
//
#include <hip/hip_runtime.h>
#include <stddef.h>

typedef unsigned short u16;
typedef unsigned int u32;

#define DEV __device__ __forceinline__

constexpr int Bb = 64;
constexpr int Tt = 512;
constexpr int Ee = 256;     // embedding dim == 2H (layer-1 input dim)
constexpr int Hh = 128;
constexpr int Kk = 32;
constexpr int G4 = 4 * Hh;  // 512 gates
constexpr int BT = Bb * Tt; // 32768 rows

DEV u16 f2b(float f) {
  u32 u = __builtin_bit_cast(u32, f);
  u += 0x7fffu + ((u >> 16) & 1u);   // round-to-nearest-even
  return (u16)(u >> 16);
}
DEV float b2f(u16 v) { return __builtin_bit_cast(float, (u32)v << 16); }
// fast reciprocal (v_rcp_f32, ~1 ulp): avoids IEEE div sequence (9 instrs)
DEV float rcp_(float x) { float r; asm("v_rcp_f32 %0, %1" : "=v"(r) : "v"(x)); return r; }
DEV float sigmoidf_(float x) { return rcp_(1.0f + __expf(-x)); }
DEV float tanhf_(float x) { return 1.0f - 2.0f * rcp_(1.0f + __expf(2.0f * x)); }

// async global->LDS, 16B per lane; LDS dest = wave-uniform base + lane*16
DEV void gload16(const void* g, void* l) {
  __builtin_amdgcn_global_load_lds(
      (const __attribute__((address_space(1))) void*)g,
      (__attribute__((address_space(3))) void*)l, 16, 0, 0);
}

// LDS-only barrier: does NOT drain vmcnt (T4: never vmcnt(0) in the loop).
DEV void lds_barrier() {
  asm volatile("s_waitcnt lgkmcnt(0)" ::: "memory");
  __builtin_amdgcn_sched_barrier(0);
  __builtin_amdgcn_s_barrier();
  __builtin_amdgcn_sched_barrier(0);
}

// ------- fused embed (blocks 0..8191) + weight prep (blocks 8192..8719) ---
__global__ __launch_bounds__(256) void k_embprep(
    const int* __restrict__ x, const float* __restrict__ emb,
    u16* __restrict__ eout,
    const float* __restrict__ W0, const float* __restrict__ W1,
    const float* __restrict__ W2, const float* __restrict__ W3,
    u16* __restrict__ d0, u16* __restrict__ d1,
    u16* __restrict__ d2, u16* __restrict__ d3,
    const float* __restrict__ fcW, u16* __restrict__ fcwb,
    const float* __restrict__ bi0, const float* __restrict__ bi1,
    const float* __restrict__ bi2, const float* __restrict__ bi3,
    float* __restrict__ bias_p) {
  int blk = blockIdx.x, tid = threadIdx.x;
  if (blk < 8192) {
    int m = blk * 4 + (tid >> 6);    // out row = t*64 + b
    int lane = tid & 63;
    int b = m & 63, t = m >> 6;
    int idx = x[b * Tt + t];
    float4 v = ((const float4*)(emb + (size_t)idx * Ee))[lane];
    uint2 p;
    p.x = (u32)f2b(v.x) | ((u32)f2b(v.y) << 16);
    p.y = (u32)f2b(v.z) | ((u32)f2b(v.w) << 16);
    ((uint2*)(eout + (size_t)m * Ee))[lane] = p;
    return;
  }
  blk -= 8192;
  if (blk < 512) {
    int a = blk >> 7;
    const float* s; u16* d;
    if (a == 0)      { s = W0; d = d0; }
    else if (a == 1) { s = W1; d = d1; }
    else if (a == 2) { s = W2; d = d2; }
    else             { s = W3; d = d3; }
    int i = (blk & 127) * 256 + tid;   // 32768 = 512 rows x 64 float4
    int np = i >> 6, k4 = i & 63;
    int src = (np & 3) * 128 + (np >> 2);
    float4 v = ((const float4*)(s + (size_t)src * 256))[k4];
    uint2 p;
    p.x = (u32)f2b(v.x) | ((u32)f2b(v.y) << 16);
    p.y = (u32)f2b(v.z) | ((u32)f2b(v.w) << 16);
    ((uint2*)(d + (size_t)np * 256))[k4] = p;
  } else if (blk < 520) {
    int i = (blk - 512) * 256 + tid;   // 2048 float4s = 32*256
    float4 v = ((const float4*)fcW)[i];
    uint2 p;
    p.x = (u32)f2b(v.x) | ((u32)f2b(v.y) << 16);
    p.y = (u32)f2b(v.z) | ((u32)f2b(v.w) << 16);
    ((uint2*)fcwb)[i] = p;
  } else {
    int i = (blk - 520) * 256 + tid;   // 2048 = 4 x 512
    int a = i >> 9, np = i & 511;
    const float* s;
    if (a == 0)      s = bi0;
    else if (a == 1) s = bi1;
    else if (a == 2) s = bi2;
    else             s = bi3;
    bias_p[i] = s[(np & 3) * 128 + (np >> 2)];
  }
}

// ---------------- MFMA GEMM v5: global_load_lds + XOR-swizzled LDS --------
// Linear LDS [128][64] u16 tiles (8 chunks of 16B per row). Slot (row,c)
// holds global chunk (c ^ (row&7)) -> staged by pre-swizzling the global
// source address; ds_read applies the same XOR (rule #21: both-sides).
// A-operand = Wp rows (np = j*4+g), B-operand = X rows (m = t*64+b), K=256.
// Lane's 4 regs = 4 gates of one (j, m) -> one uint2 store to lstm layout:
// flat = (t*16 + b/4)*2048 + j*16 + (b&3)*4 + g.
typedef __attribute__((ext_vector_type(8))) short bfrag;
typedef __attribute__((ext_vector_type(4))) float ffrag;

__global__ __launch_bounds__(256) void k_gemm5(const u16* __restrict__ X,
                                               const u16* __restrict__ Wp0,
                                               const u16* __restrict__ Wp1,
                                               const float* __restrict__ bp0,
                                               const float* __restrict__ bp1,
                                               u16* __restrict__ out0,
                                               u16* __restrict__ out1) {
  __shared__ __align__(16) u16 Xs[128 * 64];
  __shared__ __align__(16) u16 Ws[128 * 64];
  const int tid = threadIdx.x;
  const int bm = blockIdx.x * 128;            // m base
  const int sel = blockIdx.y >> 2;
  const int bnp = (blockIdx.y & 3) * 128;     // np base
  const u16* __restrict__ Wp = sel ? Wp1 : Wp0;
  const float* __restrict__ bp = sel ? bp1 : bp0;
  u16* __restrict__ outp = sel ? out1 : out0;
  const int w = tid >> 6;
  const int l = tid & 63;
  const int r16 = l & 15;
  const int q = l >> 4;
  const int wrN = (w >> 1) * 64;   // np quadrant
  const int wcM = (w & 1) * 64;    // m quadrant

  // staging geometry: wave w stages rows [32w, 32w+32) of each tile as
  // 4 chunks x (8 rows x 128B). lane -> row = chunkbase + l>>3, col = l&7;
  // global source chunk pre-swizzled: (l&7) ^ (row&7).
  const int srow = l >> 3;        // 0..7 within chunk
  const int scol = l & 7;

  ffrag acc[4][4];
#pragma unroll
  for (int i = 0; i < 4; ++i)
#pragma unroll
    for (int jn = 0; jn < 4; ++jn) acc[i][jn] = (ffrag)0.0f;

  for (int kt = 0; kt < 256; kt += 64) {
#pragma unroll
    for (int i = 0; i < 4; ++i) {
      int row = w * 32 + i * 8 + srow;
      int gcol = (scol ^ (row & 7)) << 3;         // u16 units
      gload16(&X[(size_t)(bm + row) * 256 + kt + gcol], &Xs[(w * 32 + i * 8) * 64]);
      gload16(&Wp[(size_t)(bnp + row) * 256 + kt + gcol], &Ws[(w * 32 + i * 8) * 64]);
    }
    __syncthreads();   // drains vmcnt -> staged tiles visible
#pragma unroll
    for (int kk = 0; kk < 2; ++kk) {
      bfrag af[4], bf[4];
#pragma unroll
      for (int fm = 0; fm < 4; ++fm) {
        int row = wrN + fm * 16 + r16;
        int ck = (kk * 4 + q) ^ (row & 7);
        af[fm] = *(const bfrag*)&Ws[row * 64 + ck * 8];
      }
#pragma unroll
      for (int fn = 0; fn < 4; ++fn) {
        int row = wcM + fn * 16 + r16;
        int ck = (kk * 4 + q) ^ (row & 7);
        bf[fn] = *(const bfrag*)&Xs[row * 64 + ck * 8];
      }
#pragma unroll
      for (int fm = 0; fm < 4; ++fm)
#pragma unroll
        for (int fn = 0; fn < 4; ++fn)
          acc[fm][fn] = __builtin_amdgcn_mfma_f32_16x16x32_bf16(
              af[fm], bf[fn], acc[fm][fn], 0, 0, 0);
    }
    __syncthreads();
  }
  const int Q = l >> 4;
#pragma unroll
  for (int fm = 0; fm < 4; ++fm) {
    int np0 = bnp + wrN + fm * 16 + 4 * Q;   // 4-aligned; regs = gates 0..3
    int j = np0 >> 2;
    float4 bv = *(const float4*)&bp[np0];
#pragma unroll
    for (int fn = 0; fn < 4; ++fn) {
      int m = bm + wcM + fn * 16 + r16;
      int t = m >> 6, bq = (m & 63) >> 2;
      size_t flat = ((size_t)t * 16 + bq) * 2048 + (size_t)j * 16 + (m & 3) * 4;
      float v0 = acc[fm][fn][0] + bv.x, v1 = acc[fm][fn][1] + bv.y;
      float v2 = acc[fm][fn][2] + bv.z, v3 = acc[fm][fn][3] + bv.w;
      u32 lo, hi;
      asm("v_cvt_pk_bf16_f32 %0, %1, %2" : "=v"(lo) : "v"(v0), "v"(v1));
      asm("v_cvt_pk_bf16_f32 %0, %1, %2" : "=v"(hi) : "v"(v2), "v"(v3));
      uint2 st; st.x = lo; st.y = hi;
      *(uint2*)&outp[flat] = st;
    }
  }
}

// ---------------- MFMA LSTM v9 (unchanged from round 10) ------------------
__global__ __launch_bounds__(512, 1) void k_lstm9(const u16* __restrict__ xpf,
                                                  const u16* __restrict__ xpb,
                                                  const float* __restrict__ whhf,
                                                  const float* __restrict__ whhb,
                                                  u16* __restrict__ out) {
  __shared__ u16 hbuf[2][4][128];     // dense; idx ^= (row&1)<<5 swizzle
  const int dir = blockIdx.x >> 4;
  const int wg = blockIdx.x & 15;     // batch quad: b = 4*wg + q
  const u16* __restrict__ xp = dir ? xpb : xpf;
  const float* __restrict__ whh = dir ? whhb : whhf;
  const int tid = threadIdx.x;
  const int w = tid >> 6;
  const int l = tid & 63;
  const int q = l >> 4;
  const int jw = l & 15;
  const int j = 16 * w + jw;

  for (int i = tid; i < 2 * 4 * 128; i += 512) (&hbuf[0][0][0])[i] = 0;

  bfrag wf[4][4];
#pragma unroll
  for (int g = 0; g < 4; ++g) {
    const float* rowp = whh + (size_t)(g * 128 + j) * 128;
#pragma unroll
    for (int ks = 0; ks < 4; ++ks) {
      float4 x0 = ((const float4*)(rowp + ks * 32 + q * 8))[0];
      float4 x1 = ((const float4*)(rowp + ks * 32 + q * 8))[1];
      bfrag t;
      t[0] = (short)f2b(x0.x); t[1] = (short)f2b(x0.y);
      t[2] = (short)f2b(x0.z); t[3] = (short)f2b(x0.w);
      t[4] = (short)f2b(x1.x); t[5] = (short)f2b(x1.y);
      t[6] = (short)f2b(x1.z); t[7] = (short)f2b(x1.w);
      wf[g][ks] = t;
    }
  }
  __syncthreads();

  const int dt = dir ? -1 : 1;
  const int tp0 = dir ? (Tt - 1) : 0;
  const size_t xoff = (size_t)wg * 2048 + (size_t)j * 16 + (size_t)q * 4;
  float cc = 0.f;
  int cur = 0;
  u16 hprev = 0;

  const bool ld_act = ((jw & 3) == 0);
  const int drow = jw >> 2;
  const int rsw = (drow & 1) << 5;
  const int wsw = (q & 1) << 5;
  bfrag hf0 = (bfrag)(short)0, hf1 = (bfrag)(short)0;
  bfrag hf2 = (bfrag)(short)0, hf3 = (bfrag)(short)0;

  uint2 xv[4];
#pragma unroll
  for (int d = 0; d < 4; ++d)
    xv[d] = *(const uint2*)&xp[(size_t)(tp0 + d * dt) * 32768 + xoff];

  const ptrdiff_t xstep = (ptrdiff_t)dt * 32768;
  const u16* pxq = xp + (size_t)(tp0 + 4 * dt) * 32768 + xoff;
  u16* optr = out + ((size_t)tp0 * 64 + 4 * wg + q) * 256 + (size_t)dir * 128 + j;
  const ptrdiff_t ostep = (ptrdiff_t)dt * 16384;

  for (int it = 0; it < Tt / 4; ++it) {
#pragma unroll
    for (int d = 0; d < 4; ++d) {
      if (it > 0 || d > 0) { *optr = hprev; optr += ostep; }

      if (ld_act) {
        const u16* hb = &hbuf[cur][drow][0];
        hf0 = *(const bfrag*)&hb[(0 * 32 + q * 8) ^ rsw];
        hf1 = *(const bfrag*)&hb[(1 * 32 + q * 8) ^ rsw];
        hf2 = *(const bfrag*)&hb[(2 * 32 + q * 8) ^ rsw];
        hf3 = *(const bfrag*)&hb[(3 * 32 + q * 8) ^ rsw];
      }

      ffrag a0 = __builtin_amdgcn_mfma_f32_16x16x32_bf16(hf0, wf[0][0], (ffrag)0.f, 0, 0, 0);
      ffrag a1 = __builtin_amdgcn_mfma_f32_16x16x32_bf16(hf0, wf[1][0], (ffrag)0.f, 0, 0, 0);
      ffrag a2 = __builtin_amdgcn_mfma_f32_16x16x32_bf16(hf0, wf[2][0], (ffrag)0.f, 0, 0, 0);
      ffrag a3 = __builtin_amdgcn_mfma_f32_16x16x32_bf16(hf0, wf[3][0], (ffrag)0.f, 0, 0, 0);
      a0 = __builtin_amdgcn_mfma_f32_16x16x32_bf16(hf1, wf[0][1], a0, 0, 0, 0);
      a1 = __builtin_amdgcn_mfma_f32_16x16x32_bf16(hf1, wf[1][1], a1, 0, 0, 0);
      a2 = __builtin_amdgcn_mfma_f32_16x16x32_bf16(hf1, wf[2][1], a2, 0, 0, 0);
      a3 = __builtin_amdgcn_mfma_f32_16x16x32_bf16(hf1, wf[3][1], a3, 0, 0, 0);
      a0 = __builtin_amdgcn_mfma_f32_16x16x32_bf16(hf2, wf[0][2], a0, 0, 0, 0);
      a1 = __builtin_amdgcn_mfma_f32_16x16x32_bf16(hf2, wf[1][2], a1, 0, 0, 0);
      a2 = __builtin_amdgcn_mfma_f32_16x16x32_bf16(hf2, wf[2][2], a2, 0, 0, 0);
      a3 = __builtin_amdgcn_mfma_f32_16x16x32_bf16(hf2, wf[3][2], a3, 0, 0, 0);
      a0 = __builtin_amdgcn_mfma_f32_16x16x32_bf16(hf3, wf[0][3], a0, 0, 0, 0);
      a1 = __builtin_amdgcn_mfma_f32_16x16x32_bf16(hf3, wf[1][3], a1, 0, 0, 0);
      a2 = __builtin_amdgcn_mfma_f32_16x16x32_bf16(hf3, wf[2][3], a2, 0, 0, 0);
      a3 = __builtin_amdgcn_mfma_f32_16x16x32_bf16(hf3, wf[3][3], a3, 0, 0, 0);

      float gi = a0[0] + b2f((u16)xv[d].x);
      float gf = a1[0] + b2f((u16)(xv[d].x >> 16));
      float gg = a2[0] + b2f((u16)xv[d].y);
      float go = a3[0] + b2f((u16)(xv[d].y >> 16));
      cc = sigmoidf_(gf) * cc + sigmoidf_(gi) * tanhf_(gg);
      float h = sigmoidf_(go) * tanhf_(cc);
      u16 hv = f2b(h);

      hbuf[cur ^ 1][q][j ^ wsw] = hv;
      hprev = hv;

      xv[d] = *(const uint2*)pxq;
      pxq += xstep;

      lds_barrier();
      cur ^= 1;
    }
  }
  *optr = hprev;
}

// ---------------- FC v2 (MFMA): emis = X @ fcW^T + fcb (fp32 out) ---------
__global__ __launch_bounds__(256) void k_fc2(const u16* __restrict__ X,
                                             const u16* __restrict__ Wc,
                                             const float* __restrict__ bias,
                                             float* __restrict__ emis) {
  constexpr int LDT = 72;
  __shared__ u16 Xs[128 * LDT];
  __shared__ u16 Ws[32 * LDT];
  const int tid = threadIdx.x;
  const int bm = blockIdx.x * 128;
  const int w = tid >> 6;
  const int l = tid & 63;
  const int r16 = l & 15;
  const int k8 = (l >> 4) << 3;

  ffrag acc[2][2];
#pragma unroll
  for (int i = 0; i < 2; ++i)
#pragma unroll
    for (int jn = 0; jn < 2; ++jn) acc[i][jn] = (ffrag)0.0f;

  for (int kt = 0; kt < 256; kt += 64) {
#pragma unroll
    for (int c = 0; c < 4; ++c) {   // X tile: 128x64
      int ch = tid + 256 * c;
      int row = ch >> 3, c8 = (ch & 7) << 3;
      *(uint4*)&Xs[row * LDT + c8] =
          *(const uint4*)&X[(size_t)(bm + row) * 256 + kt + c8];
    }
    {                               // fcW tile: 32x64 = 256 chunks
      int row = tid >> 3, c8 = (tid & 7) << 3;
      *(uint4*)&Ws[row * LDT + c8] =
          *(const uint4*)&Wc[(size_t)row * 256 + kt + c8];
    }
    __syncthreads();
#pragma unroll
    for (int kk = 0; kk < 2; ++kk) {
      bfrag af[2], bf[2];
#pragma unroll
      for (int fm = 0; fm < 2; ++fm)
        af[fm] = *(const bfrag*)&Xs[(32 * w + fm * 16 + r16) * LDT + kk * 32 + k8];
#pragma unroll
      for (int fn = 0; fn < 2; ++fn)
        bf[fn] = *(const bfrag*)&Ws[(fn * 16 + r16) * LDT + kk * 32 + k8];
#pragma unroll
      for (int fm = 0; fm < 2; ++fm)
#pragma unroll
        for (int fn = 0; fn < 2; ++fn)
          acc[fm][fn] = __builtin_amdgcn_mfma_f32_16x16x32_bf16(
              af[fm], bf[fn], acc[fm][fn], 0, 0, 0);
    }
    __syncthreads();
  }
  const int rbase = (l >> 4) * 4;
#pragma unroll
  for (int fm = 0; fm < 2; ++fm)
#pragma unroll
    for (int fn = 0; fn < 2; ++fn) {
      int cj = fn * 16 + r16;
      float bv = bias[cj];
#pragma unroll
      for (int r = 0; r < 4; ++r) {
        int m = bm + 32 * w + fm * 16 + rbase + r;
        emis[(size_t)m * Kk + cj] = acc[fm][fn][r] + bv;
      }
    }
}

// ---------------- CRF v4: precomputed exp(trans), single-exp step ---------
__global__ __launch_bounds__(64) void k_crf(const float* __restrict__ emis,
                                            const int* __restrict__ tags,
                                            const float* __restrict__ trans,
                                            const float* __restrict__ startv,
                                            const float* __restrict__ endv,
                                            float* __restrict__ nll) {
  __shared__ float tr[Kk * Kk];
  const int b = blockIdx.x;
  const int l = threadIdx.x;
  const int j = l & 31;
  const int half = l >> 5;
  for (int i = l; i < Kk * Kk; i += 64) tr[i] = trans[i];
  float E_r[16];
#pragma unroll
  for (int i = 0; i < 16; ++i) E_r[i] = __expf(trans[(half * 16 + i) * Kk + j]);
  const float* eb = emis + (size_t)b * Kk;   // stride per t = 64*Kk = 2048
  float aj = startv[j] + eb[j];
  float ebc = eb[2048 + j];
  __syncthreads();

  for (int t = 1; t < Tt; ++t) {
    float ebn = eb[(size_t)(t + 1) * 2048 + j];  // t+1==512 hits pad row
    float m = aj;
    m = fmaxf(m, __shfl_xor(m, 16));
    m = fmaxf(m, __shfl_xor(m, 8));
    m = fmaxf(m, __shfl_xor(m, 4));
    m = fmaxf(m, __shfl_xor(m, 2));
    m = fmaxf(m, __shfl_xor(m, 1));
    float p = __expf(aj - m);          // the ONLY exp in the loop
    float c0 = 0.f, c1 = 0.f, c2 = 0.f, c3 = 0.f;
#pragma unroll
    for (int i = 0; i < 16; i += 4) {
      c0 = fmaf(__shfl(p, half * 16 + i),     E_r[i],     c0);
      c1 = fmaf(__shfl(p, half * 16 + i + 1), E_r[i + 1], c1);
      c2 = fmaf(__shfl(p, half * 16 + i + 2), E_r[i + 2], c2);
      c3 = fmaf(__shfl(p, half * 16 + i + 3), E_r[i + 3], c3);
    }
    float s = (c0 + c1) + (c2 + c3);
    s += __shfl_xor(s, 32);            // combine the two i-halves
    aj = ebc + m + __logf(s);
    ebc = ebn;
  }

  float val = aj + endv[j];           // both halves hold identical val(j)
  float M = val;
#pragma unroll
  for (int off = 16; off > 0; off >>= 1) M = fmaxf(M, __shfl_xor(M, off));
  float sz = __expf(val - M);
#pragma unroll
  for (int off = 16; off > 0; off >>= 1) sz += __shfl_xor(sz, off);
  float logZ = M + __logf(sz);

  const int* tg = tags + (size_t)b * Tt;
  float g = 0.f;
  for (int t = l; t < Tt; t += 64) {
    int cur = tg[t];
    g += eb[(size_t)t * 2048 + cur];
    if (t >= 1) g += tr[cur * Kk + tg[t - 1]];
  }
#pragma unroll
  for (int off = 32; off > 0; off >>= 1) g += __shfl_xor(g, off);
  if (l == 0) {
    g += startv[tg[0]] + endv[tg[Tt - 1]];
    nll[b] = logZ - g;
  }
}

__global__ void k_reduce(const float* __restrict__ nll, float* __restrict__ out) {
  float v = nll[threadIdx.x];
#pragma unroll
  for (int off = 32; off > 0; off >>= 1) v += __shfl_xor(v, off);
  if (threadIdx.x == 0) out[0] = v * (1.0f / 64.0f);
}

// --------------------------------------------------------------------------
extern "C" void kernel_launch(void* const* d_in, const int* in_sizes, int n_in,
                              void* d_out, int out_size, void* d_ws, size_t ws_size,
                              hipStream_t stream) {
  (void)in_sizes; (void)n_in; (void)out_size; (void)ws_size;
  const int*   x      = (const int*)d_in[0];
  const int*   tags   = (const int*)d_in[2];
  const float* emb    = (const float*)d_in[4];
  const float* Wih0f  = (const float*)d_in[5];
  const float* Whh0f  = (const float*)d_in[6];
  const float* b0f    = (const float*)d_in[7];
  const float* Wih0b  = (const float*)d_in[8];
  const float* Whh0b  = (const float*)d_in[9];
  const float* b0b    = (const float*)d_in[10];
  const float* Wih1f  = (const float*)d_in[11];
  const float* Whh1f  = (const float*)d_in[12];
  const float* b1f    = (const float*)d_in[13];
  const float* Wih1b  = (const float*)d_in[14];
  const float* Whh1b  = (const float*)d_in[15];
  const float* b1b    = (const float*)d_in[16];
  const float* fcW    = (const float*)d_in[17];
  const float* fcb    = (const float*)d_in[18];
  const float* trans  = (const float*)d_in[19];
  const float* startv = (const float*)d_in[20];
  const float* endv   = (const float*)d_in[21];

  char* p = (char*)d_ws;
  u16* buf0 = (u16*)p; p += (size_t)BT * Ee * 2;   // embeddings / layer-1 out
  u16* buf1 = (u16*)p; p += (size_t)BT * 256 * 2;  // layer-0 out
  u16* xpf  = (u16*)p; p += (size_t)BT * G4 * 2;   // fwd proj (lstm layout)
  u16* xpb  = (u16*)p; p += (size_t)BT * G4 * 2;   // bwd proj (lstm layout)
  u16* wb[4];
  for (int i = 0; i < 4; ++i) { wb[i] = (u16*)p; p += (size_t)512 * 256 * 2; }
  u16* fcwb = (u16*)p; p += (size_t)32 * 256 * 2;
  float* bias_p = (float*)p; p += 4 * 512 * 4;     // permuted biases
  float* emis = (float*)p; p += ((size_t)BT * Kk + 64 * Kk) * 4;  // +pad row
  float* nll  = (float*)p; p += 256;

  k_embprep<<<dim3(8192 + 528), dim3(256), 0, stream>>>(
      x, emb, buf0,
      Wih0f, Wih0b, Wih1f, Wih1b, wb[0], wb[1], wb[2], wb[3],
      fcW, fcwb, b0f, b0b, b1f, b1b, bias_p);

  dim3 ggrid(BT / 128, 8);
  // layer 0
  k_gemm5<<<ggrid, dim3(256), 0, stream>>>(buf0, wb[0], wb[1],
                                           bias_p, bias_p + 512, xpf, xpb);
  k_lstm9<<<dim3(32), dim3(512), 0, stream>>>(xpf, xpb, Whh0f, Whh0b, buf1);
  // layer 1
  k_gemm5<<<ggrid, dim3(256), 0, stream>>>(buf1, wb[2], wb[3],
                                           bias_p + 1024, bias_p + 1536, xpf, xpb);
  k_lstm9<<<dim3(32), dim3(512), 0, stream>>>(xpf, xpb, Whh1f, Whh1b, buf0);
  // emissions + CRF
  k_fc2<<<dim3(BT / 128), dim3(256), 0, stream>>>(buf0, fcwb, fcb, emis);
  k_crf<<<dim3(Bb), dim3(64), 0, stream>>>(emis, tags, trans, startv, endv, nll);
  k_reduce<<<dim3(1), dim3(64), 0, stream>>>(nll, (float*)d_out);
}

// Round 12
// 709.006 us; speedup vs baseline: 3.1381x; 1.0678x over previous
//
#include <hip/hip_runtime.h>
#include <stddef.h>

typedef unsigned short u16;
typedef unsigned int u32;

#define DEV __device__ __forceinline__

constexpr int Bb = 64;
constexpr int Tt = 512;
constexpr int Ee = 256;     // embedding dim == 2H (layer-1 input dim)
constexpr int Hh = 128;
constexpr int Kk = 32;
constexpr int G4 = 4 * Hh;  // 512 gates
constexpr int BT = Bb * Tt; // 32768 rows
constexpr float L2E = 1.44269504f;   // log2(e)

DEV u16 f2b(float f) {
  u32 u = __builtin_bit_cast(u32, f);
  u += 0x7fffu + ((u >> 16) & 1u);   // round-to-nearest-even
  return (u16)(u >> 16);
}
DEV float b2f(u16 v) { return __builtin_bit_cast(float, (u32)v << 16); }
// fast reciprocal (v_rcp_f32, ~1 ulp) and raw exp2 (v_exp_f32 IS 2^x)
DEV float rcp_(float x) { float r; asm("v_rcp_f32 %0, %1" : "=v"(r) : "v"(x)); return r; }
DEV float exp2_(float x) { float r; asm("v_exp_f32 %0, %1" : "=v"(r) : "v"(x)); return r; }

// async global->LDS, 16B per lane; LDS dest = wave-uniform base + lane*16
DEV void gload16(const void* g, void* l) {
  __builtin_amdgcn_global_load_lds(
      (const __attribute__((address_space(1))) void*)g,
      (__attribute__((address_space(3))) void*)l, 16, 0, 0);
}

// LDS-only barrier: does NOT drain vmcnt (T4: never vmcnt(0) in the loop).
DEV void lds_barrier() {
  asm volatile("s_waitcnt lgkmcnt(0)" ::: "memory");
  __builtin_amdgcn_sched_barrier(0);
  __builtin_amdgcn_s_barrier();
  __builtin_amdgcn_sched_barrier(0);
}

// ------- fused embed (blocks 0..8191) + weight prep (blocks 8192..8719) ---
// Wih weights and biases are pre-scaled by log2(e) so the LSTM gate
// pre-activations arrive ready for raw v_exp_f32 (exp2) activations.
__global__ __launch_bounds__(256) void k_embprep(
    const int* __restrict__ x, const float* __restrict__ emb,
    u16* __restrict__ eout,
    const float* __restrict__ W0, const float* __restrict__ W1,
    const float* __restrict__ W2, const float* __restrict__ W3,
    u16* __restrict__ d0, u16* __restrict__ d1,
    u16* __restrict__ d2, u16* __restrict__ d3,
    const float* __restrict__ fcW, u16* __restrict__ fcwb,
    const float* __restrict__ bi0, const float* __restrict__ bi1,
    const float* __restrict__ bi2, const float* __restrict__ bi3,
    float* __restrict__ bias_p) {
  int blk = blockIdx.x, tid = threadIdx.x;
  if (blk < 8192) {
    int m = blk * 4 + (tid >> 6);    // out row = t*64 + b
    int lane = tid & 63;
    int b = m & 63, t = m >> 6;
    int idx = x[b * Tt + t];
    float4 v = ((const float4*)(emb + (size_t)idx * Ee))[lane];
    uint2 p;
    p.x = (u32)f2b(v.x) | ((u32)f2b(v.y) << 16);
    p.y = (u32)f2b(v.z) | ((u32)f2b(v.w) << 16);
    ((uint2*)(eout + (size_t)m * Ee))[lane] = p;
    return;
  }
  blk -= 8192;
  if (blk < 512) {
    int a = blk >> 7;
    const float* s; u16* d;
    if (a == 0)      { s = W0; d = d0; }
    else if (a == 1) { s = W1; d = d1; }
    else if (a == 2) { s = W2; d = d2; }
    else             { s = W3; d = d3; }
    int i = (blk & 127) * 256 + tid;   // 32768 = 512 rows x 64 float4
    int np = i >> 6, k4 = i & 63;
    int src = (np & 3) * 128 + (np >> 2);
    float4 v = ((const float4*)(s + (size_t)src * 256))[k4];
    uint2 p;
    p.x = (u32)f2b(v.x * L2E) | ((u32)f2b(v.y * L2E) << 16);
    p.y = (u32)f2b(v.z * L2E) | ((u32)f2b(v.w * L2E) << 16);
    ((uint2*)(d + (size_t)np * 256))[k4] = p;
  } else if (blk < 520) {
    int i = (blk - 512) * 256 + tid;   // 2048 float4s = 32*256
    float4 v = ((const float4*)fcW)[i];
    uint2 p;
    p.x = (u32)f2b(v.x) | ((u32)f2b(v.y) << 16);
    p.y = (u32)f2b(v.z) | ((u32)f2b(v.w) << 16);
    ((uint2*)fcwb)[i] = p;
  } else {
    int i = (blk - 520) * 256 + tid;   // 2048 = 4 x 512
    int a = i >> 9, np = i & 511;
    const float* s;
    if (a == 0)      s = bi0;
    else if (a == 1) s = bi1;
    else if (a == 2) s = bi2;
    else             s = bi3;
    bias_p[i] = s[(np & 3) * 128 + (np >> 2)] * L2E;
  }
}

// ---------------- MFMA GEMM v6: BM=256, global_load_lds, XOR swizzle ------
// A-operand = Wp rows (np = j*4+g, 128/block), B-operand = X rows (m, 256).
// 512 threads, 8 waves: wave = (w>>2) np-half x (w&3) m-quadrant.
// LDS 48 KB; lane's 4 regs = 4 gates of one (j,m) -> one uint2 store.
typedef __attribute__((ext_vector_type(8))) short bfrag;
typedef __attribute__((ext_vector_type(4))) float ffrag;

__global__ __launch_bounds__(512) void k_gemm6(const u16* __restrict__ X,
                                               const u16* __restrict__ Wp0,
                                               const u16* __restrict__ Wp1,
                                               const float* __restrict__ bp0,
                                               const float* __restrict__ bp1,
                                               u16* __restrict__ out0,
                                               u16* __restrict__ out1) {
  __shared__ __align__(16) u16 Xs[256 * 64];   // 32 KB
  __shared__ __align__(16) u16 Ws[128 * 64];   // 16 KB
  const int tid = threadIdx.x;
  const int bm = blockIdx.x * 256;            // m base
  const int sel = blockIdx.y >> 2;
  const int bnp = (blockIdx.y & 3) * 128;     // np base
  const u16* __restrict__ Wp = sel ? Wp1 : Wp0;
  const float* __restrict__ bp = sel ? bp1 : bp0;
  u16* __restrict__ outp = sel ? out1 : out0;
  const int w = tid >> 6;
  const int l = tid & 63;
  const int r16 = l & 15;
  const int q = l >> 4;
  const int wrN = (w >> 2) * 64;   // np half
  const int wcM = (w & 3) * 64;    // m quadrant
  const int srow = l >> 3;         // staging row within 8-row chunk
  const int scol = l & 7;

  ffrag acc[4][4];
#pragma unroll
  for (int i = 0; i < 4; ++i)
#pragma unroll
    for (int jn = 0; jn < 4; ++jn) acc[i][jn] = (ffrag)0.0f;

  for (int kt = 0; kt < 256; kt += 64) {
#pragma unroll
    for (int i = 0; i < 4; ++i) {            // X: rows [w*32, w*32+32)
      int row = w * 32 + i * 8 + srow;
      int gcol = (scol ^ (srow & 7)) << 3;   // row&7 == srow
      gload16(&X[(size_t)(bm + row) * 256 + kt + gcol], &Xs[(w * 32 + i * 8) * 64]);
    }
#pragma unroll
    for (int i = 0; i < 2; ++i) {            // Wp: rows [w*16, w*16+16)
      int row = w * 16 + i * 8 + srow;
      int gcol = (scol ^ (srow & 7)) << 3;
      gload16(&Wp[(size_t)(bnp + row) * 256 + kt + gcol], &Ws[(w * 16 + i * 8) * 64]);
    }
    __syncthreads();   // drains vmcnt -> staged tiles visible
#pragma unroll
    for (int kk = 0; kk < 2; ++kk) {
      bfrag af[4], bf[4];
#pragma unroll
      for (int fm = 0; fm < 4; ++fm) {
        int row = wrN + fm * 16 + r16;
        int ck = (kk * 4 + q) ^ (row & 7);
        af[fm] = *(const bfrag*)&Ws[row * 64 + ck * 8];
      }
#pragma unroll
      for (int fn = 0; fn < 4; ++fn) {
        int row = wcM + fn * 16 + r16;
        int ck = (kk * 4 + q) ^ (row & 7);
        bf[fn] = *(const bfrag*)&Xs[row * 64 + ck * 8];
      }
#pragma unroll
      for (int fm = 0; fm < 4; ++fm)
#pragma unroll
        for (int fn = 0; fn < 4; ++fn)
          acc[fm][fn] = __builtin_amdgcn_mfma_f32_16x16x32_bf16(
              af[fm], bf[fn], acc[fm][fn], 0, 0, 0);
    }
    __syncthreads();
  }
  const int Q = l >> 4;
#pragma unroll
  for (int fm = 0; fm < 4; ++fm) {
    int np0 = bnp + wrN + fm * 16 + 4 * Q;   // 4-aligned; regs = gates 0..3
    int j = np0 >> 2;
    float4 bv = *(const float4*)&bp[np0];
#pragma unroll
    for (int fn = 0; fn < 4; ++fn) {
      int m = bm + wcM + fn * 16 + r16;
      int t = m >> 6, bq = (m & 63) >> 2;
      size_t flat = ((size_t)t * 16 + bq) * 2048 + (size_t)j * 16 + (m & 3) * 4;
      float v0 = acc[fm][fn][0] + bv.x, v1 = acc[fm][fn][1] + bv.y;
      float v2 = acc[fm][fn][2] + bv.z, v3 = acc[fm][fn][3] + bv.w;
      u32 lo, hi;
      asm("v_cvt_pk_bf16_f32 %0, %1, %2" : "=v"(lo) : "v"(v0), "v"(v1));
      asm("v_cvt_pk_bf16_f32 %0, %1, %2" : "=v"(hi) : "v"(v2), "v"(v3));
      uint2 st; st.x = lo; st.y = hi;
      *(uint2*)&outp[flat] = st;
    }
  }
}

// ---------------- MFMA LSTM v10: v9 + exp2-scaled activations -------------
// Gates arrive pre-scaled by log2(e) (Wih/bias scaled in prep, Whh scaled
// here), so sigmoid/tanh use raw v_exp_f32 with no input multiply.
__global__ __launch_bounds__(512, 1) void k_lstm10(const u16* __restrict__ xpf,
                                                   const u16* __restrict__ xpb,
                                                   const float* __restrict__ whhf,
                                                   const float* __restrict__ whhb,
                                                   u16* __restrict__ out) {
  __shared__ u16 hbuf[2][4][128];     // dense; idx ^= (row&1)<<5 swizzle
  const int dir = blockIdx.x >> 4;
  const int wg = blockIdx.x & 15;     // batch quad: b = 4*wg + q
  const u16* __restrict__ xp = dir ? xpb : xpf;
  const float* __restrict__ whh = dir ? whhb : whhf;
  const int tid = threadIdx.x;
  const int w = tid >> 6;
  const int l = tid & 63;
  const int q = l >> 4;
  const int jw = l & 15;
  const int j = 16 * w + jw;

  for (int i = tid; i < 2 * 4 * 128; i += 512) (&hbuf[0][0][0])[i] = 0;

  bfrag wf[4][4];
#pragma unroll
  for (int g = 0; g < 4; ++g) {
    const float* rowp = whh + (size_t)(g * 128 + j) * 128;
#pragma unroll
    for (int ks = 0; ks < 4; ++ks) {
      float4 x0 = ((const float4*)(rowp + ks * 32 + q * 8))[0];
      float4 x1 = ((const float4*)(rowp + ks * 32 + q * 8))[1];
      bfrag t;
      t[0] = (short)f2b(x0.x * L2E); t[1] = (short)f2b(x0.y * L2E);
      t[2] = (short)f2b(x0.z * L2E); t[3] = (short)f2b(x0.w * L2E);
      t[4] = (short)f2b(x1.x * L2E); t[5] = (short)f2b(x1.y * L2E);
      t[6] = (short)f2b(x1.z * L2E); t[7] = (short)f2b(x1.w * L2E);
      wf[g][ks] = t;
    }
  }
  __syncthreads();

  const int dt = dir ? -1 : 1;
  const int tp0 = dir ? (Tt - 1) : 0;
  const size_t xoff = (size_t)wg * 2048 + (size_t)j * 16 + (size_t)q * 4;
  float cc = 0.f;
  int cur = 0;
  u16 hprev = 0;

  const bool ld_act = ((jw & 3) == 0);
  const int drow = jw >> 2;
  const int rsw = (drow & 1) << 5;
  const int wsw = (q & 1) << 5;
  bfrag hf0 = (bfrag)(short)0, hf1 = (bfrag)(short)0;
  bfrag hf2 = (bfrag)(short)0, hf3 = (bfrag)(short)0;

  uint2 xv[4];
#pragma unroll
  for (int d = 0; d < 4; ++d)
    xv[d] = *(const uint2*)&xp[(size_t)(tp0 + d * dt) * 32768 + xoff];

  const ptrdiff_t xstep = (ptrdiff_t)dt * 32768;
  const u16* pxq = xp + (size_t)(tp0 + 4 * dt) * 32768 + xoff;
  u16* optr = out + ((size_t)tp0 * 64 + 4 * wg + q) * 256 + (size_t)dir * 128 + j;
  const ptrdiff_t ostep = (ptrdiff_t)dt * 16384;

  for (int it = 0; it < Tt / 4; ++it) {
#pragma unroll
    for (int d = 0; d < 4; ++d) {
      if (it > 0 || d > 0) { *optr = hprev; optr += ostep; }

      if (ld_act) {
        const u16* hb = &hbuf[cur][drow][0];
        hf0 = *(const bfrag*)&hb[(0 * 32 + q * 8) ^ rsw];
        hf1 = *(const bfrag*)&hb[(1 * 32 + q * 8) ^ rsw];
        hf2 = *(const bfrag*)&hb[(2 * 32 + q * 8) ^ rsw];
        hf3 = *(const bfrag*)&hb[(3 * 32 + q * 8) ^ rsw];
      }

      ffrag a0 = __builtin_amdgcn_mfma_f32_16x16x32_bf16(hf0, wf[0][0], (ffrag)0.f, 0, 0, 0);
      ffrag a1 = __builtin_amdgcn_mfma_f32_16x16x32_bf16(hf0, wf[1][0], (ffrag)0.f, 0, 0, 0);
      ffrag a2 = __builtin_amdgcn_mfma_f32_16x16x32_bf16(hf0, wf[2][0], (ffrag)0.f, 0, 0, 0);
      ffrag a3 = __builtin_amdgcn_mfma_f32_16x16x32_bf16(hf0, wf[3][0], (ffrag)0.f, 0, 0, 0);
      a0 = __builtin_amdgcn_mfma_f32_16x16x32_bf16(hf1, wf[0][1], a0, 0, 0, 0);
      a1 = __builtin_amdgcn_mfma_f32_16x16x32_bf16(hf1, wf[1][1], a1, 0, 0, 0);
      a2 = __builtin_amdgcn_mfma_f32_16x16x32_bf16(hf1, wf[2][1], a2, 0, 0, 0);
      a3 = __builtin_amdgcn_mfma_f32_16x16x32_bf16(hf1, wf[3][1], a3, 0, 0, 0);
      a0 = __builtin_amdgcn_mfma_f32_16x16x32_bf16(hf2, wf[0][2], a0, 0, 0, 0);
      a1 = __builtin_amdgcn_mfma_f32_16x16x32_bf16(hf2, wf[1][2], a1, 0, 0, 0);
      a2 = __builtin_amdgcn_mfma_f32_16x16x32_bf16(hf2, wf[2][2], a2, 0, 0, 0);
      a3 = __builtin_amdgcn_mfma_f32_16x16x32_bf16(hf2, wf[3][2], a3, 0, 0, 0);
      a0 = __builtin_amdgcn_mfma_f32_16x16x32_bf16(hf3, wf[0][3], a0, 0, 0, 0);
      a1 = __builtin_amdgcn_mfma_f32_16x16x32_bf16(hf3, wf[1][3], a1, 0, 0, 0);
      a2 = __builtin_amdgcn_mfma_f32_16x16x32_bf16(hf3, wf[2][3], a2, 0, 0, 0);
      a3 = __builtin_amdgcn_mfma_f32_16x16x32_bf16(hf3, wf[3][3], a3, 0, 0, 0);

      // gates pre-scaled by log2(e): raw exp2 activations
      float gi = a0[0] + b2f((u16)xv[d].x);
      float gf = a1[0] + b2f((u16)(xv[d].x >> 16));
      float gg = a2[0] + b2f((u16)xv[d].y);
      float go = a3[0] + b2f((u16)(xv[d].y >> 16));
      float sf = rcp_(1.0f + exp2_(-gf));
      float si = rcp_(1.0f + exp2_(-gi));
      float tg = 1.0f - 2.0f * rcp_(1.0f + exp2_(gg + gg));
      float so = rcp_(1.0f + exp2_(-go));
      cc = sf * cc + si * tg;
      float th = 1.0f - 2.0f * rcp_(1.0f + exp2_(2.88539008f * cc));
      float h = so * th;
      u16 hv = f2b(h);

      hbuf[cur ^ 1][q][j ^ wsw] = hv;
      hprev = hv;

      xv[d] = *(const uint2*)pxq;
      pxq += xstep;

      lds_barrier();
      cur ^= 1;
    }
  }
  *optr = hprev;
}

// ---------------- FC v2 (MFMA): emis = X @ fcW^T + fcb (fp32 out) ---------
__global__ __launch_bounds__(256) void k_fc2(const u16* __restrict__ X,
                                             const u16* __restrict__ Wc,
                                             const float* __restrict__ bias,
                                             float* __restrict__ emis) {
  constexpr int LDT = 72;
  __shared__ u16 Xs[128 * LDT];
  __shared__ u16 Ws[32 * LDT];
  const int tid = threadIdx.x;
  const int bm = blockIdx.x * 128;
  const int w = tid >> 6;
  const int l = tid & 63;
  const int r16 = l & 15;
  const int k8 = (l >> 4) << 3;

  ffrag acc[2][2];
#pragma unroll
  for (int i = 0; i < 2; ++i)
#pragma unroll
    for (int jn = 0; jn < 2; ++jn) acc[i][jn] = (ffrag)0.0f;

  for (int kt = 0; kt < 256; kt += 64) {
#pragma unroll
    for (int c = 0; c < 4; ++c) {   // X tile: 128x64
      int ch = tid + 256 * c;
      int row = ch >> 3, c8 = (ch & 7) << 3;
      *(uint4*)&Xs[row * LDT + c8] =
          *(const uint4*)&X[(size_t)(bm + row) * 256 + kt + c8];
    }
    {                               // fcW tile: 32x64 = 256 chunks
      int row = tid >> 3, c8 = (tid & 7) << 3;
      *(uint4*)&Ws[row * LDT + c8] =
          *(const uint4*)&Wc[(size_t)row * 256 + kt + c8];
    }
    __syncthreads();
#pragma unroll
    for (int kk = 0; kk < 2; ++kk) {
      bfrag af[2], bf[2];
#pragma unroll
      for (int fm = 0; fm < 2; ++fm)
        af[fm] = *(const bfrag*)&Xs[(32 * w + fm * 16 + r16) * LDT + kk * 32 + k8];
#pragma unroll
      for (int fn = 0; fn < 2; ++fn)
        bf[fn] = *(const bfrag*)&Ws[(fn * 16 + r16) * LDT + kk * 32 + k8];
#pragma unroll
      for (int fm = 0; fm < 2; ++fm)
#pragma unroll
        for (int fn = 0; fn < 2; ++fn)
          acc[fm][fn] = __builtin_amdgcn_mfma_f32_16x16x32_bf16(
              af[fm], bf[fn], acc[fm][fn], 0, 0, 0);
    }
    __syncthreads();
  }
  const int rbase = (l >> 4) * 4;
#pragma unroll
  for (int fm = 0; fm < 2; ++fm)
#pragma unroll
    for (int fn = 0; fn < 2; ++fn) {
      int cj = fn * 16 + r16;
      float bv = bias[cj];
#pragma unroll
      for (int r = 0; r < 4; ++r) {
        int m = bm + 32 * w + fm * 16 + rbase + r;
        emis[(size_t)m * Kk + cj] = acc[fm][fn][r] + bv;
      }
    }
}

// ---------------- CRF v5: exp(trans) regs + defer-max (T13) ---------------
// m refreshed only when __any(aj - m > 30): exp(aj-m) <= e^30, s fp32-safe.
__global__ __launch_bounds__(64) void k_crf(const float* __restrict__ emis,
                                            const int* __restrict__ tags,
                                            const float* __restrict__ trans,
                                            const float* __restrict__ startv,
                                            const float* __restrict__ endv,
                                            float* __restrict__ nll) {
  __shared__ float tr[Kk * Kk];
  const int b = blockIdx.x;
  const int l = threadIdx.x;
  const int j = l & 31;
  const int half = l >> 5;
  for (int i = l; i < Kk * Kk; i += 64) tr[i] = trans[i];
  float E_r[16];
#pragma unroll
  for (int i = 0; i < 16; ++i) E_r[i] = __expf(trans[(half * 16 + i) * Kk + j]);
  const float* eb = emis + (size_t)b * Kk;   // stride per t = 64*Kk = 2048
  float aj = startv[j] + eb[j];
  float ebc = eb[2048 + j];
  __syncthreads();

  // initial max
  float m = aj;
#pragma unroll
  for (int off = 16; off > 0; off >>= 1) m = fmaxf(m, __shfl_xor(m, off));

  for (int t = 1; t < Tt; ++t) {
    float ebn = eb[(size_t)(t + 1) * 2048 + j];  // t+1==512 hits pad row
    if (__any(aj - m > 30.0f)) {                 // defer-max refresh
      m = aj;
      m = fmaxf(m, __shfl_xor(m, 16));
      m = fmaxf(m, __shfl_xor(m, 8));
      m = fmaxf(m, __shfl_xor(m, 4));
      m = fmaxf(m, __shfl_xor(m, 2));
      m = fmaxf(m, __shfl_xor(m, 1));
    }
    float p = __expf(aj - m);          // the ONLY exp in the loop
    float c0 = 0.f, c1 = 0.f, c2 = 0.f, c3 = 0.f;
#pragma unroll
    for (int i = 0; i < 16; i += 4) {
      c0 = fmaf(__shfl(p, half * 16 + i),     E_r[i],     c0);
      c1 = fmaf(__shfl(p, half * 16 + i + 1), E_r[i + 1], c1);
      c2 = fmaf(__shfl(p, half * 16 + i + 2), E_r[i + 2], c2);
      c3 = fmaf(__shfl(p, half * 16 + i + 3), E_r[i + 3], c3);
    }
    float s = (c0 + c1) + (c2 + c3);
    s += __shfl_xor(s, 32);            // combine the two i-halves
    aj = ebc + m + __logf(s);
    ebc = ebn;
  }

  float val = aj + endv[j];           // both halves hold identical val(j)
  float M = val;
#pragma unroll
  for (int off = 16; off > 0; off >>= 1) M = fmaxf(M, __shfl_xor(M, off));
  float sz = __expf(val - M);
#pragma unroll
  for (int off = 16; off > 0; off >>= 1) sz += __shfl_xor(sz, off);
  float logZ = M + __logf(sz);

  const int* tg = tags + (size_t)b * Tt;
  float g = 0.f;
  for (int t = l; t < Tt; t += 64) {
    int cur = tg[t];
    g += eb[(size_t)t * 2048 + cur];
    if (t >= 1) g += tr[cur * Kk + tg[t - 1]];
  }
#pragma unroll
  for (int off = 32; off > 0; off >>= 1) g += __shfl_xor(g, off);
  if (l == 0) {
    g += startv[tg[0]] + endv[tg[Tt - 1]];
    nll[b] = logZ - g;
  }
}

__global__ void k_reduce(const float* __restrict__ nll, float* __restrict__ out) {
  float v = nll[threadIdx.x];
#pragma unroll
  for (int off = 32; off > 0; off >>= 1) v += __shfl_xor(v, off);
  if (threadIdx.x == 0) out[0] = v * (1.0f / 64.0f);
}

// --------------------------------------------------------------------------
extern "C" void kernel_launch(void* const* d_in, const int* in_sizes, int n_in,
                              void* d_out, int out_size, void* d_ws, size_t ws_size,
                              hipStream_t stream) {
  (void)in_sizes; (void)n_in; (void)out_size; (void)ws_size;
  const int*   x      = (const int*)d_in[0];
  const int*   tags   = (const int*)d_in[2];
  const float* emb    = (const float*)d_in[4];
  const float* Wih0f  = (const float*)d_in[5];
  const float* Whh0f  = (const float*)d_in[6];
  const float* b0f    = (const float*)d_in[7];
  const float* Wih0b  = (const float*)d_in[8];
  const float* Whh0b  = (const float*)d_in[9];
  const float* b0b    = (const float*)d_in[10];
  const float* Wih1f  = (const float*)d_in[11];
  const float* Whh1f  = (const float*)d_in[12];
  const float* b1f    = (const float*)d_in[13];
  const float* Wih1b  = (const float*)d_in[14];
  const float* Whh1b  = (const float*)d_in[15];
  const float* b1b    = (const float*)d_in[16];
  const float* fcW    = (const float*)d_in[17];
  const float* fcb    = (const float*)d_in[18];
  const float* trans  = (const float*)d_in[19];
  const float* startv = (const float*)d_in[20];
  const float* endv   = (const float*)d_in[21];

  char* p = (char*)d_ws;
  u16* buf0 = (u16*)p; p += (size_t)BT * Ee * 2;   // embeddings / layer-1 out
  u16* buf1 = (u16*)p; p += (size_t)BT * 256 * 2;  // layer-0 out
  u16* xpf  = (u16*)p; p += (size_t)BT * G4 * 2;   // fwd proj (lstm layout)
  u16* xpb  = (u16*)p; p += (size_t)BT * G4 * 2;   // bwd proj (lstm layout)
  u16* wb[4];
  for (int i = 0; i < 4; ++i) { wb[i] = (u16*)p; p += (size_t)512 * 256 * 2; }
  u16* fcwb = (u16*)p; p += (size_t)32 * 256 * 2;
  float* bias_p = (float*)p; p += 4 * 512 * 4;     // permuted biases
  float* emis = (float*)p; p += ((size_t)BT * Kk + 64 * Kk) * 4;  // +pad row
  float* nll  = (float*)p; p += 256;

  k_embprep<<<dim3(8192 + 528), dim3(256), 0, stream>>>(
      x, emb, buf0,
      Wih0f, Wih0b, Wih1f, Wih1b, wb[0], wb[1], wb[2], wb[3],
      fcW, fcwb, b0f, b0b, b1f, b1b, bias_p);

  dim3 ggrid(BT / 256, 8);
  // layer 0
  k_gemm6<<<ggrid, dim3(512), 0, stream>>>(buf0, wb[0], wb[1],
                                           bias_p, bias_p + 512, xpf, xpb);
  k_lstm10<<<dim3(32), dim3(512), 0, stream>>>(xpf, xpb, Whh0f, Whh0b, buf1);
  // layer 1
  k_gemm6<<<ggrid, dim3(512), 0, stream>>>(buf1, wb[2], wb[3],
                                           bias_p + 1024, bias_p + 1536, xpf, xpb);
  k_lstm10<<<dim3(32), dim3(512), 0, stream>>>(xpf, xpb, Whh1f, Whh1b, buf0);
  // emissions + CRF
  k_fc2<<<dim3(BT / 128), dim3(256), 0, stream>>>(buf0, fcwb, fcb, emis);
  k_crf<<<dim3(Bb), dim3(64), 0, stream>>>(emis, tags, trans, startv, endv, nll);
  k_reduce<<<dim3(1), dim3(64), 0, stream>>>(nll, (float*)d_out);
}